// Round 1
// baseline (2318.639 us; speedup 1.0000x reference)
//
#include <hip/hip_runtime.h>
#include <math.h>

#define SS 512
#define AANG 60
#define DDET 729
#define NPIX (SS*SS)        // 262144
#define NSIN (AANG*DDET)    // 43740
#define NTAPS 1457

typedef float v4u __attribute__((ext_vector_type(4), aligned(4)));
typedef float v4a __attribute__((ext_vector_type(4), aligned(16)));
typedef float v2u __attribute__((ext_vector_type(2), aligned(8)));
typedef float v2a __attribute__((ext_vector_type(2), aligned(4)));
typedef short short8 __attribute__((ext_vector_type(8)));
typedef float f32x4 __attribute__((ext_vector_type(4)));

// round-to-nearest-even fp32 -> bf16 bits
__device__ inline unsigned short f2bf(float x){
  unsigned u = __float_as_uint(x);
  return (unsigned short)((u + 0x7fffu + ((u >> 16) & 1u)) >> 16);
}

// ---------------- trig table ----------------
__global__ void trig_kernel(const float* __restrict__ theta, float* __restrict__ trig){
  int a = threadIdx.x;
  if (a < AANG){ trig[a] = cosf(theta[a]); trig[AANG+a] = sinf(theta[a]); }
}

// ---------------- ramp-filter taps ----------------
__global__ void taps_kernel(float* __restrict__ taps){
  __shared__ double red[256];
  int m  = blockIdx.x;
  int mm = m - 728;
  double s = 0.0;
  for (int k = 1 + (int)threadIdx.x; k <= 1023; k += 256){
    int phase = (k*mm) & 2047;
    s += (double)k * cos((double)phase * (M_PI/1024.0));
  }
  red[threadIdx.x] = s;
  __syncthreads();
  for (int off=128; off; off>>=1){
    if ((int)threadIdx.x < off) red[threadIdx.x] += red[threadIdx.x+off];
    __syncthreads();
  }
  if (threadIdx.x==0){
    double x = (red[0]*(1.0/512.0) + ((mm & 1) ? -1.0 : 1.0)) / 2048.0;
    taps[m] = (float)(x * (M_PI/120.0));
  }
}

// ---------------- conv3 weight transposes: -> [L][Cin][9][5] ----------------
__global__ void transpose_all(const float* __restrict__ s2, float* __restrict__ d2,
                              const float* __restrict__ s5, float* __restrict__ d5){
  int idx = blockIdx.x*256 + (int)threadIdx.x;
  const float* src; float* dst;
  int Cout = 5, Cin = 32;
  if      (idx < 14400){              src=s2; dst=d2; }
  else if (idx < 28800){ idx-=14400;  src=s5; dst=d5; }
  else return;
  int t = idx % 9; int r = idx/9;
  int i = r % Cin; r /= Cin;
  int o = r % Cout; int l = r/Cout;
  dst[((l*Cin+i)*9+t)*Cout+o] = src[idx];
}

// ---------------- cg-split re-layout: [L][32][Cin][3][3] -> [L][Cin][4][9][8] ----------
__global__ void transpose_w8(const float* __restrict__ src, float* __restrict__ dst, int Cin){
  int idx = blockIdx.x*256 + (int)threadIdx.x;
  int tot = 10*32*Cin*9;
  if (idx >= tot) return;
  int t = idx % 9; int r = idx/9;
  int i = r % Cin; r /= Cin;
  int o = r % 32; int l = r/32;
  int cg = o >> 3, u = o & 7;
  dst[(((l*Cin + i)*4 + cg)*9 + t)*8 + u] = src[idx];
}

// -------- MFMA B-fragment image for pw2: [L][tap=9][n=2][prod=2][lane=64][8] bf16 --------
__global__ void prep_bimg(const float* __restrict__ w, unsigned short* __restrict__ B){
  int idx = blockIdx.x*256 + (int)threadIdx.x;
  if (idx >= 10*9*2*64*8) return;
  int j    =  idx        & 7;
  int lane = (idx >> 3)  & 63;
  int n    = (idx >> 9)  & 1;
  int r    =  idx >> 10;          // l*9 + tap
  int tap = r % 9, l = r / 9;
  int c = (lane >> 4)*8 + j;      // k = channel
  int o = n*16 + (lane & 15);     // output channel
  float x = w[(((size_t)(l*32+o)*32 + c)*9) + tap];
  unsigned short hb = f2bf(x);
  float hf = __uint_as_float((unsigned)hb << 16);
  unsigned short lb = f2bf(x - hf);
  size_t d = (size_t)l*18432 + (size_t)tap*2048 + n*1024 + lane*8 + j;
  B[d]       = hb;
  B[d + 512] = lb;
}

// ---------------- radon forward (R6-proven) ----------------
__device__ inline void clipr(float al, float be, float lo, float hi,
                             float& A, float& B, bool& empty){
  if (fabsf(al) < 1e-7f){ if (be < lo || be > hi) empty = true; return; }
  float t0 = (lo - be)/al, t1 = (hi - be)/al;
  float mn = fminf(t0,t1), mx = fmaxf(t0,t1);
  A = fmaxf(A, mn); B = fminf(B, mx);
}

__device__ inline float samp_guard(const float* __restrict__ base, float aR, float bR,
                                   float aC, float bC, int t){
  float tp = (float)t - 255.5f;
  float R = fmaf(aR, tp, bR);
  float C = fmaf(aC, tp, bC);
  float rf = floorf(R), cf = floorf(C);
  int r0 = (int)rf, c0 = (int)cf;
  int r1 = r0+1,    c1 = c0+1;
  float fr = R - rf, fc = C - cf;
  bool r0ok = (r0>=0 && r0<SS), r1ok = (r1>=0 && r1<SS);
  bool c0ok = (c0>=0 && c0<SS), c1ok = (c1>=0 && c1<SS);
  float v00 = (r0ok && c0ok) ? base[r0*SS+c0] : 0.f;
  float v01 = (r0ok && c1ok) ? base[r0*SS+c1] : 0.f;
  float v10 = (r1ok && c0ok) ? base[r1*SS+c0] : 0.f;
  float v11 = (r1ok && c1ok) ? base[r1*SS+c1] : 0.f;
  return (1.f-fr)*((1.f-fc)*v00 + fc*v01) + fr*((1.f-fc)*v10 + fc*v11);
}

__global__ __launch_bounds__(256) void radon_fwd_kernel(
    const float* __restrict__ img, const float* __restrict__ imgT,
    const float* __restrict__ trig, float* __restrict__ out){
  int gid  = blockIdx.x*4 + ((int)threadIdx.x >> 6);
  int lane = (int)threadIdx.x & 63;
  if (gid >= NSIN) return;
  int a = gid / DDET;
  int d = gid - a*DDET;
  float ca = trig[a], sa = trig[AANG+a];
  float sd = (float)d - 364.0f;
  float Rc = fmaf(sd, sa, 255.5f);
  float Cc = fmaf(sd, ca, 255.5f);
  float aR = ca, bR = Rc, aC = -sa, bC = Cc;
  const float* base = img;
  if (fabsf(ca) > fabsf(sa)){
    base = imgT;
    float tmp;
    tmp=aR; aR=aC; aC=tmp;
    tmp=bR; bR=bC; bC=tmp;
  }
  float tiA = -255.5f, tiB = 255.5f;  bool iE=false;
  float teA = -255.5f, teB = 255.5f;  bool eE=false;
  clipr(aR,bR, 0.001f, 510.999f, tiA,tiB,iE);
  clipr(aC,bC, 0.001f, 510.999f, tiA,tiB,iE);
  clipr(aR,bR, -0.999f, 511.999f, teA,teB,eE);
  clipr(aC,bC, -0.999f, 511.999f, teA,teB,eE);
  float acc = 0.f;
  if (!eE && teA <= teB){
    int eA = max(0,   (int)floorf(teA+255.5f) - 1);
    int eB = min(511, (int)ceilf (teB+255.5f) + 1);
    int iA = (int)ceilf (tiA+255.5f) + 1;
    int iB = (int)floorf(tiB+255.5f) - 1;
    iA = max(iA, eA); iB = min(iB, eB);
    if (iE || iA > iB){
      for (int t = eA+lane; t <= eB; t += 64) acc += samp_guard(base,aR,bR,aC,bC,t);
    } else {
      for (int t = eA+lane;   t <  iA; t += 64) acc += samp_guard(base,aR,bR,aC,bC,t);
      for (int t = iB+1+lane; t <= eB; t += 64) acc += samp_guard(base,aR,bR,aC,bC,t);
      for (int t = iA+lane;   t <= iB; t += 64){
        float tp = (float)t - 255.5f;
        float R = fmaf(aR, tp, bR);
        float C = fmaf(aC, tp, bC);
        int r0 = (int)R, c0 = (int)C;
        float fr = R - (float)r0, fc = C - (float)c0;
        const float* p = base + r0*SS + c0;
        float v00 = p[0], v01 = p[1], v10 = p[SS], v11 = p[SS+1];
        float top = v00 + fc*(v01-v00);
        float bot = v10 + fc*(v11-v10);
        acc += top + fr*(bot-top);
      }
    }
  }
  for (int off=32; off; off>>=1) acc += __shfl_down(acc, off);
  if (lane==0) out[gid] = acc;
}

// ---------------- ramp filter ----------------
__global__ void filter_kernel(const float* __restrict__ h0, const float* __restrict__ taps,
                              float* __restrict__ h1){
  int gid = blockIdx.x*blockDim.x + threadIdx.x;
  if (gid >= NSIN) return;
  int a = gid / DDET;
  int j = gid - a*DDET;
  const float* row = h0 + a*DDET;
  float acc = 0.f;
  for (int k=0;k<DDET;k++){
    acc += row[k] * taps[728 + j - k];
  }
  h1[gid] = acc;
}

// ---------------- backprojection ----------------
__global__ __launch_bounds__(256) void backproj_kernel(
    const float* __restrict__ h1, const float* __restrict__ trig,
    float* __restrict__ out){
  __shared__ float sh[AANG*28];
  __shared__ int   sbase[AANG];
  __shared__ float strig[2*AANG];
  int tid = threadIdx.x;
  int x0 = (blockIdx.x & 31) * 16, y0 = (blockIdx.x >> 5) * 16;
  if (tid < 2*AANG) strig[tid] = trig[tid];
  __syncthreads();
  if (tid < AANG){
    float ca = strig[tid], sa = strig[AANG+tid];
    float Xa = (float)x0 - 255.5f, Xb = Xa + 15.f;
    float Ya = (float)y0 - 255.5f, Yb = Ya + 15.f;
    float s00 = Xa*ca + Ya*sa, s01 = Xb*ca + Ya*sa;
    float s10 = Xa*ca + Yb*sa, s11 = Xb*ca + Yb*sa;
    float mn = fminf(fminf(s00,s01), fminf(s10,s11)) + 364.0f;
    sbase[tid] = (int)floorf(mn) - 2;
  }
  __syncthreads();
  for (int s = tid; s < AANG*28; s += 256){
    int a = s / 28, j = s - a*28;
    int idx = sbase[a] + j;
    sh[s] = (idx >= 0 && idx < DDET) ? h1[a*DDET + idx] : 0.f;
  }
  __syncthreads();
  int x = x0 + (tid & 15), y = y0 + (tid >> 4);
  float X = (float)x - 255.5f, Y = (float)y - 255.5f;
  float acc = 0.f;
  #pragma unroll 6
  for (int a=0;a<AANG;a++){
    float sidx = fmaf(X, strig[a], fmaf(Y, strig[AANG+a], 364.0f));
    float ff = floorf(sidx);
    int k = (int)ff - sbase[a];
    float fi = sidx - ff;
    float v0 = sh[a*28+k], v1 = sh[a*28+k+1];
    acc += v0 + fi*(v1-v0);
  }
  out[y*SS+x] = acc;
}

// ---------------- dual conv cg-split (R6-proven, global weights) ----------------
__global__ __launch_bounds__(256) void conv3x3_dualcg(
    const float* __restrict__ in1, int Cin1,
    const float* __restrict__ in2, int Cin2,
    const float* __restrict__ wt,
    const float* __restrict__ bias, const float* __restrict__ prelu,
    float* __restrict__ out)
{
  const int W = DDET, HW = NSIN;
  int pix = blockIdx.x*256 + (int)threadIdx.x;
  if (pix >= NSIN) return;
  int cg = blockIdx.y;
  int y = pix / W, x = pix - y*W;
  bool ym = y>0, yp = y<AANG-1, xm = x>0, xp = x<W-1;
  float acc[8];
  #pragma unroll
  for (int o=0;o<8;o++) acc[o] = bias[cg*8+o];
  const float* wch = wt + cg*72;
  for (int part=0; part<2; part++){
    const float* src = part ? in2 : in1;
    int nch = part ? Cin2 : Cin1;
    const float* ip = src + pix;
    for (int i=0;i<nch;i++, ip+=HW, wch+=288){
      float p4 = ip[0];
      float p0=0,p1=0,p2=0,p3=0,p5=0,p6=0,p7=0,p8=0;
      if (ym){ p1 = ip[-W]; if (xm) p0 = ip[-W-1]; if (xp) p2 = ip[-W+1]; }
      if (xm) p3 = ip[-1];
      if (xp) p5 = ip[1];
      if (yp){ p7 = ip[W]; if (xm) p6 = ip[W-1]; if (xp) p8 = ip[W+1]; }
      float p[9] = {p0,p1,p2,p3,p4,p5,p6,p7,p8};
      #pragma unroll
      for (int t=0;t<9;t++){
        float v = p[t];
        #pragma unroll
        for (int o=0;o<8;o++) acc[o] = fmaf(v, wch[t*8+o], acc[o]);
      }
    }
  }
  float aa = *prelu;
  float* op = out + (size_t)(cg*8)*HW + pix;
  #pragma unroll
  for (int o=0;o<8;o++){
    float s = acc[o];
    s = (s>=0.f) ? s : aa*s;
    op[o*HW] = s;
  }
}

// ---------------- dual conv3 (32->5): accumulate into h ----------------
template<int COUT, int W>
__global__ __launch_bounds__(256) void conv3x3_fast(
    const float* __restrict__ in1, int Cin1,
    const float* __restrict__ wt,
    const float* __restrict__ bias,
    float* __restrict__ out, int H)
{
  int HW = H*W;
  int pix = blockIdx.x*256 + (int)threadIdx.x;
  if (pix >= HW) return;
  int y = pix / W, x = pix - y*W;
  bool ym = y>0, yp = y<H-1, xm = x>0, xp = x<W-1;
  float acc[COUT];
  #pragma unroll
  for (int o=0;o<COUT;o++) acc[o] = bias[o];
  const float* wr = wt;
  const float* ip = in1 + pix;
  for (int i=0;i<Cin1;i++, ip+=HW){
    float p4 = ip[0];
    float p0=0,p1=0,p2=0,p3=0,p5=0,p6=0,p7=0,p8=0;
    if (ym){ p1 = ip[-W]; if (xm) p0 = ip[-W-1]; if (xp) p2 = ip[-W+1]; }
    if (xm) p3 = ip[-1];
    if (xp) p5 = ip[1];
    if (yp){ p7 = ip[W]; if (xm) p6 = ip[W-1]; if (xp) p8 = ip[W+1]; }
    float p[9] = {p0,p1,p2,p3,p4,p5,p6,p7,p8};
    #pragma unroll
    for (int t=0;t<9;t++){
      float v = p[t];
      #pragma unroll
      for (int o=0;o<COUT;o++) acc[o] = fmaf(v, wr[t*COUT+o], acc[o]);
    }
    wr += 9*COUT;
  }
  float* op = out + pix;
  #pragma unroll
  for (int o=0;o<COUT;o++) op[o*HW] += acc[o];
}

// ---------------- primal conv1 (6->32): R6 quad + NHWC bf16 hi/lo epilogue ----------------
__device__ inline void loadrow6(float* R, const float* p, bool valid, bool lE, bool rE){
  if (valid){
    v4u a = *(const v4u*)(p-1);
    v2a b = *(const v2a*)(p+3);
    R[0]=lE?0.f:a.x; R[1]=a.y; R[2]=a.z; R[3]=a.w;
    R[4]=b.x; R[5]=rE?0.f:b.y;
  } else {
    #pragma unroll
    for (int k=0;k<6;k++) R[k]=0.f;
  }
}

__global__ __launch_bounds__(256) void conv3x3_quad6(
    const float* __restrict__ in,      // 6 contiguous channels [f(5)|bp]
    const float* __restrict__ wt,      // [6][4][9][8]
    const float* __restrict__ bias, const float* __restrict__ prelu,
    unsigned short* __restrict__ outHi, unsigned short* __restrict__ outLo)
{
  const int W = SS, HW = NPIX;
  int rb = blockIdx.x;                       // 0..255 row-pairs
  int cg = blockIdx.y;                       // 0..3
  int yb = ((rb & 7) << 5) | (rb >> 3);      // XCD swizzle
  int wv = (int)threadIdx.x >> 6;
  int lane = (int)threadIdx.x & 63;
  int y = yb*2 + (wv >> 1);
  int xb = ((wv & 1) << 8) + lane*4;
  const float* wch = wt + cg*72;
  float acc[4][8];
  #pragma unroll
  for (int px=0;px<4;px++)
    #pragma unroll
    for (int o=0;o<8;o++) acc[px][o] = 0.f;
  bool ym = y>0, yp = y<SS-1;
  bool lE = (xb==0), rE = (xb==508);
  const float* ip = in + y*W + xb;
  for (int i=0;i<6;i++, ip+=HW, wch+=288){
    float R[3][6];
    loadrow6(R[0], ip - W, ym,   lE, rE);
    loadrow6(R[1], ip,     true, lE, rE);
    loadrow6(R[2], ip + W, yp,   lE, rE);
    #pragma unroll
    for (int dy=0;dy<3;dy++){
      #pragma unroll
      for (int dx=0;dx<3;dx++){
        #pragma unroll
        for (int o=0;o<8;o++){
          float w = wch[(dy*3+dx)*8+o];
          #pragma unroll
          for (int px=0;px<4;px++)
            acc[px][o] = fmaf(R[dy][px+dx], w, acc[px][o]);
        }
      }
    }
  }
  float aa = *prelu;
  #pragma unroll
  for (int px=0;px<4;px++){
    short8 vh, vl;
    #pragma unroll
    for (int o=0;o<8;o++){
      float s = acc[px][o] + bias[cg*8+o];
      s = (s>=0.f) ? s : aa*s;
      unsigned short hb = f2bf(s);
      float hf = __uint_as_float((unsigned)hb << 16);
      unsigned short lb = f2bf(s - hf);
      vh[o] = (short)hb; vl[o] = (short)lb;
    }
    size_t base = ((size_t)(y*W + xb + px))*32 + cg*8;
    *(short8*)(outHi + base) = vh;
    *(short8*)(outLo + base) = vl;
  }
}

// ---------------- primal conv2 (32->32): implicit-GEMM MFMA bf16 hi/lo ----------------
// Block = 4 waves, each wave: 64 px (4 m-subtiles of 16) x 32 outs (2 n-subtiles).
// K = 9 taps x 32 channels; per tap 3 products (hi*hi, lo*hi, hi*lo).
__global__ __launch_bounds__(256) void conv_mfma32(
    const unsigned short* __restrict__ hiB, const unsigned short* __restrict__ loB,
    const unsigned short* __restrict__ Bimg,   // this layer: [9][2][2][64][8]
    const float* __restrict__ bias, const float* __restrict__ prelu,
    float* __restrict__ out)
{
  int b = blockIdx.x;                 // 0..1023
  int by = b >> 1, half = b & 1;
  int y = ((by & 7) << 6) | (by >> 3);   // XCD row swizzle
  int wv = (int)threadIdx.x >> 6;
  int lane = (int)threadIdx.x & 63;
  int xw = half*256 + wv*64;
  int lm = lane & 15, lq = lane >> 4;
  int laneoff = lm*32 + lq*8;
  f32x4 acc[4][2];
  #pragma unroll
  for (int s=0;s<4;s++){ acc[s][0] = (f32x4)0.f; acc[s][1] = (f32x4)0.f; }
  bool fastx = (xw != 0) && (xw != 448);
  const short8* Bf = (const short8*)Bimg;
  #pragma unroll
  for (int dy=-1; dy<=1; dy++){
    int yy = y + dy;
    if ((unsigned)yy >= 512u) continue;
    const unsigned short* rh = hiB + (size_t)yy*512*32;
    const unsigned short* rl = loB + (size_t)yy*512*32;
    #pragma unroll
    for (int dx=-1; dx<=1; dx++){
      int tap = (dy+1)*3 + (dx+1);
      const short8* bp8 = Bf + tap*256 + lane;
      short8 bh0 = bp8[0];     // n=0 hi
      short8 bl0 = bp8[64];    // n=0 lo
      short8 bh1 = bp8[128];   // n=1 hi
      short8 bl1 = bp8[192];   // n=1 lo
      int xoff = (xw + dx)*32 + laneoff;
      #pragma unroll
      for (int s=0; s<4; s++){
        short8 ah, al;
        const unsigned short* ph = rh + xoff + s*512;
        const unsigned short* pl = rl + xoff + s*512;
        if (fastx){
          ah = *(const short8*)ph;
          al = *(const short8*)pl;
        } else {
          int x = xw + s*16 + lm + dx;
          bool ok = ((unsigned)x < 512u);
          ah = ok ? *(const short8*)ph : (short8)0;
          al = ok ? *(const short8*)pl : (short8)0;
        }
        acc[s][0] = __builtin_amdgcn_mfma_f32_16x16x32_bf16(ah, bh0, acc[s][0], 0,0,0);
        acc[s][1] = __builtin_amdgcn_mfma_f32_16x16x32_bf16(ah, bh1, acc[s][1], 0,0,0);
        acc[s][0] = __builtin_amdgcn_mfma_f32_16x16x32_bf16(al, bh0, acc[s][0], 0,0,0);
        acc[s][1] = __builtin_amdgcn_mfma_f32_16x16x32_bf16(al, bh1, acc[s][1], 0,0,0);
        acc[s][0] = __builtin_amdgcn_mfma_f32_16x16x32_bf16(ah, bl0, acc[s][0], 0,0,0);
        acc[s][1] = __builtin_amdgcn_mfma_f32_16x16x32_bf16(ah, bl1, acc[s][1], 0,0,0);
      }
    }
  }
  // epilogue: bias + prelu + planar fp32 store
  float aa = *prelu;
  #pragma unroll
  for (int s=0;s<4;s++){
    #pragma unroll
    for (int n=0;n<2;n++){
      int o = n*16 + lm;
      float bv = bias[o];
      f32x4 v = acc[s][n];
      v.x+=bv; v.y+=bv; v.z+=bv; v.w+=bv;
      v.x=(v.x>=0.f)?v.x:aa*v.x; v.y=(v.y>=0.f)?v.y:aa*v.y;
      v.z=(v.z>=0.f)?v.z:aa*v.z; v.w=(v.w>=0.f)?v.w:aa*v.w;
      *(f32x4*)(out + (size_t)o*NPIX + y*SS + xw + s*16 + lq*4) = v;
    }
  }
}

// ---------------- primal conv3 (32->5): one row per block, 2 px/thread ----------------
template<int COUT>
__global__ __launch_bounds__(256) void conv3x3_duo(
    const float* __restrict__ in1, int Cin1,
    const float* __restrict__ wt,
    const float* __restrict__ bias,
    float* __restrict__ out,
    float* __restrict__ fout, float* __restrict__ tout)
{
  const int W = SS, HW = NPIX;
  int b = blockIdx.x;
  int y = ((b & 7) << 6) | (b >> 3);
  int x0 = (int)threadIdx.x * 2;
  int pix0 = y*W + x0;
  bool ym = y > 0, yp = y < SS-1;
  bool l0 = x0 > 0;
  bool r3 = x0 + 2 < W;
  float acc0[COUT], acc1[COUT];
  #pragma unroll
  for (int o=0;o<COUT;o++){ float bv = bias[o]; acc0[o]=bv; acc1[o]=bv; }
  const float* wr = wt;
  const float* ip = in1 + pix0;
  #pragma unroll 2
  for (int i=0;i<Cin1;i++, ip+=HW){
    v4u A = ym ? *(const v4u*)(ip - W - 1) : (v4u)0.f;
    v4u B = *(const v4u*)(ip - 1);
    v4u D = yp ? *(const v4u*)(ip + W - 1) : (v4u)0.f;
    if (!l0){ A.x = 0.f; B.x = 0.f; D.x = 0.f; }
    if (!r3){ A.w = 0.f; B.w = 0.f; D.w = 0.f; }
    float w0[9] = {A.x,A.y,A.z, B.x,B.y,B.z, D.x,D.y,D.z};
    float w1[9] = {A.y,A.z,A.w, B.y,B.z,B.w, D.y,D.z,D.w};
    #pragma unroll
    for (int t=0;t<9;t++){
      float v0 = w0[t], v1 = w1[t];
      #pragma unroll
      for (int o=0;o<COUT;o++){
        float w = wr[t*COUT+o];
        acc0[o] = fmaf(v0, w, acc0[o]);
        acc1[o] = fmaf(v1, w, acc1[o]);
      }
    }
    wr += 9*COUT;
  }
  float* op = out + pix0;
  #pragma unroll
  for (int o=0;o<COUT;o++){
    float s0 = acc0[o], s1 = acc1[o];
    v2u old = *(const v2u*)(op + o*HW);
    s0 += old.x; s1 += old.y;
    v2u st; st.x = s0; st.y = s1;
    *(v2u*)(op + o*HW) = st;
    if (o==1 && tout){ tout[x0*SS + y] = s0; tout[(x0+1)*SS + y] = s1; }
    if (o==0 && fout){
      *(v2u*)(fout + pix0) = st;
      *(v2u*)(fout + HW + pix0) = st;
      *(v2u*)(fout + 2*HW + pix0) = st;
    }
  }
}

extern "C" void kernel_launch(void* const* d_in, const int* in_sizes, int n_in,
                              void* d_out, int out_size, void* d_ws, size_t ws_size,
                              hipStream_t stream){
  const float* g     = (const float*)d_in[2];
  const float* theta = (const float*)d_in[3];
  const float* dw1 = (const float*)d_in[5];
  const float* db1 = (const float*)d_in[6];
  const float* da1 = (const float*)d_in[7];
  const float* dw2 = (const float*)d_in[8];
  const float* db2 = (const float*)d_in[9];
  const float* da2 = (const float*)d_in[10];
  const float* dw3 = (const float*)d_in[11];
  const float* db3 = (const float*)d_in[12];
  const float* pw1 = (const float*)d_in[13];
  const float* pb1 = (const float*)d_in[14];
  const float* pa1 = (const float*)d_in[15];
  const float* pw2 = (const float*)d_in[16];
  const float* pb2 = (const float*)d_in[17];
  const float* pa2 = (const float*)d_in[18];
  const float* pw3 = (const float*)d_in[19];
  const float* pb3 = (const float*)d_in[20];

  float* ws     = (float*)d_ws;
  float* trig   = ws;                    // 128
  float* taps   = ws + 128;              // -> 2048
  float* h      = ws + 2048;             // 5*NSIN
  float* opf    = h + 5*NSIN;            // NSIN
  float* gcopy  = opf + NSIN;            // NSIN
  float* h1     = gcopy + NSIN;          // NSIN
  float* f      = h1 + NSIN;             // 5*NPIX
  float* bp     = f + 5*NPIX;            // NPIX
  float* imgT   = bp + NPIX;             // NPIX
  float* dualT1 = imgT + NPIX;           // 32*NSIN
  float* dualT2 = dualT1 + 32*NSIN;      // 32*NSIN
  float* primT2 = dualT2 + 32*NSIN;      // 32*NPIX
  unsigned short* nhwcHi = (unsigned short*)(primT2 + 32*NPIX);  // 32*NPIX ushorts
  unsigned short* nhwcLo = nhwcHi + (size_t)32*NPIX;             // 32*NPIX ushorts
  float* wsp   = (float*)(nhwcLo + (size_t)32*NPIX);
  float* wtd3  = wsp;                    // 14400
  float* wtp3  = wsp + 14400;            // 14400
  float* wtd1b = wsp + 28800;            // 20160
  float* wtd2b = wsp + 48960;            // 92160
  float* wtp1b = wsp + 141120;           // 17280
  unsigned short* Bimg = (unsigned short*)(wsp + 158400);  // 184320 ushorts

  hipMemsetAsync(h, 0, (size_t)(5*NSIN)*sizeof(float), stream);
  hipMemsetAsync(f, 0, (size_t)(7*NPIX)*sizeof(float), stream);   // f, bp, imgT
  hipMemcpyAsync(gcopy, g, (size_t)NSIN*sizeof(float), hipMemcpyDeviceToDevice, stream);
  trig_kernel<<<1,64,0,stream>>>(theta, trig);
  taps_kernel<<<NTAPS,256,0,stream>>>(taps);
  transpose_all<<<(28800+255)/256,256,0,stream>>>(dw3,wtd3, pw3,wtp3);
  transpose_w8<<<(20160+255)/256,256,0,stream>>>(dw1, wtd1b, 7);
  transpose_w8<<<(92160+255)/256,256,0,stream>>>(dw2, wtd2b, 32);
  transpose_w8<<<(17280+255)/256,256,0,stream>>>(pw1, wtp1b, 6);
  prep_bimg<<<(92160+255)/256,256,0,stream>>>(pw2, Bimg);

  const int GD = (NSIN+255)/256;       // 171

  for (int i=0;i<10;i++){
    radon_fwd_kernel<<<(NSIN+3)/4,256,0,stream>>>(f + NPIX, imgT, trig, opf);
    // dual block: in = [h(5) | opf | g] (opf,gcopy contiguous after h)
    conv3x3_dualcg<<<dim3(GD,4),256,0,stream>>>(h, 5, opf, 2,      wtd1b+(size_t)i*7*288,  db1+(size_t)i*32, da1+i, dualT1);
    conv3x3_dualcg<<<dim3(GD,4),256,0,stream>>>(dualT1, 32, nullptr, 0, wtd2b+(size_t)i*32*288, db2+(size_t)i*32, da2+i, dualT2);
    conv3x3_fast<5,DDET><<<GD,256,0,stream>>>(dualT2, 32, wtd3+i*1440, db3+(size_t)i*5, h, AANG);
    filter_kernel<<<GD,256,0,stream>>>(h, taps, h1);
    backproj_kernel<<<NPIX/256,256,0,stream>>>(h1, trig, bp);
    // primal block: in = [f(5) | bp] contiguous
    conv3x3_quad6<<<dim3(256,4),256,0,stream>>>(f, wtp1b+(size_t)i*6*288, pb1+(size_t)i*32, pa1+i, nhwcHi, nhwcLo);
    conv_mfma32<<<1024,256,0,stream>>>(nhwcHi, nhwcLo, Bimg+(size_t)i*18432, pb2+(size_t)i*32, pa2+i, primT2);
    conv3x3_duo<5><<<SS,256,0,stream>>>(primT2, 32, wtp3+i*1440, pb3+(size_t)i*5, f,
                                        (i==9) ? (float*)d_out : nullptr, imgT);
  }
}

// Round 2
// 2224.149 us; speedup vs baseline: 1.0425x; 1.0425x over previous
//
#include <hip/hip_runtime.h>
#include <math.h>

#define SS 512
#define AANG 60
#define DDET 729
#define NPIX (SS*SS)        // 262144
#define NSIN (AANG*DDET)    // 43740
#define NTAPS 1457

typedef float v4u __attribute__((ext_vector_type(4), aligned(4)));
typedef float v4a __attribute__((ext_vector_type(4), aligned(16)));
typedef float v2u __attribute__((ext_vector_type(2), aligned(8)));
typedef float v2a __attribute__((ext_vector_type(2), aligned(4)));
typedef short short8 __attribute__((ext_vector_type(8)));
typedef float f32x4 __attribute__((ext_vector_type(4)));

// round-to-nearest-even fp32 -> bf16 bits
__device__ inline unsigned short f2bf(float x){
  unsigned u = __float_as_uint(x);
  return (unsigned short)((u + 0x7fffu + ((u >> 16) & 1u)) >> 16);
}

// ---------------- trig table ----------------
__global__ void trig_kernel(const float* __restrict__ theta, float* __restrict__ trig){
  int a = threadIdx.x;
  if (a < AANG){ trig[a] = cosf(theta[a]); trig[AANG+a] = sinf(theta[a]); }
}

// ---------------- ramp-filter taps ----------------
__global__ void taps_kernel(float* __restrict__ taps){
  __shared__ double red[256];
  int m  = blockIdx.x;
  int mm = m - 728;
  double s = 0.0;
  for (int k = 1 + (int)threadIdx.x; k <= 1023; k += 256){
    int phase = (k*mm) & 2047;
    s += (double)k * cos((double)phase * (M_PI/1024.0));
  }
  red[threadIdx.x] = s;
  __syncthreads();
  for (int off=128; off; off>>=1){
    if ((int)threadIdx.x < off) red[threadIdx.x] += red[threadIdx.x+off];
    __syncthreads();
  }
  if (threadIdx.x==0){
    double x = (red[0]*(1.0/512.0) + ((mm & 1) ? -1.0 : 1.0)) / 2048.0;
    taps[m] = (float)(x * (M_PI/120.0));
  }
}

// ---------------- conv3 weight transposes: -> [L][Cin][9][5] ----------------
__global__ void transpose_all(const float* __restrict__ s2, float* __restrict__ d2,
                              const float* __restrict__ s5, float* __restrict__ d5){
  int idx = blockIdx.x*256 + (int)threadIdx.x;
  const float* src; float* dst;
  int Cout = 5, Cin = 32;
  if      (idx < 14400){              src=s2; dst=d2; }
  else if (idx < 28800){ idx-=14400;  src=s5; dst=d5; }
  else return;
  int t = idx % 9; int r = idx/9;
  int i = r % Cin; r /= Cin;
  int o = r % Cout; int l = r/Cout;
  dst[((l*Cin+i)*9+t)*Cout+o] = src[idx];
}

// ---------------- cg-split re-layout: [L][32][Cin][3][3] -> [L][Cin][4][9][8] ----------
__global__ void transpose_w8(const float* __restrict__ src, float* __restrict__ dst, int Cin){
  int idx = blockIdx.x*256 + (int)threadIdx.x;
  int tot = 10*32*Cin*9;
  if (idx >= tot) return;
  int t = idx % 9; int r = idx/9;
  int i = r % Cin; r /= Cin;
  int o = r % 32; int l = r/32;
  int cg = o >> 3, u = o & 7;
  dst[(((l*Cin + i)*4 + cg)*9 + t)*8 + u] = src[idx];
}

// -------- MFMA B-fragment image for pw2: [L][tap=9][n=2][prod=2][lane=64][8] bf16 --------
__global__ void prep_bimg(const float* __restrict__ w, unsigned short* __restrict__ B){
  int idx = blockIdx.x*256 + (int)threadIdx.x;
  if (idx >= 10*9*2*64*8) return;
  int j    =  idx        & 7;
  int lane = (idx >> 3)  & 63;
  int n    = (idx >> 9)  & 1;
  int r    =  idx >> 10;          // l*9 + tap
  int tap = r % 9, l = r / 9;
  int c = (lane >> 4)*8 + j;      // k = channel
  int o = n*16 + (lane & 15);     // output channel
  float x = w[(((size_t)(l*32+o)*32 + c)*9) + tap];
  unsigned short hb = f2bf(x);
  float hf = __uint_as_float((unsigned)hb << 16);
  unsigned short lb = f2bf(x - hf);
  size_t d = (size_t)l*18432 + (size_t)tap*2048 + n*1024 + lane*8 + j;
  B[d]       = hb;
  B[d + 512] = lb;
}

// ---------------- radon forward: rcp-hoisted clip ----------------
__device__ inline void clipr(float al, float ial, float be, float lo, float hi,
                             float& A, float& B, bool& empty){
  if (fabsf(al) < 1e-7f){ if (be < lo || be > hi) empty = true; return; }
  float t0 = (lo - be)*ial, t1 = (hi - be)*ial;
  float mn = fminf(t0,t1), mx = fmaxf(t0,t1);
  A = fmaxf(A, mn); B = fminf(B, mx);
}

__device__ inline float samp_guard(const float* __restrict__ base, float aR, float bR,
                                   float aC, float bC, int t){
  float tp = (float)t - 255.5f;
  float R = fmaf(aR, tp, bR);
  float C = fmaf(aC, tp, bC);
  float rf = floorf(R), cf = floorf(C);
  int r0 = (int)rf, c0 = (int)cf;
  int r1 = r0+1,    c1 = c0+1;
  float fr = R - rf, fc = C - cf;
  bool r0ok = (r0>=0 && r0<SS), r1ok = (r1>=0 && r1<SS);
  bool c0ok = (c0>=0 && c0<SS), c1ok = (c1>=0 && c1<SS);
  float v00 = (r0ok && c0ok) ? base[r0*SS+c0] : 0.f;
  float v01 = (r0ok && c1ok) ? base[r0*SS+c1] : 0.f;
  float v10 = (r1ok && c0ok) ? base[r1*SS+c0] : 0.f;
  float v11 = (r1ok && c1ok) ? base[r1*SS+c1] : 0.f;
  return (1.f-fr)*((1.f-fc)*v00 + fc*v01) + fr*((1.f-fc)*v10 + fc*v11);
}

__global__ __launch_bounds__(256) void radon_fwd_kernel(
    const float* __restrict__ img, const float* __restrict__ imgT,
    const float* __restrict__ trig, float* __restrict__ out){
  int gid  = blockIdx.x*4 + ((int)threadIdx.x >> 6);
  int lane = (int)threadIdx.x & 63;
  if (gid >= NSIN) return;
  int a = gid / DDET;
  int d = gid - a*DDET;
  float ca = trig[a], sa = trig[AANG+a];
  float sd = (float)d - 364.0f;
  float Rc = fmaf(sd, sa, 255.5f);
  float Cc = fmaf(sd, ca, 255.5f);
  float aR = ca, bR = Rc, aC = -sa, bC = Cc;
  const float* base = img;
  if (fabsf(ca) > fabsf(sa)){
    base = imgT;
    float tmp;
    tmp=aR; aR=aC; aC=tmp;
    tmp=bR; bR=bC; bC=tmp;
  }
  float iaR = __builtin_amdgcn_rcpf(aR);
  float iaC = __builtin_amdgcn_rcpf(aC);
  float tiA = -255.5f, tiB = 255.5f;  bool iE=false;
  float teA = -255.5f, teB = 255.5f;  bool eE=false;
  clipr(aR,iaR,bR, 0.001f, 510.999f, tiA,tiB,iE);
  clipr(aC,iaC,bC, 0.001f, 510.999f, tiA,tiB,iE);
  clipr(aR,iaR,bR, -0.999f, 511.999f, teA,teB,eE);
  clipr(aC,iaC,bC, -0.999f, 511.999f, teA,teB,eE);
  float acc = 0.f;
  if (!eE && teA <= teB){
    int eA = max(0,   (int)floorf(teA+255.5f) - 1);
    int eB = min(511, (int)ceilf (teB+255.5f) + 1);
    int iA = (int)ceilf (tiA+255.5f) + 1;
    int iB = (int)floorf(tiB+255.5f) - 1;
    iA = max(iA, eA); iB = min(iB, eB);
    if (iE || iA > iB){
      for (int t = eA+lane; t <= eB; t += 64) acc += samp_guard(base,aR,bR,aC,bC,t);
    } else {
      for (int t = eA+lane;   t <  iA; t += 64) acc += samp_guard(base,aR,bR,aC,bC,t);
      for (int t = iB+1+lane; t <= eB; t += 64) acc += samp_guard(base,aR,bR,aC,bC,t);
      for (int t = iA+lane;   t <= iB; t += 64){
        float tp = (float)t - 255.5f;
        float R = fmaf(aR, tp, bR);
        float C = fmaf(aC, tp, bC);
        int r0 = (int)R, c0 = (int)C;
        float fr = R - (float)r0, fc = C - (float)c0;
        const float* p = base + r0*SS + c0;
        float v00 = p[0], v01 = p[1], v10 = p[SS], v11 = p[SS+1];
        float top = v00 + fc*(v01-v00);
        float bot = v10 + fc*(v11-v10);
        acc += top + fr*(bot-top);
      }
    }
  }
  for (int off=32; off; off>>=1) acc += __shfl_down(acc, off);
  if (lane==0) out[gid] = acc;
}

// ---------------- ramp filter: 4-way k-split, 64 outputs/block ----------------
__global__ __launch_bounds__(256) void filter_kernel2(
    const float* __restrict__ h0, const float* __restrict__ taps,
    float* __restrict__ h1){
  __shared__ float red[256];
  int a  = blockIdx.x / 12;
  int jb = blockIdx.x - a*12;
  int jl = (int)threadIdx.x & 63;
  int kq = (int)threadIdx.x >> 6;
  int j  = jb*64 + jl;
  float acc = 0.f;
  if (j < DDET){
    const float* row = h0 + a*DDET;
    const float* tp  = taps + 728 + j;
    int k0 = kq*183;
    int k1 = min(k0+183, DDET);
    for (int k=k0;k<k1;k++) acc = fmaf(row[k], tp[-k], acc);
  }
  red[threadIdx.x] = acc;
  __syncthreads();
  if ((int)threadIdx.x < 64 && j < DDET){
    float s = red[jl] + red[64+jl] + red[128+jl] + red[192+jl];
    h1[a*DDET + j] = s;
  }
}

// ---------------- backprojection ----------------
__global__ __launch_bounds__(256) void backproj_kernel(
    const float* __restrict__ h1, const float* __restrict__ trig,
    float* __restrict__ out){
  __shared__ float sh[AANG*28];
  __shared__ int   sbase[AANG];
  __shared__ float strig[2*AANG];
  int tid = threadIdx.x;
  int x0 = (blockIdx.x & 31) * 16, y0 = (blockIdx.x >> 5) * 16;
  if (tid < 2*AANG) strig[tid] = trig[tid];
  __syncthreads();
  if (tid < AANG){
    float ca = strig[tid], sa = strig[AANG+tid];
    float Xa = (float)x0 - 255.5f, Xb = Xa + 15.f;
    float Ya = (float)y0 - 255.5f, Yb = Ya + 15.f;
    float s00 = Xa*ca + Ya*sa, s01 = Xb*ca + Ya*sa;
    float s10 = Xa*ca + Yb*sa, s11 = Xb*ca + Yb*sa;
    float mn = fminf(fminf(s00,s01), fminf(s10,s11)) + 364.0f;
    sbase[tid] = (int)floorf(mn) - 2;
  }
  __syncthreads();
  for (int s = tid; s < AANG*28; s += 256){
    int a = s / 28, j = s - a*28;
    int idx = sbase[a] + j;
    sh[s] = (idx >= 0 && idx < DDET) ? h1[a*DDET + idx] : 0.f;
  }
  __syncthreads();
  int x = x0 + (tid & 15), y = y0 + (tid >> 4);
  float X = (float)x - 255.5f, Y = (float)y - 255.5f;
  float acc = 0.f;
  #pragma unroll 6
  for (int a=0;a<AANG;a++){
    float sidx = fmaf(X, strig[a], fmaf(Y, strig[AANG+a], 364.0f));
    float ff = floorf(sidx);
    int k = (int)ff - sbase[a];
    float fi = sidx - ff;
    float v0 = sh[a*28+k], v1 = sh[a*28+k+1];
    acc += v0 + fi*(v1-v0);
  }
  out[y*SS+x] = acc;
}

// ---------------- dual conv cg-split (R6-proven, global weights) ----------------
__global__ __launch_bounds__(256) void conv3x3_dualcg(
    const float* __restrict__ in1, int Cin1,
    const float* __restrict__ in2, int Cin2,
    const float* __restrict__ wt,
    const float* __restrict__ bias, const float* __restrict__ prelu,
    float* __restrict__ out)
{
  const int W = DDET, HW = NSIN;
  int pix = blockIdx.x*256 + (int)threadIdx.x;
  if (pix >= NSIN) return;
  int cg = blockIdx.y;
  int y = pix / W, x = pix - y*W;
  bool ym = y>0, yp = y<AANG-1, xm = x>0, xp = x<W-1;
  float acc[8];
  #pragma unroll
  for (int o=0;o<8;o++) acc[o] = bias[cg*8+o];
  const float* wch = wt + cg*72;
  for (int part=0; part<2; part++){
    const float* src = part ? in2 : in1;
    int nch = part ? Cin2 : Cin1;
    const float* ip = src + pix;
    for (int i=0;i<nch;i++, ip+=HW, wch+=288){
      float p4 = ip[0];
      float p0=0,p1=0,p2=0,p3=0,p5=0,p6=0,p7=0,p8=0;
      if (ym){ p1 = ip[-W]; if (xm) p0 = ip[-W-1]; if (xp) p2 = ip[-W+1]; }
      if (xm) p3 = ip[-1];
      if (xp) p5 = ip[1];
      if (yp){ p7 = ip[W]; if (xm) p6 = ip[W-1]; if (xp) p8 = ip[W+1]; }
      float p[9] = {p0,p1,p2,p3,p4,p5,p6,p7,p8};
      #pragma unroll
      for (int t=0;t<9;t++){
        float v = p[t];
        #pragma unroll
        for (int o=0;o<8;o++) acc[o] = fmaf(v, wch[t*8+o], acc[o]);
      }
    }
  }
  float aa = *prelu;
  float* op = out + (size_t)(cg*8)*HW + pix;
  #pragma unroll
  for (int o=0;o<8;o++){
    float s = acc[o];
    s = (s>=0.f) ? s : aa*s;
    op[o*HW] = s;
  }
}

// ---------------- dual conv3 (32->5): 2-way channel split + LDS reduce ----------------
template<int COUT, int W>
__global__ __launch_bounds__(256) void conv3x3_fast2(
    const float* __restrict__ in1, int Cin1,
    const float* __restrict__ wt,
    const float* __restrict__ bias,
    float* __restrict__ out, int H)
{
  __shared__ float red[128*COUT];
  int HW = H*W;
  int pl = (int)threadIdx.x & 127;
  int half = (int)threadIdx.x >> 7;
  int pix = blockIdx.x*128 + pl;
  bool valid = (pix < HW);
  float acc[COUT];
  #pragma unroll
  for (int o=0;o<COUT;o++) acc[o] = 0.f;
  if (valid){
    int y = pix / W, x = pix - y*W;
    bool ym = y>0, yp = y<H-1, xm = x>0, xp = x<W-1;
    int nch = Cin1 >> 1;
    const float* wr = wt + half*nch*9*COUT;
    const float* ip = in1 + pix + (size_t)half*nch*HW;
    for (int i=0;i<nch;i++, ip+=HW){
      float p4 = ip[0];
      float p0=0,p1=0,p2=0,p3=0,p5=0,p6=0,p7=0,p8=0;
      if (ym){ p1 = ip[-W]; if (xm) p0 = ip[-W-1]; if (xp) p2 = ip[-W+1]; }
      if (xm) p3 = ip[-1];
      if (xp) p5 = ip[1];
      if (yp){ p7 = ip[W]; if (xm) p6 = ip[W-1]; if (xp) p8 = ip[W+1]; }
      float p[9] = {p0,p1,p2,p3,p4,p5,p6,p7,p8};
      #pragma unroll
      for (int t=0;t<9;t++){
        float v = p[t];
        #pragma unroll
        for (int o=0;o<COUT;o++) acc[o] = fmaf(v, wr[t*COUT+o], acc[o]);
      }
      wr += 9*COUT;
    }
  }
  if (half == 1){
    #pragma unroll
    for (int o=0;o<COUT;o++) red[pl*COUT+o] = acc[o];
  }
  __syncthreads();
  if (half == 0 && valid){
    float* op = out + pix;
    #pragma unroll
    for (int o=0;o<COUT;o++)
      op[o*HW] += acc[o] + red[pl*COUT+o] + bias[o];
  }
}

// ---------------- primal conv1 (6->32): R6 quad + NHWC bf16 hi/lo epilogue ----------------
__device__ inline void loadrow6(float* R, const float* p, bool valid, bool lE, bool rE){
  if (valid){
    v4u a = *(const v4u*)(p-1);
    v2a b = *(const v2a*)(p+3);
    R[0]=lE?0.f:a.x; R[1]=a.y; R[2]=a.z; R[3]=a.w;
    R[4]=b.x; R[5]=rE?0.f:b.y;
  } else {
    #pragma unroll
    for (int k=0;k<6;k++) R[k]=0.f;
  }
}

__global__ __launch_bounds__(256) void conv3x3_quad6(
    const float* __restrict__ in,      // 6 contiguous channels [f(5)|bp]
    const float* __restrict__ wt,      // [6][4][9][8]
    const float* __restrict__ bias, const float* __restrict__ prelu,
    unsigned short* __restrict__ outHi, unsigned short* __restrict__ outLo)
{
  const int W = SS, HW = NPIX;
  int rb = blockIdx.x;                       // 0..255 row-pairs
  int cg = blockIdx.y;                       // 0..3
  int yb = ((rb & 7) << 5) | (rb >> 3);      // XCD swizzle
  int wv = (int)threadIdx.x >> 6;
  int lane = (int)threadIdx.x & 63;
  int y = yb*2 + (wv >> 1);
  int xb = ((wv & 1) << 8) + lane*4;
  const float* wch = wt + cg*72;
  float acc[4][8];
  #pragma unroll
  for (int px=0;px<4;px++)
    #pragma unroll
    for (int o=0;o<8;o++) acc[px][o] = 0.f;
  bool ym = y>0, yp = y<SS-1;
  bool lE = (xb==0), rE = (xb==508);
  const float* ip = in + y*W + xb;
  for (int i=0;i<6;i++, ip+=HW, wch+=288){
    float R[3][6];
    loadrow6(R[0], ip - W, ym,   lE, rE);
    loadrow6(R[1], ip,     true, lE, rE);
    loadrow6(R[2], ip + W, yp,   lE, rE);
    #pragma unroll
    for (int dy=0;dy<3;dy++){
      #pragma unroll
      for (int dx=0;dx<3;dx++){
        #pragma unroll
        for (int o=0;o<8;o++){
          float w = wch[(dy*3+dx)*8+o];
          #pragma unroll
          for (int px=0;px<4;px++)
            acc[px][o] = fmaf(R[dy][px+dx], w, acc[px][o]);
        }
      }
    }
  }
  float aa = *prelu;
  #pragma unroll
  for (int px=0;px<4;px++){
    short8 vh, vl;
    #pragma unroll
    for (int o=0;o<8;o++){
      float s = acc[px][o] + bias[cg*8+o];
      s = (s>=0.f) ? s : aa*s;
      unsigned short hb = f2bf(s);
      float hf = __uint_as_float((unsigned)hb << 16);
      unsigned short lb = f2bf(s - hf);
      vh[o] = (short)hb; vl[o] = (short)lb;
    }
    size_t base = ((size_t)(y*W + xb + px))*32 + cg*8;
    *(short8*)(outHi + base) = vh;
    *(short8*)(outLo + base) = vl;
  }
}

// ---------------- primal conv2 (32->32): implicit-GEMM MFMA bf16 hi/lo ----------------
__global__ __launch_bounds__(256) void conv_mfma32(
    const unsigned short* __restrict__ hiB, const unsigned short* __restrict__ loB,
    const unsigned short* __restrict__ Bimg,   // this layer: [9][2][2][64][8]
    const float* __restrict__ bias, const float* __restrict__ prelu,
    float* __restrict__ out)
{
  int b = blockIdx.x;                 // 0..1023
  int by = b >> 1, half = b & 1;
  int y = ((by & 7) << 6) | (by >> 3);   // XCD row swizzle
  int wv = (int)threadIdx.x >> 6;
  int lane = (int)threadIdx.x & 63;
  int xw = half*256 + wv*64;
  int lm = lane & 15, lq = lane >> 4;
  int laneoff = lm*32 + lq*8;
  f32x4 acc[4][2];
  #pragma unroll
  for (int s=0;s<4;s++){ acc[s][0] = (f32x4)0.f; acc[s][1] = (f32x4)0.f; }
  bool fastx = (xw != 0) && (xw != 448);
  const short8* Bf = (const short8*)Bimg;
  #pragma unroll
  for (int dy=-1; dy<=1; dy++){
    int yy = y + dy;
    if ((unsigned)yy >= 512u) continue;
    const unsigned short* rh = hiB + (size_t)yy*512*32;
    const unsigned short* rl = loB + (size_t)yy*512*32;
    #pragma unroll
    for (int dx=-1; dx<=1; dx++){
      int tap = (dy+1)*3 + (dx+1);
      const short8* bp8 = Bf + tap*256 + lane;
      short8 bh0 = bp8[0];     // n=0 hi
      short8 bl0 = bp8[64];    // n=0 lo
      short8 bh1 = bp8[128];   // n=1 hi
      short8 bl1 = bp8[192];   // n=1 lo
      int xoff = (xw + dx)*32 + laneoff;
      #pragma unroll
      for (int s=0; s<4; s++){
        short8 ah, al;
        const unsigned short* ph = rh + xoff + s*512;
        const unsigned short* pl = rl + xoff + s*512;
        if (fastx){
          ah = *(const short8*)ph;
          al = *(const short8*)pl;
        } else {
          int x = xw + s*16 + lm + dx;
          bool ok = ((unsigned)x < 512u);
          ah = ok ? *(const short8*)ph : (short8)0;
          al = ok ? *(const short8*)pl : (short8)0;
        }
        acc[s][0] = __builtin_amdgcn_mfma_f32_16x16x32_bf16(ah, bh0, acc[s][0], 0,0,0);
        acc[s][1] = __builtin_amdgcn_mfma_f32_16x16x32_bf16(ah, bh1, acc[s][1], 0,0,0);
        acc[s][0] = __builtin_amdgcn_mfma_f32_16x16x32_bf16(al, bh0, acc[s][0], 0,0,0);
        acc[s][1] = __builtin_amdgcn_mfma_f32_16x16x32_bf16(al, bh1, acc[s][1], 0,0,0);
        acc[s][0] = __builtin_amdgcn_mfma_f32_16x16x32_bf16(ah, bl0, acc[s][0], 0,0,0);
        acc[s][1] = __builtin_amdgcn_mfma_f32_16x16x32_bf16(ah, bl1, acc[s][1], 0,0,0);
      }
    }
  }
  // epilogue: bias + prelu + planar fp32 store
  float aa = *prelu;
  #pragma unroll
  for (int s=0;s<4;s++){
    #pragma unroll
    for (int n=0;n<2;n++){
      int o = n*16 + lm;
      float bv = bias[o];
      f32x4 v = acc[s][n];
      v.x+=bv; v.y+=bv; v.z+=bv; v.w+=bv;
      v.x=(v.x>=0.f)?v.x:aa*v.x; v.y=(v.y>=0.f)?v.y:aa*v.y;
      v.z=(v.z>=0.f)?v.z:aa*v.z; v.w=(v.w>=0.f)?v.w:aa*v.w;
      *(f32x4*)(out + (size_t)o*NPIX + y*SS + xw + s*16 + lq*4) = v;
    }
  }
}

// ---------------- primal conv3 (32->5): one row per block, 2 px/thread ----------------
template<int COUT>
__global__ __launch_bounds__(256) void conv3x3_duo(
    const float* __restrict__ in1, int Cin1,
    const float* __restrict__ wt,
    const float* __restrict__ bias,
    float* __restrict__ out,
    float* __restrict__ fout, float* __restrict__ tout)
{
  const int W = SS, HW = NPIX;
  int b = blockIdx.x;
  int y = ((b & 7) << 6) | (b >> 3);
  int x0 = (int)threadIdx.x * 2;
  int pix0 = y*W + x0;
  bool ym = y > 0, yp = y < SS-1;
  bool l0 = x0 > 0;
  bool r3 = x0 + 2 < W;
  float acc0[COUT], acc1[COUT];
  #pragma unroll
  for (int o=0;o<COUT;o++){ float bv = bias[o]; acc0[o]=bv; acc1[o]=bv; }
  const float* wr = wt;
  const float* ip = in1 + pix0;
  #pragma unroll 2
  for (int i=0;i<Cin1;i++, ip+=HW){
    v4u A = ym ? *(const v4u*)(ip - W - 1) : (v4u)0.f;
    v4u B = *(const v4u*)(ip - 1);
    v4u D = yp ? *(const v4u*)(ip + W - 1) : (v4u)0.f;
    if (!l0){ A.x = 0.f; B.x = 0.f; D.x = 0.f; }
    if (!r3){ A.w = 0.f; B.w = 0.f; D.w = 0.f; }
    float w0[9] = {A.x,A.y,A.z, B.x,B.y,B.z, D.x,D.y,D.z};
    float w1[9] = {A.y,A.z,A.w, B.y,B.z,B.w, D.y,D.z,D.w};
    #pragma unroll
    for (int t=0;t<9;t++){
      float v0 = w0[t], v1 = w1[t];
      #pragma unroll
      for (int o=0;o<COUT;o++){
        float w = wr[t*COUT+o];
        acc0[o] = fmaf(v0, w, acc0[o]);
        acc1[o] = fmaf(v1, w, acc1[o]);
      }
    }
    wr += 9*COUT;
  }
  float* op = out + pix0;
  #pragma unroll
  for (int o=0;o<COUT;o++){
    float s0 = acc0[o], s1 = acc1[o];
    v2u old = *(const v2u*)(op + o*HW);
    s0 += old.x; s1 += old.y;
    v2u st; st.x = s0; st.y = s1;
    *(v2u*)(op + o*HW) = st;
    if (o==1 && tout){ tout[x0*SS + y] = s0; tout[(x0+1)*SS + y] = s1; }
    if (o==0 && fout){
      *(v2u*)(fout + pix0) = st;
      *(v2u*)(fout + HW + pix0) = st;
      *(v2u*)(fout + 2*HW + pix0) = st;
    }
  }
}

extern "C" void kernel_launch(void* const* d_in, const int* in_sizes, int n_in,
                              void* d_out, int out_size, void* d_ws, size_t ws_size,
                              hipStream_t stream){
  const float* g     = (const float*)d_in[2];
  const float* theta = (const float*)d_in[3];
  const float* dw1 = (const float*)d_in[5];
  const float* db1 = (const float*)d_in[6];
  const float* da1 = (const float*)d_in[7];
  const float* dw2 = (const float*)d_in[8];
  const float* db2 = (const float*)d_in[9];
  const float* da2 = (const float*)d_in[10];
  const float* dw3 = (const float*)d_in[11];
  const float* db3 = (const float*)d_in[12];
  const float* pw1 = (const float*)d_in[13];
  const float* pb1 = (const float*)d_in[14];
  const float* pa1 = (const float*)d_in[15];
  const float* pw2 = (const float*)d_in[16];
  const float* pb2 = (const float*)d_in[17];
  const float* pa2 = (const float*)d_in[18];
  const float* pw3 = (const float*)d_in[19];
  const float* pb3 = (const float*)d_in[20];

  float* ws     = (float*)d_ws;
  float* trig   = ws;                    // 128
  float* taps   = ws + 128;              // -> 2048
  float* h      = ws + 2048;             // 5*NSIN
  float* opf    = h + 5*NSIN;            // NSIN
  float* gcopy  = opf + NSIN;            // NSIN
  float* h1     = gcopy + NSIN;          // NSIN
  float* f      = h1 + NSIN;             // 5*NPIX
  float* bp     = f + 5*NPIX;            // NPIX
  float* imgT   = bp + NPIX;             // NPIX
  float* dualT1 = imgT + NPIX;           // 32*NSIN
  float* dualT2 = dualT1 + 32*NSIN;      // 32*NSIN
  float* primT2 = dualT2 + 32*NSIN;      // 32*NPIX
  unsigned short* nhwcHi = (unsigned short*)(primT2 + 32*NPIX);  // 32*NPIX ushorts
  unsigned short* nhwcLo = nhwcHi + (size_t)32*NPIX;             // 32*NPIX ushorts
  float* wsp   = (float*)(nhwcLo + (size_t)32*NPIX);
  float* wtd3  = wsp;                    // 14400
  float* wtp3  = wsp + 14400;            // 14400
  float* wtd1b = wsp + 28800;            // 20160
  float* wtd2b = wsp + 48960;            // 92160
  float* wtp1b = wsp + 141120;           // 17280
  unsigned short* Bimg = (unsigned short*)(wsp + 158400);  // 184320 ushorts

  hipMemsetAsync(h, 0, (size_t)(5*NSIN)*sizeof(float), stream);
  hipMemsetAsync(f, 0, (size_t)(7*NPIX)*sizeof(float), stream);   // f, bp, imgT
  hipMemcpyAsync(gcopy, g, (size_t)NSIN*sizeof(float), hipMemcpyDeviceToDevice, stream);
  trig_kernel<<<1,64,0,stream>>>(theta, trig);
  taps_kernel<<<NTAPS,256,0,stream>>>(taps);
  transpose_all<<<(28800+255)/256,256,0,stream>>>(dw3,wtd3, pw3,wtp3);
  transpose_w8<<<(20160+255)/256,256,0,stream>>>(dw1, wtd1b, 7);
  transpose_w8<<<(92160+255)/256,256,0,stream>>>(dw2, wtd2b, 32);
  transpose_w8<<<(17280+255)/256,256,0,stream>>>(pw1, wtp1b, 6);
  prep_bimg<<<(92160+255)/256,256,0,stream>>>(pw2, Bimg);

  const int GD = (NSIN+255)/256;       // 171

  for (int i=0;i<10;i++){
    radon_fwd_kernel<<<(NSIN+3)/4,256,0,stream>>>(f + NPIX, imgT, trig, opf);
    // dual block: in = [h(5) | opf | g] (opf,gcopy contiguous after h)
    conv3x3_dualcg<<<dim3(GD,4),256,0,stream>>>(h, 5, opf, 2,      wtd1b+(size_t)i*7*288,  db1+(size_t)i*32, da1+i, dualT1);
    conv3x3_dualcg<<<dim3(GD,4),256,0,stream>>>(dualT1, 32, nullptr, 0, wtd2b+(size_t)i*32*288, db2+(size_t)i*32, da2+i, dualT2);
    conv3x3_fast2<5,DDET><<<(NSIN+127)/128,256,0,stream>>>(dualT2, 32, wtd3+i*1440, db3+(size_t)i*5, h, AANG);
    filter_kernel2<<<AANG*12,256,0,stream>>>(h, taps, h1);
    backproj_kernel<<<NPIX/256,256,0,stream>>>(h1, trig, bp);
    // primal block: in = [f(5) | bp] contiguous
    conv3x3_quad6<<<dim3(256,4),256,0,stream>>>(f, wtp1b+(size_t)i*6*288, pb1+(size_t)i*32, pa1+i, nhwcHi, nhwcLo);
    conv_mfma32<<<1024,256,0,stream>>>(nhwcHi, nhwcLo, Bimg+(size_t)i*18432, pb2+(size_t)i*32, pa2+i, primT2);
    conv3x3_duo<5><<<SS,256,0,stream>>>(primT2, 32, wtp3+i*1440, pb3+(size_t)i*5, f,
                                        (i==9) ? (float*)d_out : nullptr, imgT);
  }
}

// Round 3
// 2152.797 us; speedup vs baseline: 1.0770x; 1.0331x over previous
//
#include <hip/hip_runtime.h>
#include <math.h>

#define SS 512
#define AANG 60
#define DDET 729
#define NPIX (SS*SS)        // 262144
#define NSIN (AANG*DDET)    // 43740
#define NTAPS 1457
#define DRS 768             // dual NHWC padded row stride

typedef float v4u __attribute__((ext_vector_type(4), aligned(4)));
typedef float v4a __attribute__((ext_vector_type(4), aligned(16)));
typedef float v2u __attribute__((ext_vector_type(2), aligned(8)));
typedef float v2a __attribute__((ext_vector_type(2), aligned(4)));
typedef short short8 __attribute__((ext_vector_type(8)));
typedef float f32x4 __attribute__((ext_vector_type(4)));

// round-to-nearest-even fp32 -> bf16 bits
__device__ inline unsigned short f2bf(float x){
  unsigned u = __float_as_uint(x);
  return (unsigned short)((u + 0x7fffu + ((u >> 16) & 1u)) >> 16);
}

// ---------------- trig table ----------------
__global__ void trig_kernel(const float* __restrict__ theta, float* __restrict__ trig){
  int a = threadIdx.x;
  if (a < AANG){ trig[a] = cosf(theta[a]); trig[AANG+a] = sinf(theta[a]); }
}

// ---------------- ramp-filter taps ----------------
__global__ void taps_kernel(float* __restrict__ taps){
  __shared__ double red[256];
  int m  = blockIdx.x;
  int mm = m - 728;
  double s = 0.0;
  for (int k = 1 + (int)threadIdx.x; k <= 1023; k += 256){
    int phase = (k*mm) & 2047;
    s += (double)k * cos((double)phase * (M_PI/1024.0));
  }
  red[threadIdx.x] = s;
  __syncthreads();
  for (int off=128; off; off>>=1){
    if ((int)threadIdx.x < off) red[threadIdx.x] += red[threadIdx.x+off];
    __syncthreads();
  }
  if (threadIdx.x==0){
    double x = (red[0]*(1.0/512.0) + ((mm & 1) ? -1.0 : 1.0)) / 2048.0;
    taps[m] = (float)(x * (M_PI/120.0));
  }
}

// ---------------- conv3 weight transposes: -> [L][Cin][9][5] ----------------
__global__ void transpose_all(const float* __restrict__ s2, float* __restrict__ d2,
                              const float* __restrict__ s5, float* __restrict__ d5){
  int idx = blockIdx.x*256 + (int)threadIdx.x;
  const float* src; float* dst;
  int Cout = 5, Cin = 32;
  if      (idx < 14400){              src=s2; dst=d2; }
  else if (idx < 28800){ idx-=14400;  src=s5; dst=d5; }
  else return;
  int t = idx % 9; int r = idx/9;
  int i = r % Cin; r /= Cin;
  int o = r % Cout; int l = r/Cout;
  dst[((l*Cin+i)*9+t)*Cout+o] = src[idx];
}

// ---------------- cg-split re-layout: [L][32][Cin][3][3] -> [L][Cin][4][9][8] ----------
__global__ void transpose_w8(const float* __restrict__ src, float* __restrict__ dst, int Cin){
  int idx = blockIdx.x*256 + (int)threadIdx.x;
  int tot = 10*32*Cin*9;
  if (idx >= tot) return;
  int t = idx % 9; int r = idx/9;
  int i = r % Cin; r /= Cin;
  int o = r % 32; int l = r/32;
  int cg = o >> 3, u = o & 7;
  dst[(((l*Cin + i)*4 + cg)*9 + t)*8 + u] = src[idx];
}

// -------- MFMA B-fragment image: [L][tap=9][n=2][prod=2][lane=64][8] bf16 --------
// works for any [L][32][32][3][3] weight tensor (pw2 and dw2)
__global__ void prep_bimg(const float* __restrict__ w, unsigned short* __restrict__ B){
  int idx = blockIdx.x*256 + (int)threadIdx.x;
  if (idx >= 10*9*2*64*8) return;
  int j    =  idx        & 7;
  int lane = (idx >> 3)  & 63;
  int n    = (idx >> 9)  & 1;
  int r    =  idx >> 10;          // l*9 + tap
  int tap = r % 9, l = r / 9;
  int c = (lane >> 4)*8 + j;      // k = channel
  int o = n*16 + (lane & 15);     // output channel
  float x = w[(((size_t)(l*32+o)*32 + c)*9) + tap];
  unsigned short hb = f2bf(x);
  float hf = __uint_as_float((unsigned)hb << 16);
  unsigned short lb = f2bf(x - hf);
  size_t d = (size_t)l*18432 + (size_t)tap*2048 + n*1024 + lane*8 + j;
  B[d]       = hb;
  B[d + 512] = lb;
}

// ---------------- radon forward: rcp-hoisted clip ----------------
__device__ inline void clipr(float al, float ial, float be, float lo, float hi,
                             float& A, float& B, bool& empty){
  if (fabsf(al) < 1e-7f){ if (be < lo || be > hi) empty = true; return; }
  float t0 = (lo - be)*ial, t1 = (hi - be)*ial;
  float mn = fminf(t0,t1), mx = fmaxf(t0,t1);
  A = fmaxf(A, mn); B = fminf(B, mx);
}

__device__ inline float samp_guard(const float* __restrict__ base, float aR, float bR,
                                   float aC, float bC, int t){
  float tp = (float)t - 255.5f;
  float R = fmaf(aR, tp, bR);
  float C = fmaf(aC, tp, bC);
  float rf = floorf(R), cf = floorf(C);
  int r0 = (int)rf, c0 = (int)cf;
  int r1 = r0+1,    c1 = c0+1;
  float fr = R - rf, fc = C - cf;
  bool r0ok = (r0>=0 && r0<SS), r1ok = (r1>=0 && r1<SS);
  bool c0ok = (c0>=0 && c0<SS), c1ok = (c1>=0 && c1<SS);
  float v00 = (r0ok && c0ok) ? base[r0*SS+c0] : 0.f;
  float v01 = (r0ok && c1ok) ? base[r0*SS+c1] : 0.f;
  float v10 = (r1ok && c0ok) ? base[r1*SS+c0] : 0.f;
  float v11 = (r1ok && c1ok) ? base[r1*SS+c1] : 0.f;
  return (1.f-fr)*((1.f-fc)*v00 + fc*v01) + fr*((1.f-fc)*v10 + fc*v11);
}

__global__ __launch_bounds__(256) void radon_fwd_kernel(
    const float* __restrict__ img, const float* __restrict__ imgT,
    const float* __restrict__ trig, float* __restrict__ out){
  int gid  = blockIdx.x*4 + ((int)threadIdx.x >> 6);
  int lane = (int)threadIdx.x & 63;
  if (gid >= NSIN) return;
  int a = gid / DDET;
  int d = gid - a*DDET;
  float ca = trig[a], sa = trig[AANG+a];
  float sd = (float)d - 364.0f;
  float Rc = fmaf(sd, sa, 255.5f);
  float Cc = fmaf(sd, ca, 255.5f);
  float aR = ca, bR = Rc, aC = -sa, bC = Cc;
  const float* base = img;
  if (fabsf(ca) > fabsf(sa)){
    base = imgT;
    float tmp;
    tmp=aR; aR=aC; aC=tmp;
    tmp=bR; bR=bC; bC=tmp;
  }
  float iaR = __builtin_amdgcn_rcpf(aR);
  float iaC = __builtin_amdgcn_rcpf(aC);
  float tiA = -255.5f, tiB = 255.5f;  bool iE=false;
  float teA = -255.5f, teB = 255.5f;  bool eE=false;
  clipr(aR,iaR,bR, 0.001f, 510.999f, tiA,tiB,iE);
  clipr(aC,iaC,bC, 0.001f, 510.999f, tiA,tiB,iE);
  clipr(aR,iaR,bR, -0.999f, 511.999f, teA,teB,eE);
  clipr(aC,iaC,bC, -0.999f, 511.999f, teA,teB,eE);
  float acc = 0.f;
  if (!eE && teA <= teB){
    int eA = max(0,   (int)floorf(teA+255.5f) - 1);
    int eB = min(511, (int)ceilf (teB+255.5f) + 1);
    int iA = (int)ceilf (tiA+255.5f) + 1;
    int iB = (int)floorf(tiB+255.5f) - 1;
    iA = max(iA, eA); iB = min(iB, eB);
    if (iE || iA > iB){
      for (int t = eA+lane; t <= eB; t += 64) acc += samp_guard(base,aR,bR,aC,bC,t);
    } else {
      for (int t = eA+lane;   t <  iA; t += 64) acc += samp_guard(base,aR,bR,aC,bC,t);
      for (int t = iB+1+lane; t <= eB; t += 64) acc += samp_guard(base,aR,bR,aC,bC,t);
      for (int t = iA+lane;   t <= iB; t += 64){
        float tp = (float)t - 255.5f;
        float R = fmaf(aR, tp, bR);
        float C = fmaf(aC, tp, bC);
        int r0 = (int)R, c0 = (int)C;
        float fr = R - (float)r0, fc = C - (float)c0;
        const float* p = base + r0*SS + c0;
        float v00 = p[0], v01 = p[1], v10 = p[SS], v11 = p[SS+1];
        float top = v00 + fc*(v01-v00);
        float bot = v10 + fc*(v11-v10);
        acc += top + fr*(bot-top);
      }
    }
  }
  for (int off=32; off; off>>=1) acc += __shfl_down(acc, off);
  if (lane==0) out[gid] = acc;
}

// ---------------- ramp filter: 4-way k-split, 64 outputs/block ----------------
__global__ __launch_bounds__(256) void filter_kernel2(
    const float* __restrict__ h0, const float* __restrict__ taps,
    float* __restrict__ h1){
  __shared__ float red[256];
  int a  = blockIdx.x / 12;
  int jb = blockIdx.x - a*12;
  int jl = (int)threadIdx.x & 63;
  int kq = (int)threadIdx.x >> 6;
  int j  = jb*64 + jl;
  float acc = 0.f;
  if (j < DDET){
    const float* row = h0 + a*DDET;
    const float* tp  = taps + 728 + j;
    int k0 = kq*183;
    int k1 = min(k0+183, DDET);
    for (int k=k0;k<k1;k++) acc = fmaf(row[k], tp[-k], acc);
  }
  red[threadIdx.x] = acc;
  __syncthreads();
  if ((int)threadIdx.x < 64 && j < DDET){
    float s = red[jl] + red[64+jl] + red[128+jl] + red[192+jl];
    h1[a*DDET + j] = s;
  }
}

// ---------------- backprojection ----------------
__global__ __launch_bounds__(256) void backproj_kernel(
    const float* __restrict__ h1, const float* __restrict__ trig,
    float* __restrict__ out){
  __shared__ float sh[AANG*28];
  __shared__ int   sbase[AANG];
  __shared__ float strig[2*AANG];
  int tid = threadIdx.x;
  int x0 = (blockIdx.x & 31) * 16, y0 = (blockIdx.x >> 5) * 16;
  if (tid < 2*AANG) strig[tid] = trig[tid];
  __syncthreads();
  if (tid < AANG){
    float ca = strig[tid], sa = strig[AANG+tid];
    float Xa = (float)x0 - 255.5f, Xb = Xa + 15.f;
    float Ya = (float)y0 - 255.5f, Yb = Ya + 15.f;
    float s00 = Xa*ca + Ya*sa, s01 = Xb*ca + Ya*sa;
    float s10 = Xa*ca + Yb*sa, s11 = Xb*ca + Yb*sa;
    float mn = fminf(fminf(s00,s01), fminf(s10,s11)) + 364.0f;
    sbase[tid] = (int)floorf(mn) - 2;
  }
  __syncthreads();
  for (int s = tid; s < AANG*28; s += 256){
    int a = s / 28, j = s - a*28;
    int idx = sbase[a] + j;
    sh[s] = (idx >= 0 && idx < DDET) ? h1[a*DDET + idx] : 0.f;
  }
  __syncthreads();
  int x = x0 + (tid & 15), y = y0 + (tid >> 4);
  float X = (float)x - 255.5f, Y = (float)y - 255.5f;
  float acc = 0.f;
  #pragma unroll 6
  for (int a=0;a<AANG;a++){
    float sidx = fmaf(X, strig[a], fmaf(Y, strig[AANG+a], 364.0f));
    float ff = floorf(sidx);
    int k = (int)ff - sbase[a];
    float fi = sidx - ff;
    float v0 = sh[a*28+k], v1 = sh[a*28+k+1];
    acc += v0 + fi*(v1-v0);
  }
  out[y*SS+x] = acc;
}

// ---------------- dual conv1 (7->32): cg-split scalar + NHWC bf16 hi/lo epilogue ----
// outputs NHWC [62 rows x DRS x 32] with +1 guard-row offset (row y at y+1)
__global__ __launch_bounds__(256) void conv3x3_dual1(
    const float* __restrict__ in1, int Cin1,
    const float* __restrict__ in2, int Cin2,
    const float* __restrict__ wt,
    const float* __restrict__ bias, const float* __restrict__ prelu,
    unsigned short* __restrict__ outHi, unsigned short* __restrict__ outLo)
{
  const int W = DDET, HW = NSIN;
  int pix = blockIdx.x*256 + (int)threadIdx.x;
  if (pix >= NSIN) return;
  int cg = blockIdx.y;
  int y = pix / W, x = pix - y*W;
  bool ym = y>0, yp = y<AANG-1, xm = x>0, xp = x<W-1;
  float acc[8];
  #pragma unroll
  for (int o=0;o<8;o++) acc[o] = bias[cg*8+o];
  const float* wch = wt + cg*72;
  for (int part=0; part<2; part++){
    const float* src = part ? in2 : in1;
    int nch = part ? Cin2 : Cin1;
    const float* ip = src + pix;
    for (int i=0;i<nch;i++, ip+=HW, wch+=288){
      float p4 = ip[0];
      float p0=0,p1=0,p2=0,p3=0,p5=0,p6=0,p7=0,p8=0;
      if (ym){ p1 = ip[-W]; if (xm) p0 = ip[-W-1]; if (xp) p2 = ip[-W+1]; }
      if (xm) p3 = ip[-1];
      if (xp) p5 = ip[1];
      if (yp){ p7 = ip[W]; if (xm) p6 = ip[W-1]; if (xp) p8 = ip[W+1]; }
      float p[9] = {p0,p1,p2,p3,p4,p5,p6,p7,p8};
      #pragma unroll
      for (int t=0;t<9;t++){
        float v = p[t];
        #pragma unroll
        for (int o=0;o<8;o++) acc[o] = fmaf(v, wch[t*8+o], acc[o]);
      }
    }
  }
  float aa = *prelu;
  short8 vh, vl;
  #pragma unroll
  for (int o=0;o<8;o++){
    float s = acc[o];
    s = (s>=0.f) ? s : aa*s;
    unsigned short hb = f2bf(s);
    float hf = __uint_as_float((unsigned)hb << 16);
    unsigned short lb = f2bf(s - hf);
    vh[o] = (short)hb; vl[o] = (short)lb;
  }
  size_t base = ((size_t)(y+1)*DRS + x)*32 + cg*8;
  *(short8*)(outHi + base) = vh;
  *(short8*)(outLo + base) = vl;
}

// ---------------- dual conv2 (32->32): implicit-GEMM MFMA bf16 hi/lo ----------------
// NHWC input padded to DRS with zero guard rows/pads: all loads unguarded.
__global__ __launch_bounds__(256) void dual_mfma32(
    const unsigned short* __restrict__ hiB, const unsigned short* __restrict__ loB,
    const unsigned short* __restrict__ Bimg,   // this layer: [9][2][2][64][8]
    const float* __restrict__ bias, const float* __restrict__ prelu,
    float* __restrict__ out)
{
  int y  = blockIdx.y;                               // 0..59
  int wv = (int)threadIdx.x >> 6;
  int lane = (int)threadIdx.x & 63;
  int xw = blockIdx.x*256 + wv*64;                   // 0..704 step 64
  int lm = lane & 15, lq = lane >> 4;
  int laneoff = lm*32 + lq*8;
  f32x4 acc[4][2];
  #pragma unroll
  for (int s=0;s<4;s++){ acc[s][0] = (f32x4)0.f; acc[s][1] = (f32x4)0.f; }
  const short8* Bf = (const short8*)Bimg;
  #pragma unroll
  for (int dy=-1; dy<=1; dy++){
    const unsigned short* rh = hiB + (size_t)(y+dy+1)*DRS*32;
    const unsigned short* rl = loB + (size_t)(y+dy+1)*DRS*32;
    #pragma unroll
    for (int dx=-1; dx<=1; dx++){
      int tap = (dy+1)*3 + (dx+1);
      const short8* bp8 = Bf + tap*256 + lane;
      short8 bh0 = bp8[0];     // n=0 hi
      short8 bl0 = bp8[64];    // n=0 lo
      short8 bh1 = bp8[128];   // n=1 hi
      short8 bl1 = bp8[192];   // n=1 lo
      int xoff = (xw + dx)*32 + laneoff;
      #pragma unroll
      for (int s=0; s<4; s++){
        short8 ah = *(const short8*)(rh + xoff + s*512);
        short8 al = *(const short8*)(rl + xoff + s*512);
        acc[s][0] = __builtin_amdgcn_mfma_f32_16x16x32_bf16(ah, bh0, acc[s][0], 0,0,0);
        acc[s][1] = __builtin_amdgcn_mfma_f32_16x16x32_bf16(ah, bh1, acc[s][1], 0,0,0);
        acc[s][0] = __builtin_amdgcn_mfma_f32_16x16x32_bf16(al, bh0, acc[s][0], 0,0,0);
        acc[s][1] = __builtin_amdgcn_mfma_f32_16x16x32_bf16(al, bh1, acc[s][1], 0,0,0);
        acc[s][0] = __builtin_amdgcn_mfma_f32_16x16x32_bf16(ah, bl0, acc[s][0], 0,0,0);
        acc[s][1] = __builtin_amdgcn_mfma_f32_16x16x32_bf16(ah, bl1, acc[s][1], 0,0,0);
      }
    }
  }
  // epilogue: bias + prelu + planar fp32 store (4B-aligned: 729 stride is odd)
  float aa = *prelu;
  #pragma unroll
  for (int s=0;s<4;s++){
    int px0 = xw + s*16 + lq*4;
    #pragma unroll
    for (int n=0;n<2;n++){
      int o = n*16 + lm;
      float bv = bias[o];
      f32x4 v = acc[s][n];
      v.x+=bv; v.y+=bv; v.z+=bv; v.w+=bv;
      v.x=(v.x>=0.f)?v.x:aa*v.x; v.y=(v.y>=0.f)?v.y:aa*v.y;
      v.z=(v.z>=0.f)?v.z:aa*v.z; v.w=(v.w>=0.f)?v.w:aa*v.w;
      float* op = out + (size_t)o*NSIN + y*DDET + px0;
      if (px0 + 3 <= DDET-1){
        v4u st; st.x=v.x; st.y=v.y; st.z=v.z; st.w=v.w;
        *(v4u*)op = st;
      } else {
        if (px0   <= DDET-1) op[0] = v.x;
        if (px0+1 <= DDET-1) op[1] = v.y;
        if (px0+2 <= DDET-1) op[2] = v.z;
      }
    }
  }
}

// ---------------- dual conv3 (32->5): 2-way channel split + LDS reduce ----------------
template<int COUT, int W>
__global__ __launch_bounds__(256) void conv3x3_fast2(
    const float* __restrict__ in1, int Cin1,
    const float* __restrict__ wt,
    const float* __restrict__ bias,
    float* __restrict__ out, int H)
{
  __shared__ float red[128*COUT];
  int HW = H*W;
  int pl = (int)threadIdx.x & 127;
  int half = (int)threadIdx.x >> 7;
  int pix = blockIdx.x*128 + pl;
  bool valid = (pix < HW);
  float acc[COUT];
  #pragma unroll
  for (int o=0;o<COUT;o++) acc[o] = 0.f;
  if (valid){
    int y = pix / W, x = pix - y*W;
    bool ym = y>0, yp = y<H-1, xm = x>0, xp = x<W-1;
    int nch = Cin1 >> 1;
    const float* wr = wt + half*nch*9*COUT;
    const float* ip = in1 + pix + (size_t)half*nch*HW;
    for (int i=0;i<nch;i++, ip+=HW){
      float p4 = ip[0];
      float p0=0,p1=0,p2=0,p3=0,p5=0,p6=0,p7=0,p8=0;
      if (ym){ p1 = ip[-W]; if (xm) p0 = ip[-W-1]; if (xp) p2 = ip[-W+1]; }
      if (xm) p3 = ip[-1];
      if (xp) p5 = ip[1];
      if (yp){ p7 = ip[W]; if (xm) p6 = ip[W-1]; if (xp) p8 = ip[W+1]; }
      float p[9] = {p0,p1,p2,p3,p4,p5,p6,p7,p8};
      #pragma unroll
      for (int t=0;t<9;t++){
        float v = p[t];
        #pragma unroll
        for (int o=0;o<COUT;o++) acc[o] = fmaf(v, wr[t*COUT+o], acc[o]);
      }
      wr += 9*COUT;
    }
  }
  if (half == 1){
    #pragma unroll
    for (int o=0;o<COUT;o++) red[pl*COUT+o] = acc[o];
  }
  __syncthreads();
  if (half == 0 && valid){
    float* op = out + pix;
    #pragma unroll
    for (int o=0;o<COUT;o++)
      op[o*HW] += acc[o] + red[pl*COUT+o] + bias[o];
  }
}

// ---------------- primal conv1 (6->32): R6 quad + NHWC bf16 hi/lo epilogue ----------------
__device__ inline void loadrow6(float* R, const float* p, bool valid, bool lE, bool rE){
  if (valid){
    v4u a = *(const v4u*)(p-1);
    v2a b = *(const v2a*)(p+3);
    R[0]=lE?0.f:a.x; R[1]=a.y; R[2]=a.z; R[3]=a.w;
    R[4]=b.x; R[5]=rE?0.f:b.y;
  } else {
    #pragma unroll
    for (int k=0;k<6;k++) R[k]=0.f;
  }
}

__global__ __launch_bounds__(256) void conv3x3_quad6(
    const float* __restrict__ in,      // 6 contiguous channels [f(5)|bp]
    const float* __restrict__ wt,      // [6][4][9][8]
    const float* __restrict__ bias, const float* __restrict__ prelu,
    unsigned short* __restrict__ outHi, unsigned short* __restrict__ outLo)
{
  const int W = SS, HW = NPIX;
  int rb = blockIdx.x;                       // 0..255 row-pairs
  int cg = blockIdx.y;                       // 0..3
  int yb = ((rb & 7) << 5) | (rb >> 3);      // XCD swizzle
  int wv = (int)threadIdx.x >> 6;
  int lane = (int)threadIdx.x & 63;
  int y = yb*2 + (wv >> 1);
  int xb = ((wv & 1) << 8) + lane*4;
  const float* wch = wt + cg*72;
  float acc[4][8];
  #pragma unroll
  for (int px=0;px<4;px++)
    #pragma unroll
    for (int o=0;o<8;o++) acc[px][o] = 0.f;
  bool ym = y>0, yp = y<SS-1;
  bool lE = (xb==0), rE = (xb==508);
  const float* ip = in + y*W + xb;
  for (int i=0;i<6;i++, ip+=HW, wch+=288){
    float R[3][6];
    loadrow6(R[0], ip - W, ym,   lE, rE);
    loadrow6(R[1], ip,     true, lE, rE);
    loadrow6(R[2], ip + W, yp,   lE, rE);
    #pragma unroll
    for (int dy=0;dy<3;dy++){
      #pragma unroll
      for (int dx=0;dx<3;dx++){
        #pragma unroll
        for (int o=0;o<8;o++){
          float w = wch[(dy*3+dx)*8+o];
          #pragma unroll
          for (int px=0;px<4;px++)
            acc[px][o] = fmaf(R[dy][px+dx], w, acc[px][o]);
        }
      }
    }
  }
  float aa = *prelu;
  #pragma unroll
  for (int px=0;px<4;px++){
    short8 vh, vl;
    #pragma unroll
    for (int o=0;o<8;o++){
      float s = acc[px][o] + bias[cg*8+o];
      s = (s>=0.f) ? s : aa*s;
      unsigned short hb = f2bf(s);
      float hf = __uint_as_float((unsigned)hb << 16);
      unsigned short lb = f2bf(s - hf);
      vh[o] = (short)hb; vl[o] = (short)lb;
    }
    size_t base = ((size_t)(y*W + xb + px))*32 + cg*8;
    *(short8*)(outHi + base) = vh;
    *(short8*)(outLo + base) = vl;
  }
}

// ---------------- primal conv2 (32->32): implicit-GEMM MFMA bf16 hi/lo ----------------
__global__ __launch_bounds__(256) void conv_mfma32(
    const unsigned short* __restrict__ hiB, const unsigned short* __restrict__ loB,
    const unsigned short* __restrict__ Bimg,   // this layer: [9][2][2][64][8]
    const float* __restrict__ bias, const float* __restrict__ prelu,
    float* __restrict__ out)
{
  int b = blockIdx.x;                 // 0..1023
  int by = b >> 1, half = b & 1;
  int y = ((by & 7) << 6) | (by >> 3);   // XCD row swizzle
  int wv = (int)threadIdx.x >> 6;
  int lane = (int)threadIdx.x & 63;
  int xw = half*256 + wv*64;
  int lm = lane & 15, lq = lane >> 4;
  int laneoff = lm*32 + lq*8;
  f32x4 acc[4][2];
  #pragma unroll
  for (int s=0;s<4;s++){ acc[s][0] = (f32x4)0.f; acc[s][1] = (f32x4)0.f; }
  bool fastx = (xw != 0) && (xw != 448);
  const short8* Bf = (const short8*)Bimg;
  #pragma unroll
  for (int dy=-1; dy<=1; dy++){
    int yy = y + dy;
    if ((unsigned)yy >= 512u) continue;
    const unsigned short* rh = hiB + (size_t)yy*512*32;
    const unsigned short* rl = loB + (size_t)yy*512*32;
    #pragma unroll
    for (int dx=-1; dx<=1; dx++){
      int tap = (dy+1)*3 + (dx+1);
      const short8* bp8 = Bf + tap*256 + lane;
      short8 bh0 = bp8[0];     // n=0 hi
      short8 bl0 = bp8[64];    // n=0 lo
      short8 bh1 = bp8[128];   // n=1 hi
      short8 bl1 = bp8[192];   // n=1 lo
      int xoff = (xw + dx)*32 + laneoff;
      #pragma unroll
      for (int s=0; s<4; s++){
        short8 ah, al;
        const unsigned short* ph = rh + xoff + s*512;
        const unsigned short* pl = rl + xoff + s*512;
        if (fastx){
          ah = *(const short8*)ph;
          al = *(const short8*)pl;
        } else {
          int x = xw + s*16 + lm + dx;
          bool ok = ((unsigned)x < 512u);
          ah = ok ? *(const short8*)ph : (short8)0;
          al = ok ? *(const short8*)pl : (short8)0;
        }
        acc[s][0] = __builtin_amdgcn_mfma_f32_16x16x32_bf16(ah, bh0, acc[s][0], 0,0,0);
        acc[s][1] = __builtin_amdgcn_mfma_f32_16x16x32_bf16(ah, bh1, acc[s][1], 0,0,0);
        acc[s][0] = __builtin_amdgcn_mfma_f32_16x16x32_bf16(al, bh0, acc[s][0], 0,0,0);
        acc[s][1] = __builtin_amdgcn_mfma_f32_16x16x32_bf16(al, bh1, acc[s][1], 0,0,0);
        acc[s][0] = __builtin_amdgcn_mfma_f32_16x16x32_bf16(ah, bl0, acc[s][0], 0,0,0);
        acc[s][1] = __builtin_amdgcn_mfma_f32_16x16x32_bf16(ah, bl1, acc[s][1], 0,0,0);
      }
    }
  }
  // epilogue: bias + prelu + planar fp32 store
  float aa = *prelu;
  #pragma unroll
  for (int s=0;s<4;s++){
    #pragma unroll
    for (int n=0;n<2;n++){
      int o = n*16 + lm;
      float bv = bias[o];
      f32x4 v = acc[s][n];
      v.x+=bv; v.y+=bv; v.z+=bv; v.w+=bv;
      v.x=(v.x>=0.f)?v.x:aa*v.x; v.y=(v.y>=0.f)?v.y:aa*v.y;
      v.z=(v.z>=0.f)?v.z:aa*v.z; v.w=(v.w>=0.f)?v.w:aa*v.w;
      *(f32x4*)(out + (size_t)o*NPIX + y*SS + xw + s*16 + lq*4) = v;
    }
  }
}

// ---------------- primal conv3 (32->5): one row per block, 2 px/thread ----------------
template<int COUT>
__global__ __launch_bounds__(256) void conv3x3_duo(
    const float* __restrict__ in1, int Cin1,
    const float* __restrict__ wt,
    const float* __restrict__ bias,
    float* __restrict__ out,
    float* __restrict__ fout, float* __restrict__ tout)
{
  const int W = SS, HW = NPIX;
  int b = blockIdx.x;
  int y = ((b & 7) << 6) | (b >> 3);
  int x0 = (int)threadIdx.x * 2;
  int pix0 = y*W + x0;
  bool ym = y > 0, yp = y < SS-1;
  bool l0 = x0 > 0;
  bool r3 = x0 + 2 < W;
  float acc0[COUT], acc1[COUT];
  #pragma unroll
  for (int o=0;o<COUT;o++){ float bv = bias[o]; acc0[o]=bv; acc1[o]=bv; }
  const float* wr = wt;
  const float* ip = in1 + pix0;
  #pragma unroll 2
  for (int i=0;i<Cin1;i++, ip+=HW){
    v4u A = ym ? *(const v4u*)(ip - W - 1) : (v4u)0.f;
    v4u B = *(const v4u*)(ip - 1);
    v4u D = yp ? *(const v4u*)(ip + W - 1) : (v4u)0.f;
    if (!l0){ A.x = 0.f; B.x = 0.f; D.x = 0.f; }
    if (!r3){ A.w = 0.f; B.w = 0.f; D.w = 0.f; }
    float w0[9] = {A.x,A.y,A.z, B.x,B.y,B.z, D.x,D.y,D.z};
    float w1[9] = {A.y,A.z,A.w, B.y,B.z,B.w, D.y,D.z,D.w};
    #pragma unroll
    for (int t=0;t<9;t++){
      float v0 = w0[t], v1 = w1[t];
      #pragma unroll
      for (int o=0;o<COUT;o++){
        float w = wr[t*COUT+o];
        acc0[o] = fmaf(v0, w, acc0[o]);
        acc1[o] = fmaf(v1, w, acc1[o]);
      }
    }
    wr += 9*COUT;
  }
  float* op = out + pix0;
  #pragma unroll
  for (int o=0;o<COUT;o++){
    float s0 = acc0[o], s1 = acc1[o];
    v2u old = *(const v2u*)(op + o*HW);
    s0 += old.x; s1 += old.y;
    v2u st; st.x = s0; st.y = s1;
    *(v2u*)(op + o*HW) = st;
    if (o==1 && tout){ tout[x0*SS + y] = s0; tout[(x0+1)*SS + y] = s1; }
    if (o==0 && fout){
      *(v2u*)(fout + pix0) = st;
      *(v2u*)(fout + HW + pix0) = st;
      *(v2u*)(fout + 2*HW + pix0) = st;
    }
  }
}

extern "C" void kernel_launch(void* const* d_in, const int* in_sizes, int n_in,
                              void* d_out, int out_size, void* d_ws, size_t ws_size,
                              hipStream_t stream){
  const float* g     = (const float*)d_in[2];
  const float* theta = (const float*)d_in[3];
  const float* dw1 = (const float*)d_in[5];
  const float* db1 = (const float*)d_in[6];
  const float* da1 = (const float*)d_in[7];
  const float* dw2 = (const float*)d_in[8];
  const float* db2 = (const float*)d_in[9];
  const float* da2 = (const float*)d_in[10];
  const float* dw3 = (const float*)d_in[11];
  const float* db3 = (const float*)d_in[12];
  const float* pw1 = (const float*)d_in[13];
  const float* pb1 = (const float*)d_in[14];
  const float* pa1 = (const float*)d_in[15];
  const float* pw2 = (const float*)d_in[16];
  const float* pb2 = (const float*)d_in[17];
  const float* pa2 = (const float*)d_in[18];
  const float* pw3 = (const float*)d_in[19];
  const float* pb3 = (const float*)d_in[20];

  float* ws     = (float*)d_ws;
  float* trig   = ws;                    // 128
  float* taps   = ws + 128;              // -> 2048
  float* h      = ws + 2048;             // 5*NSIN
  float* opf    = h + 5*NSIN;            // NSIN
  float* gcopy  = opf + NSIN;            // NSIN
  float* h1     = gcopy + NSIN;          // NSIN
  float* f      = h1 + NSIN;             // 5*NPIX
  float* bp     = f + 5*NPIX;            // NPIX
  float* imgT   = bp + NPIX;             // NPIX
  float* dualT1 = imgT + NPIX;           // 32*NSIN (unused now, keeps layout)
  float* dualT2 = dualT1 + 32*NSIN;      // 32*NSIN
  float* primT2 = dualT2 + 32*NSIN;      // 32*NPIX
  unsigned short* nhwcHi = (unsigned short*)(primT2 + 32*NPIX);  // 32*NPIX ushorts
  unsigned short* nhwcLo = nhwcHi + (size_t)32*NPIX;             // 32*NPIX ushorts
  float* wsp   = (float*)(nhwcLo + (size_t)32*NPIX);
  float* wtd3  = wsp;                    // 14400
  float* wtp3  = wsp + 14400;            // 14400
  float* wtd1b = wsp + 28800;            // 20160
  float* wtd2b = wsp + 48960;            // 92160 (unused now, keeps layout)
  float* wtp1b = wsp + 141120;           // 17280
  unsigned short* Bimg  = (unsigned short*)(wsp + 158400);       // 184320 ushorts
  unsigned short* Bimg2 = Bimg + 184320;                         // 184320 ushorts
  // dual NHWC hi/lo: 62 rows x DRS x 32ch + 64-ushort zero prefix/suffix
  const size_t DUALSZ = (size_t)64 + (size_t)62*DRS*32 + 64;
  unsigned short* dualHiRaw = Bimg2 + 184320;
  unsigned short* dualLoRaw = dualHiRaw + DUALSZ;
  unsigned short* dualHi = dualHiRaw + 64;
  unsigned short* dualLo = dualLoRaw + 64;

  hipMemsetAsync(h, 0, (size_t)(5*NSIN)*sizeof(float), stream);
  hipMemsetAsync(f, 0, (size_t)(7*NPIX)*sizeof(float), stream);   // f, bp, imgT
  hipMemsetAsync(dualHiRaw, 0, 2*DUALSZ*sizeof(unsigned short), stream); // zero pads once
  hipMemcpyAsync(gcopy, g, (size_t)NSIN*sizeof(float), hipMemcpyDeviceToDevice, stream);
  trig_kernel<<<1,64,0,stream>>>(theta, trig);
  taps_kernel<<<NTAPS,256,0,stream>>>(taps);
  transpose_all<<<(28800+255)/256,256,0,stream>>>(dw3,wtd3, pw3,wtp3);
  transpose_w8<<<(20160+255)/256,256,0,stream>>>(dw1, wtd1b, 7);
  transpose_w8<<<(17280+255)/256,256,0,stream>>>(pw1, wtp1b, 6);
  prep_bimg<<<(92160+255)/256,256,0,stream>>>(pw2, Bimg);
  prep_bimg<<<(92160+255)/256,256,0,stream>>>(dw2, Bimg2);

  const int GD = (NSIN+255)/256;       // 171

  for (int i=0;i<10;i++){
    radon_fwd_kernel<<<(NSIN+3)/4,256,0,stream>>>(f + NPIX, imgT, trig, opf);
    // dual block: in = [h(5) | opf | g] (opf,gcopy contiguous after h)
    conv3x3_dual1<<<dim3(GD,4),256,0,stream>>>(h, 5, opf, 2, wtd1b+(size_t)i*7*288,
                                               db1+(size_t)i*32, da1+i, dualHi, dualLo);
    dual_mfma32<<<dim3(3,AANG),256,0,stream>>>(dualHi, dualLo, Bimg2+(size_t)i*18432,
                                               db2+(size_t)i*32, da2+i, dualT2);
    conv3x3_fast2<5,DDET><<<(NSIN+127)/128,256,0,stream>>>(dualT2, 32, wtd3+i*1440, db3+(size_t)i*5, h, AANG);
    filter_kernel2<<<AANG*12,256,0,stream>>>(h, taps, h1);
    backproj_kernel<<<NPIX/256,256,0,stream>>>(h1, trig, bp);
    // primal block: in = [f(5) | bp] contiguous
    conv3x3_quad6<<<dim3(256,4),256,0,stream>>>(f, wtp1b+(size_t)i*6*288, pb1+(size_t)i*32, pa1+i, nhwcHi, nhwcLo);
    conv_mfma32<<<1024,256,0,stream>>>(nhwcHi, nhwcLo, Bimg+(size_t)i*18432, pb2+(size_t)i*32, pa2+i, primT2);
    conv3x3_duo<5><<<SS,256,0,stream>>>(primT2, 32, wtp3+i*1440, pb3+(size_t)i*5, f,
                                        (i==9) ? (float*)d_out : nullptr, imgT);
  }
}

// Round 4
// 2064.735 us; speedup vs baseline: 1.1230x; 1.0427x over previous
//
#include <hip/hip_runtime.h>
#include <math.h>

#define SS 512
#define AANG 60
#define DDET 729
#define NPIX (SS*SS)        // 262144
#define NSIN (AANG*DDET)    // 43740
#define NTAPS 1457
#define DRS 768             // dual NHWC padded row stride

typedef float v4u __attribute__((ext_vector_type(4), aligned(4)));
typedef float v4a __attribute__((ext_vector_type(4), aligned(16)));
typedef float v2u __attribute__((ext_vector_type(2), aligned(8)));
typedef float v2a __attribute__((ext_vector_type(2), aligned(4)));
typedef short short8 __attribute__((ext_vector_type(8)));
typedef float f32x4 __attribute__((ext_vector_type(4)));

// round-to-nearest-even fp32 -> bf16 bits
__device__ inline unsigned short f2bf(float x){
  unsigned u = __float_as_uint(x);
  return (unsigned short)((u + 0x7fffu + ((u >> 16) & 1u)) >> 16);
}

// ---------------- trig table ----------------
__global__ void trig_kernel(const float* __restrict__ theta, float* __restrict__ trig){
  int a = threadIdx.x;
  if (a < AANG){ trig[a] = cosf(theta[a]); trig[AANG+a] = sinf(theta[a]); }
}

// ---------------- ramp-filter taps ----------------
__global__ void taps_kernel(float* __restrict__ taps){
  __shared__ double red[256];
  int m  = blockIdx.x;
  int mm = m - 728;
  double s = 0.0;
  for (int k = 1 + (int)threadIdx.x; k <= 1023; k += 256){
    int phase = (k*mm) & 2047;
    s += (double)k * cos((double)phase * (M_PI/1024.0));
  }
  red[threadIdx.x] = s;
  __syncthreads();
  for (int off=128; off; off>>=1){
    if ((int)threadIdx.x < off) red[threadIdx.x] += red[threadIdx.x+off];
    __syncthreads();
  }
  if (threadIdx.x==0){
    double x = (red[0]*(1.0/512.0) + ((mm & 1) ? -1.0 : 1.0)) / 2048.0;
    taps[m] = (float)(x * (M_PI/120.0));
  }
}

// ---------------- conv3 weight transposes: -> [L][Cin][9][5] ----------------
__global__ void transpose_all(const float* __restrict__ s2, float* __restrict__ d2,
                              const float* __restrict__ s5, float* __restrict__ d5){
  int idx = blockIdx.x*256 + (int)threadIdx.x;
  const float* src; float* dst;
  int Cout = 5, Cin = 32;
  if      (idx < 14400){              src=s2; dst=d2; }
  else if (idx < 28800){ idx-=14400;  src=s5; dst=d5; }
  else return;
  int t = idx % 9; int r = idx/9;
  int i = r % Cin; r /= Cin;
  int o = r % Cout; int l = r/Cout;
  dst[((l*Cin+i)*9+t)*Cout+o] = src[idx];
}

// ---------------- cg-split re-layout: [L][32][Cin][3][3] -> [L][Cin][4][9][8] ----------
__global__ void transpose_w8(const float* __restrict__ src, float* __restrict__ dst, int Cin){
  int idx = blockIdx.x*256 + (int)threadIdx.x;
  int tot = 10*32*Cin*9;
  if (idx >= tot) return;
  int t = idx % 9; int r = idx/9;
  int i = r % Cin; r /= Cin;
  int o = r % 32; int l = r/32;
  int cg = o >> 3, u = o & 7;
  dst[(((l*Cin + i)*4 + cg)*9 + t)*8 + u] = src[idx];
}

// -------- MFMA B-fragment image: [L][tap=9][n=2][prod=2][lane=64][8] bf16 --------
// works for any [L][32][32][3][3] weight tensor (pw2 and dw2)
__global__ void prep_bimg(const float* __restrict__ w, unsigned short* __restrict__ B){
  int idx = blockIdx.x*256 + (int)threadIdx.x;
  if (idx >= 10*9*2*64*8) return;
  int j    =  idx        & 7;
  int lane = (idx >> 3)  & 63;
  int n    = (idx >> 9)  & 1;
  int r    =  idx >> 10;          // l*9 + tap
  int tap = r % 9, l = r / 9;
  int c = (lane >> 4)*8 + j;      // k = channel
  int o = n*16 + (lane & 15);     // output channel
  float x = w[(((size_t)(l*32+o)*32 + c)*9) + tap];
  unsigned short hb = f2bf(x);
  float hf = __uint_as_float((unsigned)hb << 16);
  unsigned short lb = f2bf(x - hf);
  size_t d = (size_t)l*18432 + (size_t)tap*2048 + n*1024 + lane*8 + j;
  B[d]       = hb;
  B[d + 512] = lb;
}

// -------- MFMA B-fragment image for pw3 [L][5][32][3][3]: [L][tap=9][prod=2][lane=64][8] --------
// N=16 single n-subtile, only cols o<5 nonzero
__global__ void prep_bimg3(const float* __restrict__ w, unsigned short* __restrict__ B){
  int idx = blockIdx.x*256 + (int)threadIdx.x;
  if (idx >= 10*9*64*8) return;
  int j    =  idx       & 7;
  int lane = (idx >> 3) & 63;
  int r    =  idx >> 9;           // l*9 + tap
  int tap = r % 9, l = r / 9;
  int c = (lane >> 4)*8 + j;      // k = channel
  int o = lane & 15;              // output channel (5 real)
  float x = (o < 5) ? w[(((size_t)(l*5+o)*32 + c)*9) + tap] : 0.f;
  unsigned short hb = f2bf(x);
  float hf = __uint_as_float((unsigned)hb << 16);
  unsigned short lb = f2bf(x - hf);
  size_t d = (size_t)l*9216 + (size_t)tap*1024 + lane*8 + j;
  B[d]       = hb;
  B[d + 512] = lb;
}

// ---------------- radon forward: rcp-hoisted clip ----------------
__device__ inline void clipr(float al, float ial, float be, float lo, float hi,
                             float& A, float& B, bool& empty){
  if (fabsf(al) < 1e-7f){ if (be < lo || be > hi) empty = true; return; }
  float t0 = (lo - be)*ial, t1 = (hi - be)*ial;
  float mn = fminf(t0,t1), mx = fmaxf(t0,t1);
  A = fmaxf(A, mn); B = fminf(B, mx);
}

__device__ inline float samp_guard(const float* __restrict__ base, float aR, float bR,
                                   float aC, float bC, int t){
  float tp = (float)t - 255.5f;
  float R = fmaf(aR, tp, bR);
  float C = fmaf(aC, tp, bC);
  float rf = floorf(R), cf = floorf(C);
  int r0 = (int)rf, c0 = (int)cf;
  int r1 = r0+1,    c1 = c0+1;
  float fr = R - rf, fc = C - cf;
  bool r0ok = (r0>=0 && r0<SS), r1ok = (r1>=0 && r1<SS);
  bool c0ok = (c0>=0 && c0<SS), c1ok = (c1>=0 && c1<SS);
  float v00 = (r0ok && c0ok) ? base[r0*SS+c0] : 0.f;
  float v01 = (r0ok && c1ok) ? base[r0*SS+c1] : 0.f;
  float v10 = (r1ok && c0ok) ? base[r1*SS+c0] : 0.f;
  float v11 = (r1ok && c1ok) ? base[r1*SS+c1] : 0.f;
  return (1.f-fr)*((1.f-fc)*v00 + fc*v01) + fr*((1.f-fc)*v10 + fc*v11);
}

__global__ __launch_bounds__(256) void radon_fwd_kernel(
    const float* __restrict__ img, const float* __restrict__ imgT,
    const float* __restrict__ trig, float* __restrict__ out){
  int gid  = blockIdx.x*4 + ((int)threadIdx.x >> 6);
  int lane = (int)threadIdx.x & 63;
  if (gid >= NSIN) return;
  int a = gid / DDET;
  int d = gid - a*DDET;
  float ca = trig[a], sa = trig[AANG+a];
  float sd = (float)d - 364.0f;
  float Rc = fmaf(sd, sa, 255.5f);
  float Cc = fmaf(sd, ca, 255.5f);
  float aR = ca, bR = Rc, aC = -sa, bC = Cc;
  const float* base = img;
  if (fabsf(ca) > fabsf(sa)){
    base = imgT;
    float tmp;
    tmp=aR; aR=aC; aC=tmp;
    tmp=bR; bR=bC; bC=tmp;
  }
  float iaR = __builtin_amdgcn_rcpf(aR);
  float iaC = __builtin_amdgcn_rcpf(aC);
  float tiA = -255.5f, tiB = 255.5f;  bool iE=false;
  float teA = -255.5f, teB = 255.5f;  bool eE=false;
  clipr(aR,iaR,bR, 0.001f, 510.999f, tiA,tiB,iE);
  clipr(aC,iaC,bC, 0.001f, 510.999f, tiA,tiB,iE);
  clipr(aR,iaR,bR, -0.999f, 511.999f, teA,teB,eE);
  clipr(aC,iaC,bC, -0.999f, 511.999f, teA,teB,eE);
  float acc = 0.f;
  if (!eE && teA <= teB){
    int eA = max(0,   (int)floorf(teA+255.5f) - 1);
    int eB = min(511, (int)ceilf (teB+255.5f) + 1);
    int iA = (int)ceilf (tiA+255.5f) + 1;
    int iB = (int)floorf(tiB+255.5f) - 1;
    iA = max(iA, eA); iB = min(iB, eB);
    if (iE || iA > iB){
      for (int t = eA+lane; t <= eB; t += 64) acc += samp_guard(base,aR,bR,aC,bC,t);
    } else {
      for (int t = eA+lane;   t <  iA; t += 64) acc += samp_guard(base,aR,bR,aC,bC,t);
      for (int t = iB+1+lane; t <= eB; t += 64) acc += samp_guard(base,aR,bR,aC,bC,t);
      for (int t = iA+lane;   t <= iB; t += 64){
        float tp = (float)t - 255.5f;
        float R = fmaf(aR, tp, bR);
        float C = fmaf(aC, tp, bC);
        int r0 = (int)R, c0 = (int)C;
        float fr = R - (float)r0, fc = C - (float)c0;
        const float* p = base + r0*SS + c0;
        float v00 = p[0], v01 = p[1], v10 = p[SS], v11 = p[SS+1];
        float top = v00 + fc*(v01-v00);
        float bot = v10 + fc*(v11-v10);
        acc += top + fr*(bot-top);
      }
    }
  }
  for (int off=32; off; off>>=1) acc += __shfl_down(acc, off);
  if (lane==0) out[gid] = acc;
}

// ---------------- ramp filter: 4-way k-split, 64 outputs/block ----------------
__global__ __launch_bounds__(256) void filter_kernel2(
    const float* __restrict__ h0, const float* __restrict__ taps,
    float* __restrict__ h1){
  __shared__ float red[256];
  int a  = blockIdx.x / 12;
  int jb = blockIdx.x - a*12;
  int jl = (int)threadIdx.x & 63;
  int kq = (int)threadIdx.x >> 6;
  int j  = jb*64 + jl;
  float acc = 0.f;
  if (j < DDET){
    const float* row = h0 + a*DDET;
    const float* tp  = taps + 728 + j;
    int k0 = kq*183;
    int k1 = min(k0+183, DDET);
    for (int k=k0;k<k1;k++) acc = fmaf(row[k], tp[-k], acc);
  }
  red[threadIdx.x] = acc;
  __syncthreads();
  if ((int)threadIdx.x < 64 && j < DDET){
    float s = red[jl] + red[64+jl] + red[128+jl] + red[192+jl];
    h1[a*DDET + j] = s;
  }
}

// ---------------- backprojection ----------------
__global__ __launch_bounds__(256) void backproj_kernel(
    const float* __restrict__ h1, const float* __restrict__ trig,
    float* __restrict__ out){
  __shared__ float sh[AANG*28];
  __shared__ int   sbase[AANG];
  __shared__ float strig[2*AANG];
  int tid = threadIdx.x;
  int x0 = (blockIdx.x & 31) * 16, y0 = (blockIdx.x >> 5) * 16;
  if (tid < 2*AANG) strig[tid] = trig[tid];
  __syncthreads();
  if (tid < AANG){
    float ca = strig[tid], sa = strig[AANG+tid];
    float Xa = (float)x0 - 255.5f, Xb = Xa + 15.f;
    float Ya = (float)y0 - 255.5f, Yb = Ya + 15.f;
    float s00 = Xa*ca + Ya*sa, s01 = Xb*ca + Ya*sa;
    float s10 = Xa*ca + Yb*sa, s11 = Xb*ca + Yb*sa;
    float mn = fminf(fminf(s00,s01), fminf(s10,s11)) + 364.0f;
    sbase[tid] = (int)floorf(mn) - 2;
  }
  __syncthreads();
  for (int s = tid; s < AANG*28; s += 256){
    int a = s / 28, j = s - a*28;
    int idx = sbase[a] + j;
    sh[s] = (idx >= 0 && idx < DDET) ? h1[a*DDET + idx] : 0.f;
  }
  __syncthreads();
  int x = x0 + (tid & 15), y = y0 + (tid >> 4);
  float X = (float)x - 255.5f, Y = (float)y - 255.5f;
  float acc = 0.f;
  #pragma unroll 6
  for (int a=0;a<AANG;a++){
    float sidx = fmaf(X, strig[a], fmaf(Y, strig[AANG+a], 364.0f));
    float ff = floorf(sidx);
    int k = (int)ff - sbase[a];
    float fi = sidx - ff;
    float v0 = sh[a*28+k], v1 = sh[a*28+k+1];
    acc += v0 + fi*(v1-v0);
  }
  out[y*SS+x] = acc;
}

// ---------------- dual conv1 (7->32): cg-split scalar + NHWC bf16 hi/lo epilogue ----
// outputs NHWC [62 rows x DRS x 32] with +1 guard-row offset (row y at y+1)
__global__ __launch_bounds__(256) void conv3x3_dual1(
    const float* __restrict__ in1, int Cin1,
    const float* __restrict__ in2, int Cin2,
    const float* __restrict__ wt,
    const float* __restrict__ bias, const float* __restrict__ prelu,
    unsigned short* __restrict__ outHi, unsigned short* __restrict__ outLo)
{
  const int W = DDET, HW = NSIN;
  int pix = blockIdx.x*256 + (int)threadIdx.x;
  if (pix >= NSIN) return;
  int cg = blockIdx.y;
  int y = pix / W, x = pix - y*W;
  bool ym = y>0, yp = y<AANG-1, xm = x>0, xp = x<W-1;
  float acc[8];
  #pragma unroll
  for (int o=0;o<8;o++) acc[o] = bias[cg*8+o];
  const float* wch = wt + cg*72;
  for (int part=0; part<2; part++){
    const float* src = part ? in2 : in1;
    int nch = part ? Cin2 : Cin1;
    const float* ip = src + pix;
    for (int i=0;i<nch;i++, ip+=HW, wch+=288){
      float p4 = ip[0];
      float p0=0,p1=0,p2=0,p3=0,p5=0,p6=0,p7=0,p8=0;
      if (ym){ p1 = ip[-W]; if (xm) p0 = ip[-W-1]; if (xp) p2 = ip[-W+1]; }
      if (xm) p3 = ip[-1];
      if (xp) p5 = ip[1];
      if (yp){ p7 = ip[W]; if (xm) p6 = ip[W-1]; if (xp) p8 = ip[W+1]; }
      float p[9] = {p0,p1,p2,p3,p4,p5,p6,p7,p8};
      #pragma unroll
      for (int t=0;t<9;t++){
        float v = p[t];
        #pragma unroll
        for (int o=0;o<8;o++) acc[o] = fmaf(v, wch[t*8+o], acc[o]);
      }
    }
  }
  float aa = *prelu;
  short8 vh, vl;
  #pragma unroll
  for (int o=0;o<8;o++){
    float s = acc[o];
    s = (s>=0.f) ? s : aa*s;
    unsigned short hb = f2bf(s);
    float hf = __uint_as_float((unsigned)hb << 16);
    unsigned short lb = f2bf(s - hf);
    vh[o] = (short)hb; vl[o] = (short)lb;
  }
  size_t base = ((size_t)(y+1)*DRS + x)*32 + cg*8;
  *(short8*)(outHi + base) = vh;
  *(short8*)(outLo + base) = vl;
}

// ---------------- dual conv2 (32->32): implicit-GEMM MFMA bf16 hi/lo ----------------
// NHWC input padded to DRS with zero guard rows/pads: all loads unguarded.
__global__ __launch_bounds__(256) void dual_mfma32(
    const unsigned short* __restrict__ hiB, const unsigned short* __restrict__ loB,
    const unsigned short* __restrict__ Bimg,   // this layer: [9][2][2][64][8]
    const float* __restrict__ bias, const float* __restrict__ prelu,
    float* __restrict__ out)
{
  int y  = blockIdx.y;                               // 0..59
  int wv = (int)threadIdx.x >> 6;
  int lane = (int)threadIdx.x & 63;
  int xw = blockIdx.x*256 + wv*64;                   // 0..704 step 64
  int lm = lane & 15, lq = lane >> 4;
  int laneoff = lm*32 + lq*8;
  f32x4 acc[4][2];
  #pragma unroll
  for (int s=0;s<4;s++){ acc[s][0] = (f32x4)0.f; acc[s][1] = (f32x4)0.f; }
  const short8* Bf = (const short8*)Bimg;
  #pragma unroll
  for (int dy=-1; dy<=1; dy++){
    const unsigned short* rh = hiB + (size_t)(y+dy+1)*DRS*32;
    const unsigned short* rl = loB + (size_t)(y+dy+1)*DRS*32;
    #pragma unroll
    for (int dx=-1; dx<=1; dx++){
      int tap = (dy+1)*3 + (dx+1);
      const short8* bp8 = Bf + tap*256 + lane;
      short8 bh0 = bp8[0];     // n=0 hi
      short8 bl0 = bp8[64];    // n=0 lo
      short8 bh1 = bp8[128];   // n=1 hi
      short8 bl1 = bp8[192];   // n=1 lo
      int xoff = (xw + dx)*32 + laneoff;
      #pragma unroll
      for (int s=0; s<4; s++){
        short8 ah = *(const short8*)(rh + xoff + s*512);
        short8 al = *(const short8*)(rl + xoff + s*512);
        acc[s][0] = __builtin_amdgcn_mfma_f32_16x16x32_bf16(ah, bh0, acc[s][0], 0,0,0);
        acc[s][1] = __builtin_amdgcn_mfma_f32_16x16x32_bf16(ah, bh1, acc[s][1], 0,0,0);
        acc[s][0] = __builtin_amdgcn_mfma_f32_16x16x32_bf16(al, bh0, acc[s][0], 0,0,0);
        acc[s][1] = __builtin_amdgcn_mfma_f32_16x16x32_bf16(al, bh1, acc[s][1], 0,0,0);
        acc[s][0] = __builtin_amdgcn_mfma_f32_16x16x32_bf16(ah, bl0, acc[s][0], 0,0,0);
        acc[s][1] = __builtin_amdgcn_mfma_f32_16x16x32_bf16(ah, bl1, acc[s][1], 0,0,0);
      }
    }
  }
  // epilogue: bias + prelu + planar fp32 store (4B-aligned: 729 stride is odd)
  float aa = *prelu;
  #pragma unroll
  for (int s=0;s<4;s++){
    int px0 = xw + s*16 + lq*4;
    #pragma unroll
    for (int n=0;n<2;n++){
      int o = n*16 + lm;
      float bv = bias[o];
      f32x4 v = acc[s][n];
      v.x+=bv; v.y+=bv; v.z+=bv; v.w+=bv;
      v.x=(v.x>=0.f)?v.x:aa*v.x; v.y=(v.y>=0.f)?v.y:aa*v.y;
      v.z=(v.z>=0.f)?v.z:aa*v.z; v.w=(v.w>=0.f)?v.w:aa*v.w;
      float* op = out + (size_t)o*NSIN + y*DDET + px0;
      if (px0 + 3 <= DDET-1){
        v4u st; st.x=v.x; st.y=v.y; st.z=v.z; st.w=v.w;
        *(v4u*)op = st;
      } else {
        if (px0   <= DDET-1) op[0] = v.x;
        if (px0+1 <= DDET-1) op[1] = v.y;
        if (px0+2 <= DDET-1) op[2] = v.z;
      }
    }
  }
}

// ---------------- dual conv3 (32->5): 2-way channel split + LDS reduce ----------------
template<int COUT, int W>
__global__ __launch_bounds__(256) void conv3x3_fast2(
    const float* __restrict__ in1, int Cin1,
    const float* __restrict__ wt,
    const float* __restrict__ bias,
    float* __restrict__ out, int H)
{
  __shared__ float red[128*COUT];
  int HW = H*W;
  int pl = (int)threadIdx.x & 127;
  int half = (int)threadIdx.x >> 7;
  int pix = blockIdx.x*128 + pl;
  bool valid = (pix < HW);
  float acc[COUT];
  #pragma unroll
  for (int o=0;o<COUT;o++) acc[o] = 0.f;
  if (valid){
    int y = pix / W, x = pix - y*W;
    bool ym = y>0, yp = y<H-1, xm = x>0, xp = x<W-1;
    int nch = Cin1 >> 1;
    const float* wr = wt + half*nch*9*COUT;
    const float* ip = in1 + pix + (size_t)half*nch*HW;
    for (int i=0;i<nch;i++, ip+=HW){
      float p4 = ip[0];
      float p0=0,p1=0,p2=0,p3=0,p5=0,p6=0,p7=0,p8=0;
      if (ym){ p1 = ip[-W]; if (xm) p0 = ip[-W-1]; if (xp) p2 = ip[-W+1]; }
      if (xm) p3 = ip[-1];
      if (xp) p5 = ip[1];
      if (yp){ p7 = ip[W]; if (xm) p6 = ip[W-1]; if (xp) p8 = ip[W+1]; }
      float p[9] = {p0,p1,p2,p3,p4,p5,p6,p7,p8};
      #pragma unroll
      for (int t=0;t<9;t++){
        float v = p[t];
        #pragma unroll
        for (int o=0;o<COUT;o++) acc[o] = fmaf(v, wr[t*COUT+o], acc[o]);
      }
      wr += 9*COUT;
    }
  }
  if (half == 1){
    #pragma unroll
    for (int o=0;o<COUT;o++) red[pl*COUT+o] = acc[o];
  }
  __syncthreads();
  if (half == 0 && valid){
    float* op = out + pix;
    #pragma unroll
    for (int o=0;o<COUT;o++)
      op[o*HW] += acc[o] + red[pl*COUT+o] + bias[o];
  }
}

// ---------------- primal conv1 (6->32): R6 quad + NHWC bf16 hi/lo epilogue ----------------
__device__ inline void loadrow6(float* R, const float* p, bool valid, bool lE, bool rE){
  if (valid){
    v4u a = *(const v4u*)(p-1);
    v2a b = *(const v2a*)(p+3);
    R[0]=lE?0.f:a.x; R[1]=a.y; R[2]=a.z; R[3]=a.w;
    R[4]=b.x; R[5]=rE?0.f:b.y;
  } else {
    #pragma unroll
    for (int k=0;k<6;k++) R[k]=0.f;
  }
}

__global__ __launch_bounds__(256) void conv3x3_quad6(
    const float* __restrict__ in,      // 6 contiguous channels [f(5)|bp]
    const float* __restrict__ wt,      // [6][4][9][8]
    const float* __restrict__ bias, const float* __restrict__ prelu,
    unsigned short* __restrict__ outHi, unsigned short* __restrict__ outLo)
{
  const int W = SS, HW = NPIX;
  int rb = blockIdx.x;                       // 0..255 row-pairs
  int cg = blockIdx.y;                       // 0..3
  int yb = ((rb & 7) << 5) | (rb >> 3);      // XCD swizzle
  int wv = (int)threadIdx.x >> 6;
  int lane = (int)threadIdx.x & 63;
  int y = yb*2 + (wv >> 1);
  int xb = ((wv & 1) << 8) + lane*4;
  const float* wch = wt + cg*72;
  float acc[4][8];
  #pragma unroll
  for (int px=0;px<4;px++)
    #pragma unroll
    for (int o=0;o<8;o++) acc[px][o] = 0.f;
  bool ym = y>0, yp = y<SS-1;
  bool lE = (xb==0), rE = (xb==508);
  const float* ip = in + y*W + xb;
  for (int i=0;i<6;i++, ip+=HW, wch+=288){
    float R[3][6];
    loadrow6(R[0], ip - W, ym,   lE, rE);
    loadrow6(R[1], ip,     true, lE, rE);
    loadrow6(R[2], ip + W, yp,   lE, rE);
    #pragma unroll
    for (int dy=0;dy<3;dy++){
      #pragma unroll
      for (int dx=0;dx<3;dx++){
        #pragma unroll
        for (int o=0;o<8;o++){
          float w = wch[(dy*3+dx)*8+o];
          #pragma unroll
          for (int px=0;px<4;px++)
            acc[px][o] = fmaf(R[dy][px+dx], w, acc[px][o]);
        }
      }
    }
  }
  float aa = *prelu;
  #pragma unroll
  for (int px=0;px<4;px++){
    short8 vh, vl;
    #pragma unroll
    for (int o=0;o<8;o++){
      float s = acc[px][o] + bias[cg*8+o];
      s = (s>=0.f) ? s : aa*s;
      unsigned short hb = f2bf(s);
      float hf = __uint_as_float((unsigned)hb << 16);
      unsigned short lb = f2bf(s - hf);
      vh[o] = (short)hb; vl[o] = (short)lb;
    }
    size_t base = ((size_t)(y*W + xb + px))*32 + cg*8;
    *(short8*)(outHi + base) = vh;
    *(short8*)(outLo + base) = vl;
  }
}

// ---------------- primal conv2 (32->32): implicit-GEMM MFMA bf16 hi/lo ----------------
// epilogue: bias+prelu, repack to NHWC bf16 hi/lo via per-wave LDS transpose
__global__ __launch_bounds__(256) void conv_mfma32(
    const unsigned short* __restrict__ hiB, const unsigned short* __restrict__ loB,
    const unsigned short* __restrict__ Bimg,   // this layer: [9][2][2][64][8]
    const float* __restrict__ bias, const float* __restrict__ prelu,
    unsigned short* __restrict__ outHi, unsigned short* __restrict__ outLo)
{
  __shared__ unsigned int tr[4][64][33];
  int b = blockIdx.x;                 // 0..1023
  int by = b >> 1, half = b & 1;
  int y = ((by & 7) << 6) | (by >> 3);   // XCD row swizzle
  int wv = (int)threadIdx.x >> 6;
  int lane = (int)threadIdx.x & 63;
  int xw = half*256 + wv*64;
  int lm = lane & 15, lq = lane >> 4;
  int laneoff = lm*32 + lq*8;
  f32x4 acc[4][2];
  #pragma unroll
  for (int s=0;s<4;s++){ acc[s][0] = (f32x4)0.f; acc[s][1] = (f32x4)0.f; }
  bool fastx = (xw != 0) && (xw != 448);
  const short8* Bf = (const short8*)Bimg;
  #pragma unroll
  for (int dy=-1; dy<=1; dy++){
    int yy = y + dy;
    if ((unsigned)yy >= 512u) continue;
    const unsigned short* rh = hiB + (size_t)yy*512*32;
    const unsigned short* rl = loB + (size_t)yy*512*32;
    #pragma unroll
    for (int dx=-1; dx<=1; dx++){
      int tap = (dy+1)*3 + (dx+1);
      const short8* bp8 = Bf + tap*256 + lane;
      short8 bh0 = bp8[0];     // n=0 hi
      short8 bl0 = bp8[64];    // n=0 lo
      short8 bh1 = bp8[128];   // n=1 hi
      short8 bl1 = bp8[192];   // n=1 lo
      int xoff = (xw + dx)*32 + laneoff;
      #pragma unroll
      for (int s=0; s<4; s++){
        short8 ah, al;
        const unsigned short* ph = rh + xoff + s*512;
        const unsigned short* pl = rl + xoff + s*512;
        if (fastx){
          ah = *(const short8*)ph;
          al = *(const short8*)pl;
        } else {
          int x = xw + s*16 + lm + dx;
          bool ok = ((unsigned)x < 512u);
          ah = ok ? *(const short8*)ph : (short8)0;
          al = ok ? *(const short8*)pl : (short8)0;
        }
        acc[s][0] = __builtin_amdgcn_mfma_f32_16x16x32_bf16(ah, bh0, acc[s][0], 0,0,0);
        acc[s][1] = __builtin_amdgcn_mfma_f32_16x16x32_bf16(ah, bh1, acc[s][1], 0,0,0);
        acc[s][0] = __builtin_amdgcn_mfma_f32_16x16x32_bf16(al, bh0, acc[s][0], 0,0,0);
        acc[s][1] = __builtin_amdgcn_mfma_f32_16x16x32_bf16(al, bh1, acc[s][1], 0,0,0);
        acc[s][0] = __builtin_amdgcn_mfma_f32_16x16x32_bf16(ah, bl0, acc[s][0], 0,0,0);
        acc[s][1] = __builtin_amdgcn_mfma_f32_16x16x32_bf16(ah, bl1, acc[s][1], 0,0,0);
      }
    }
  }
  // epilogue: bias + prelu + pack hi/lo into LDS [px][ch]
  float aa = *prelu;
  #pragma unroll
  for (int s=0;s<4;s++){
    #pragma unroll
    for (int n=0;n<2;n++){
      int o = n*16 + lm;
      float bv = bias[o];
      f32x4 v = acc[s][n];
      v.x+=bv; v.y+=bv; v.z+=bv; v.w+=bv;
      v.x=(v.x>=0.f)?v.x:aa*v.x; v.y=(v.y>=0.f)?v.y:aa*v.y;
      v.z=(v.z>=0.f)?v.z:aa*v.z; v.w=(v.w>=0.f)?v.w:aa*v.w;
      #pragma unroll
      for (int r=0;r<4;r++){
        float x = v[r];
        unsigned short hb = f2bf(x);
        float hf = __uint_as_float((unsigned)hb << 16);
        unsigned short lb = f2bf(x - hf);
        tr[wv][s*16 + lq*4 + r][o] = ((unsigned)hb << 16) | (unsigned)lb;
      }
    }
  }
  __syncthreads();
  // read channel-contiguous, split, coalesced NHWC stores
  int c8 = lane & 3;             // 8-channel chunk
  int pxl = lane >> 2;           // 0..15
  #pragma unroll
  for (int k=0;k<4;k++){
    int px = pxl + k*16;
    short8 vh, vl;
    #pragma unroll
    for (int j=0;j<8;j++){
      unsigned p = tr[wv][px][c8*8 + j];
      vh[j] = (short)(p >> 16);
      vl[j] = (short)(p & 0xffffu);
    }
    size_t base = ((size_t)(y*SS + xw + px))*32 + c8*8;
    *(short8*)(outHi + base) = vh;
    *(short8*)(outLo + base) = vl;
  }
}

// ---------------- primal conv3 (32->5): implicit-GEMM MFMA, N=16 (5 real) ----------------
// accumulates into f, writes imgT transpose (ch1) and final output replication (ch0)
__global__ __launch_bounds__(256) void duo_mfma(
    const unsigned short* __restrict__ hiB, const unsigned short* __restrict__ loB,
    const unsigned short* __restrict__ Bimg3,   // this layer: [9][2][64][8]
    const float* __restrict__ bias,
    float* __restrict__ f,
    float* __restrict__ fout, float* __restrict__ tout)
{
  int b = blockIdx.x;                 // 0..1023
  int by = b >> 1, half = b & 1;
  int y = ((by & 7) << 6) | (by >> 3);   // XCD row swizzle
  int wv = (int)threadIdx.x >> 6;
  int lane = (int)threadIdx.x & 63;
  int xw = half*256 + wv*64;
  int lm = lane & 15, lq = lane >> 4;
  int laneoff = lm*32 + lq*8;
  f32x4 acc[4];
  #pragma unroll
  for (int s=0;s<4;s++) acc[s] = (f32x4)0.f;
  bool fastx = (xw != 0) && (xw != 448);
  const short8* Bf = (const short8*)Bimg3;
  #pragma unroll
  for (int dy=-1; dy<=1; dy++){
    int yy = y + dy;
    if ((unsigned)yy >= 512u) continue;
    const unsigned short* rh = hiB + (size_t)yy*512*32;
    const unsigned short* rl = loB + (size_t)yy*512*32;
    #pragma unroll
    for (int dx=-1; dx<=1; dx++){
      int tap = (dy+1)*3 + (dx+1);
      const short8* bp8 = Bf + tap*128 + lane;
      short8 bh = bp8[0];
      short8 bl = bp8[64];
      int xoff = (xw + dx)*32 + laneoff;
      #pragma unroll
      for (int s=0; s<4; s++){
        short8 ah, al;
        const unsigned short* ph = rh + xoff + s*512;
        const unsigned short* pl = rl + xoff + s*512;
        if (fastx){
          ah = *(const short8*)ph;
          al = *(const short8*)pl;
        } else {
          int x = xw + s*16 + lm + dx;
          bool ok = ((unsigned)x < 512u);
          ah = ok ? *(const short8*)ph : (short8)0;
          al = ok ? *(const short8*)pl : (short8)0;
        }
        acc[s] = __builtin_amdgcn_mfma_f32_16x16x32_bf16(ah, bh, acc[s], 0,0,0);
        acc[s] = __builtin_amdgcn_mfma_f32_16x16x32_bf16(al, bh, acc[s], 0,0,0);
        acc[s] = __builtin_amdgcn_mfma_f32_16x16x32_bf16(ah, bl, acc[s], 0,0,0);
      }
    }
  }
  // epilogue: f += conv3 + bias on lanes lm<5; imgT transpose (lm==1); output rep (lm==0)
  if (lm < 5){
    float bv = bias[lm];
    #pragma unroll
    for (int s=0;s<4;s++){
      int px0 = xw + s*16 + lq*4;
      float* op = f + (size_t)lm*NPIX + y*SS + px0;
      f32x4 old = *(const f32x4*)op;
      f32x4 v = acc[s];
      v.x += old.x + bv; v.y += old.y + bv;
      v.z += old.z + bv; v.w += old.w + bv;
      *(f32x4*)op = v;
      if (lm == 1){
        tout[(px0  )*SS + y] = v.x;
        tout[(px0+1)*SS + y] = v.y;
        tout[(px0+2)*SS + y] = v.z;
        tout[(px0+3)*SS + y] = v.w;
      }
      if (lm == 0 && fout){
        float* q = fout + y*SS + px0;
        *(f32x4*)q = v;
        *(f32x4*)(q + NPIX) = v;
        *(f32x4*)(q + 2*NPIX) = v;
      }
    }
  }
}

extern "C" void kernel_launch(void* const* d_in, const int* in_sizes, int n_in,
                              void* d_out, int out_size, void* d_ws, size_t ws_size,
                              hipStream_t stream){
  const float* g     = (const float*)d_in[2];
  const float* theta = (const float*)d_in[3];
  const float* dw1 = (const float*)d_in[5];
  const float* db1 = (const float*)d_in[6];
  const float* da1 = (const float*)d_in[7];
  const float* dw2 = (const float*)d_in[8];
  const float* db2 = (const float*)d_in[9];
  const float* da2 = (const float*)d_in[10];
  const float* dw3 = (const float*)d_in[11];
  const float* db3 = (const float*)d_in[12];
  const float* pw1 = (const float*)d_in[13];
  const float* pb1 = (const float*)d_in[14];
  const float* pa1 = (const float*)d_in[15];
  const float* pw2 = (const float*)d_in[16];
  const float* pb2 = (const float*)d_in[17];
  const float* pa2 = (const float*)d_in[18];
  const float* pw3 = (const float*)d_in[19];
  const float* pb3 = (const float*)d_in[20];

  float* ws     = (float*)d_ws;
  float* trig   = ws;                    // 128
  float* taps   = ws + 128;              // -> 2048
  float* h      = ws + 2048;             // 5*NSIN
  float* opf    = h + 5*NSIN;            // NSIN
  float* gcopy  = opf + NSIN;            // NSIN
  float* h1     = gcopy + NSIN;          // NSIN
  float* f      = h1 + NSIN;             // 5*NPIX
  float* bp     = f + 5*NPIX;            // NPIX
  float* imgT   = bp + NPIX;             // NPIX
  float* dualT1 = imgT + NPIX;           // 32*NSIN (unused, keeps layout)
  float* dualT2 = dualT1 + 32*NSIN;      // 32*NSIN
  float* primT2slot = dualT2 + 32*NSIN;  // 32*NPIX floats of space
  unsigned short* primHi = (unsigned short*)primT2slot;          // 32*NPIX ushorts
  unsigned short* primLo = primHi + (size_t)32*NPIX;             // 32*NPIX ushorts
  unsigned short* nhwcHi = (unsigned short*)(primT2slot + 32*NPIX);  // 32*NPIX ushorts
  unsigned short* nhwcLo = nhwcHi + (size_t)32*NPIX;             // 32*NPIX ushorts
  float* wsp   = (float*)(nhwcLo + (size_t)32*NPIX);
  float* wtd3  = wsp;                    // 14400
  float* wtp3  = wsp + 14400;            // 14400 (unused now)
  float* wtd1b = wsp + 28800;            // 20160
  float* wtd2b = wsp + 48960;            // 92160 (unused, keeps layout)
  float* wtp1b = wsp + 141120;           // 17280
  unsigned short* Bimg  = (unsigned short*)(wsp + 158400);       // 184320 ushorts
  unsigned short* Bimg2 = Bimg + 184320;                         // 184320 ushorts
  unsigned short* Bimg3 = Bimg2 + 184320;                        // 92160 ushorts
  // dual NHWC hi/lo: 62 rows x DRS x 32ch + 64-ushort zero prefix/suffix
  const size_t DUALSZ = (size_t)64 + (size_t)62*DRS*32 + 64;
  unsigned short* dualHiRaw = Bimg3 + 92160;
  unsigned short* dualLoRaw = dualHiRaw + DUALSZ;
  unsigned short* dualHi = dualHiRaw + 64;
  unsigned short* dualLo = dualLoRaw + 64;

  hipMemsetAsync(h, 0, (size_t)(5*NSIN)*sizeof(float), stream);
  hipMemsetAsync(f, 0, (size_t)(7*NPIX)*sizeof(float), stream);   // f, bp, imgT
  hipMemsetAsync(dualHiRaw, 0, 2*DUALSZ*sizeof(unsigned short), stream); // zero pads once
  hipMemcpyAsync(gcopy, g, (size_t)NSIN*sizeof(float), hipMemcpyDeviceToDevice, stream);
  trig_kernel<<<1,64,0,stream>>>(theta, trig);
  taps_kernel<<<NTAPS,256,0,stream>>>(taps);
  transpose_all<<<(28800+255)/256,256,0,stream>>>(dw3,wtd3, pw3,wtp3);
  transpose_w8<<<(20160+255)/256,256,0,stream>>>(dw1, wtd1b, 7);
  transpose_w8<<<(17280+255)/256,256,0,stream>>>(pw1, wtp1b, 6);
  prep_bimg<<<(92160+255)/256,256,0,stream>>>(pw2, Bimg);
  prep_bimg<<<(92160+255)/256,256,0,stream>>>(dw2, Bimg2);
  prep_bimg3<<<(46080+255)/256,256,0,stream>>>(pw3, Bimg3);

  const int GD = (NSIN+255)/256;       // 171

  for (int i=0;i<10;i++){
    radon_fwd_kernel<<<(NSIN+3)/4,256,0,stream>>>(f + NPIX, imgT, trig, opf);
    // dual block: in = [h(5) | opf | g] (opf,gcopy contiguous after h)
    conv3x3_dual1<<<dim3(GD,4),256,0,stream>>>(h, 5, opf, 2, wtd1b+(size_t)i*7*288,
                                               db1+(size_t)i*32, da1+i, dualHi, dualLo);
    dual_mfma32<<<dim3(3,AANG),256,0,stream>>>(dualHi, dualLo, Bimg2+(size_t)i*18432,
                                               db2+(size_t)i*32, da2+i, dualT2);
    conv3x3_fast2<5,DDET><<<(NSIN+127)/128,256,0,stream>>>(dualT2, 32, wtd3+i*1440, db3+(size_t)i*5, h, AANG);
    filter_kernel2<<<AANG*12,256,0,stream>>>(h, taps, h1);
    backproj_kernel<<<NPIX/256,256,0,stream>>>(h1, trig, bp);
    // primal block: in = [f(5) | bp] contiguous
    conv3x3_quad6<<<dim3(256,4),256,0,stream>>>(f, wtp1b+(size_t)i*6*288, pb1+(size_t)i*32, pa1+i, nhwcHi, nhwcLo);
    conv_mfma32<<<1024,256,0,stream>>>(nhwcHi, nhwcLo, Bimg+(size_t)i*18432, pb2+(size_t)i*32, pa2+i, primHi, primLo);
    duo_mfma<<<1024,256,0,stream>>>(primHi, primLo, Bimg3+(size_t)i*9216, pb3+(size_t)i*5, f,
                                    (i==9) ? (float*)d_out : nullptr, imgT);
  }
}

// Round 5
// 1881.799 us; speedup vs baseline: 1.2321x; 1.0972x over previous
//
#include <hip/hip_runtime.h>
#include <math.h>

#define SS 512
#define AANG 60
#define DDET 729
#define NPIX (SS*SS)        // 262144
#define NSIN (AANG*DDET)    // 43740
#define NTAPS 1457
#define DRS 768             // dual NHWC padded row stride

typedef float v4u __attribute__((ext_vector_type(4), aligned(4)));
typedef float v4a __attribute__((ext_vector_type(4), aligned(16)));
typedef float v2u __attribute__((ext_vector_type(2), aligned(8)));
typedef float v2a __attribute__((ext_vector_type(2), aligned(4)));
typedef short short8 __attribute__((ext_vector_type(8)));
typedef short short4v __attribute__((ext_vector_type(4)));
typedef float f32x4 __attribute__((ext_vector_type(4)));

// round-to-nearest-even fp32 -> bf16 bits
__device__ inline unsigned short f2bf(float x){
  unsigned u = __float_as_uint(x);
  return (unsigned short)((u + 0x7fffu + ((u >> 16) & 1u)) >> 16);
}

// ---------------- trig table ----------------
__global__ void trig_kernel(const float* __restrict__ theta, float* __restrict__ trig){
  int a = threadIdx.x;
  if (a < AANG){ trig[a] = cosf(theta[a]); trig[AANG+a] = sinf(theta[a]); }
}

// ---------------- ramp-filter taps ----------------
__global__ void taps_kernel(float* __restrict__ taps){
  __shared__ double red[256];
  int m  = blockIdx.x;
  int mm = m - 728;
  double s = 0.0;
  for (int k = 1 + (int)threadIdx.x; k <= 1023; k += 256){
    int phase = (k*mm) & 2047;
    s += (double)k * cos((double)phase * (M_PI/1024.0));
  }
  red[threadIdx.x] = s;
  __syncthreads();
  for (int off=128; off; off>>=1){
    if ((int)threadIdx.x < off) red[threadIdx.x] += red[threadIdx.x+off];
    __syncthreads();
  }
  if (threadIdx.x==0){
    double x = (red[0]*(1.0/512.0) + ((mm & 1) ? -1.0 : 1.0)) / 2048.0;
    taps[m] = (float)(x * (M_PI/120.0));
  }
}

// ---------------- conv3 weight transposes: -> [L][Cin][9][5] ----------------
__global__ void transpose_all(const float* __restrict__ s2, float* __restrict__ d2,
                              const float* __restrict__ s5, float* __restrict__ d5){
  int idx = blockIdx.x*256 + (int)threadIdx.x;
  const float* src; float* dst;
  int Cout = 5, Cin = 32;
  if      (idx < 14400){              src=s2; dst=d2; }
  else if (idx < 28800){ idx-=14400;  src=s5; dst=d5; }
  else return;
  int t = idx % 9; int r = idx/9;
  int i = r % Cin; r /= Cin;
  int o = r % Cout; int l = r/Cout;
  dst[((l*Cin+i)*9+t)*Cout+o] = src[idx];
}

// ---------------- cg-split re-layout: [L][32][Cin][3][3] -> [L][Cin][4][9][8] ----------
__global__ void transpose_w8(const float* __restrict__ src, float* __restrict__ dst, int Cin){
  int idx = blockIdx.x*256 + (int)threadIdx.x;
  int tot = 10*32*Cin*9;
  if (idx >= tot) return;
  int t = idx % 9; int r = idx/9;
  int i = r % Cin; r /= Cin;
  int o = r % 32; int l = r/32;
  int cg = o >> 3, u = o & 7;
  dst[(((l*Cin + i)*4 + cg)*9 + t)*8 + u] = src[idx];
}

// -------- MFMA B-fragment image: [L][tap=9][n=2][prod=2][lane=64][8] bf16 --------
// works for any [L][32][32][3][3] weight tensor (pw2 and dw2)
__global__ void prep_bimg(const float* __restrict__ w, unsigned short* __restrict__ B){
  int idx = blockIdx.x*256 + (int)threadIdx.x;
  if (idx >= 10*9*2*64*8) return;
  int j    =  idx        & 7;
  int lane = (idx >> 3)  & 63;
  int n    = (idx >> 9)  & 1;
  int r    =  idx >> 10;          // l*9 + tap
  int tap = r % 9, l = r / 9;
  int c = (lane >> 4)*8 + j;      // k = channel
  int o = n*16 + (lane & 15);     // output channel
  float x = w[(((size_t)(l*32+o)*32 + c)*9) + tap];
  unsigned short hb = f2bf(x);
  float hf = __uint_as_float((unsigned)hb << 16);
  unsigned short lb = f2bf(x - hf);
  size_t d = (size_t)l*18432 + (size_t)tap*2048 + n*1024 + lane*8 + j;
  B[d]       = hb;
  B[d + 512] = lb;
}

// -------- MFMA B-fragment image for pw3 [L][5][32][3][3]: [L][tap=9][prod=2][lane=64][8] --------
// N=16 single n-subtile, only cols o<5 nonzero
__global__ void prep_bimg3(const float* __restrict__ w, unsigned short* __restrict__ B){
  int idx = blockIdx.x*256 + (int)threadIdx.x;
  if (idx >= 10*9*64*8) return;
  int j    =  idx       & 7;
  int lane = (idx >> 3) & 63;
  int r    =  idx >> 9;           // l*9 + tap
  int tap = r % 9, l = r / 9;
  int c = (lane >> 4)*8 + j;      // k = channel
  int o = lane & 15;              // output channel (5 real)
  float x = (o < 5) ? w[(((size_t)(l*5+o)*32 + c)*9) + tap] : 0.f;
  unsigned short hb = f2bf(x);
  float hf = __uint_as_float((unsigned)hb << 16);
  unsigned short lb = f2bf(x - hf);
  size_t d = (size_t)l*9216 + (size_t)tap*1024 + lane*8 + j;
  B[d]       = hb;
  B[d + 512] = lb;
}

// -------- MFMA B-fragment image for pw1 [L][32][6][3][3]: [L][g=3][n=2][prod=2][64][8] --------
// k = tap_local*8 + ch; t = g*4+tap_local; ch>=6 or t>=9 -> 0
__global__ void prep_bimg1(const float* __restrict__ w, unsigned short* __restrict__ B){
  int idx = blockIdx.x*256 + (int)threadIdx.x;
  if (idx >= 10*3*2*64*8) return;
  int j    =  idx       & 7;
  int lane = (idx >> 3) & 63;
  int n    = (idx >> 9) & 1;
  int r    =  idx >> 10;          // l*3 + g
  int g = r % 3, l = r / 3;
  int t = g*4 + (lane >> 4);
  int o = n*16 + (lane & 15);
  float x = (t < 9 && j < 6) ? w[(((size_t)(l*32+o)*6 + j)*9) + t] : 0.f;
  unsigned short hb = f2bf(x);
  float hf = __uint_as_float((unsigned)hb << 16);
  unsigned short lb = f2bf(x - hf);
  size_t d = (size_t)l*6144 + (size_t)g*2048 + n*1024 + lane*8 + j;
  B[d]       = hb;
  B[d + 512] = lb;
}

// ---------------- radon forward: rcp-hoisted clip ----------------
__device__ inline void clipr(float al, float ial, float be, float lo, float hi,
                             float& A, float& B, bool& empty){
  if (fabsf(al) < 1e-7f){ if (be < lo || be > hi) empty = true; return; }
  float t0 = (lo - be)*ial, t1 = (hi - be)*ial;
  float mn = fminf(t0,t1), mx = fmaxf(t0,t1);
  A = fmaxf(A, mn); B = fminf(B, mx);
}

__device__ inline float samp_guard(const float* __restrict__ base, float aR, float bR,
                                   float aC, float bC, int t){
  float tp = (float)t - 255.5f;
  float R = fmaf(aR, tp, bR);
  float C = fmaf(aC, tp, bC);
  float rf = floorf(R), cf = floorf(C);
  int r0 = (int)rf, c0 = (int)cf;
  int r1 = r0+1,    c1 = c0+1;
  float fr = R - rf, fc = C - cf;
  bool r0ok = (r0>=0 && r0<SS), r1ok = (r1>=0 && r1<SS);
  bool c0ok = (c0>=0 && c0<SS), c1ok = (c1>=0 && c1<SS);
  float v00 = (r0ok && c0ok) ? base[r0*SS+c0] : 0.f;
  float v01 = (r0ok && c1ok) ? base[r0*SS+c1] : 0.f;
  float v10 = (r1ok && c0ok) ? base[r1*SS+c0] : 0.f;
  float v11 = (r1ok && c1ok) ? base[r1*SS+c1] : 0.f;
  return (1.f-fr)*((1.f-fc)*v00 + fc*v01) + fr*((1.f-fc)*v10 + fc*v11);
}

__global__ __launch_bounds__(256) void radon_fwd_kernel(
    const float* __restrict__ img, const float* __restrict__ imgT,
    const float* __restrict__ trig, float* __restrict__ out){
  int gid  = blockIdx.x*4 + ((int)threadIdx.x >> 6);
  int lane = (int)threadIdx.x & 63;
  if (gid >= NSIN) return;
  int a = gid / DDET;
  int d = gid - a*DDET;
  float ca = trig[a], sa = trig[AANG+a];
  float sd = (float)d - 364.0f;
  float Rc = fmaf(sd, sa, 255.5f);
  float Cc = fmaf(sd, ca, 255.5f);
  float aR = ca, bR = Rc, aC = -sa, bC = Cc;
  const float* base = img;
  if (fabsf(ca) > fabsf(sa)){
    base = imgT;
    float tmp;
    tmp=aR; aR=aC; aC=tmp;
    tmp=bR; bR=bC; bC=tmp;
  }
  float iaR = __builtin_amdgcn_rcpf(aR);
  float iaC = __builtin_amdgcn_rcpf(aC);
  float tiA = -255.5f, tiB = 255.5f;  bool iE=false;
  float teA = -255.5f, teB = 255.5f;  bool eE=false;
  clipr(aR,iaR,bR, 0.001f, 510.999f, tiA,tiB,iE);
  clipr(aC,iaC,bC, 0.001f, 510.999f, tiA,tiB,iE);
  clipr(aR,iaR,bR, -0.999f, 511.999f, teA,teB,eE);
  clipr(aC,iaC,bC, -0.999f, 511.999f, teA,teB,eE);
  float acc = 0.f;
  if (!eE && teA <= teB){
    int eA = max(0,   (int)floorf(teA+255.5f) - 1);
    int eB = min(511, (int)ceilf (teB+255.5f) + 1);
    int iA = (int)ceilf (tiA+255.5f) + 1;
    int iB = (int)floorf(tiB+255.5f) - 1;
    iA = max(iA, eA); iB = min(iB, eB);
    if (iE || iA > iB){
      for (int t = eA+lane; t <= eB; t += 64) acc += samp_guard(base,aR,bR,aC,bC,t);
    } else {
      for (int t = eA+lane;   t <  iA; t += 64) acc += samp_guard(base,aR,bR,aC,bC,t);
      for (int t = iB+1+lane; t <= eB; t += 64) acc += samp_guard(base,aR,bR,aC,bC,t);
      for (int t = iA+lane;   t <= iB; t += 64){
        float tp = (float)t - 255.5f;
        float R = fmaf(aR, tp, bR);
        float C = fmaf(aC, tp, bC);
        int r0 = (int)R, c0 = (int)C;
        float fr = R - (float)r0, fc = C - (float)c0;
        const float* p = base + r0*SS + c0;
        float v00 = p[0], v01 = p[1], v10 = p[SS], v11 = p[SS+1];
        float top = v00 + fc*(v01-v00);
        float bot = v10 + fc*(v11-v10);
        acc += top + fr*(bot-top);
      }
    }
  }
  for (int off=32; off; off>>=1) acc += __shfl_down(acc, off);
  if (lane==0) out[gid] = acc;
}

// ---------------- ramp filter: 4-way k-split, 64 outputs/block ----------------
__global__ __launch_bounds__(256) void filter_kernel2(
    const float* __restrict__ h0, const float* __restrict__ taps,
    float* __restrict__ h1){
  __shared__ float red[256];
  int a  = blockIdx.x / 12;
  int jb = blockIdx.x - a*12;
  int jl = (int)threadIdx.x & 63;
  int kq = (int)threadIdx.x >> 6;
  int j  = jb*64 + jl;
  float acc = 0.f;
  if (j < DDET){
    const float* row = h0 + a*DDET;
    const float* tp  = taps + 728 + j;
    int k0 = kq*183;
    int k1 = min(k0+183, DDET);
    for (int k=k0;k<k1;k++) acc = fmaf(row[k], tp[-k], acc);
  }
  red[threadIdx.x] = acc;
  __syncthreads();
  if ((int)threadIdx.x < 64 && j < DDET){
    float s = red[jl] + red[64+jl] + red[128+jl] + red[192+jl];
    h1[a*DDET + j] = s;
  }
}

// ---------------- backprojection: writes NHWC8 ch5 bf16 hi/lo ----------------
__global__ __launch_bounds__(256) void backproj_kernel(
    const float* __restrict__ h1, const float* __restrict__ trig,
    unsigned short* __restrict__ hi8, unsigned short* __restrict__ lo8){
  __shared__ float sh[AANG*28];
  __shared__ int   sbase[AANG];
  __shared__ float strig[2*AANG];
  int tid = threadIdx.x;
  int x0 = (blockIdx.x & 31) * 16, y0 = (blockIdx.x >> 5) * 16;
  if (tid < 2*AANG) strig[tid] = trig[tid];
  __syncthreads();
  if (tid < AANG){
    float ca = strig[tid], sa = strig[AANG+tid];
    float Xa = (float)x0 - 255.5f, Xb = Xa + 15.f;
    float Ya = (float)y0 - 255.5f, Yb = Ya + 15.f;
    float s00 = Xa*ca + Ya*sa, s01 = Xb*ca + Ya*sa;
    float s10 = Xa*ca + Yb*sa, s11 = Xb*ca + Yb*sa;
    float mn = fminf(fminf(s00,s01), fminf(s10,s11)) + 364.0f;
    sbase[tid] = (int)floorf(mn) - 2;
  }
  __syncthreads();
  for (int s = tid; s < AANG*28; s += 256){
    int a = s / 28, j = s - a*28;
    int idx = sbase[a] + j;
    sh[s] = (idx >= 0 && idx < DDET) ? h1[a*DDET + idx] : 0.f;
  }
  __syncthreads();
  int x = x0 + (tid & 15), y = y0 + (tid >> 4);
  float X = (float)x - 255.5f, Y = (float)y - 255.5f;
  float acc = 0.f;
  #pragma unroll 6
  for (int a=0;a<AANG;a++){
    float sidx = fmaf(X, strig[a], fmaf(Y, strig[AANG+a], 364.0f));
    float ff = floorf(sidx);
    int k = (int)ff - sbase[a];
    float fi = sidx - ff;
    float v0 = sh[a*28+k], v1 = sh[a*28+k+1];
    acc += v0 + fi*(v1-v0);
  }
  unsigned short hb = f2bf(acc);
  float hf = __uint_as_float((unsigned)hb << 16);
  unsigned short lb = f2bf(acc - hf);
  size_t p8 = ((size_t)(y*SS + x))*8 + 5;
  hi8[p8] = hb;
  lo8[p8] = lb;
}

// ---------------- dual conv1 (7->32): cg-split scalar + NHWC bf16 hi/lo epilogue ----
// outputs NHWC [62 rows x DRS x 32] with +1 guard-row offset (row y at y+1)
__global__ __launch_bounds__(256) void conv3x3_dual1(
    const float* __restrict__ in1, int Cin1,
    const float* __restrict__ in2, int Cin2,
    const float* __restrict__ wt,
    const float* __restrict__ bias, const float* __restrict__ prelu,
    unsigned short* __restrict__ outHi, unsigned short* __restrict__ outLo)
{
  const int W = DDET, HW = NSIN;
  int pix = blockIdx.x*256 + (int)threadIdx.x;
  if (pix >= NSIN) return;
  int cg = blockIdx.y;
  int y = pix / W, x = pix - y*W;
  bool ym = y>0, yp = y<AANG-1, xm = x>0, xp = x<W-1;
  float acc[8];
  #pragma unroll
  for (int o=0;o<8;o++) acc[o] = bias[cg*8+o];
  const float* wch = wt + cg*72;
  for (int part=0; part<2; part++){
    const float* src = part ? in2 : in1;
    int nch = part ? Cin2 : Cin1;
    const float* ip = src + pix;
    for (int i=0;i<nch;i++, ip+=HW, wch+=288){
      float p4 = ip[0];
      float p0=0,p1=0,p2=0,p3=0,p5=0,p6=0,p7=0,p8=0;
      if (ym){ p1 = ip[-W]; if (xm) p0 = ip[-W-1]; if (xp) p2 = ip[-W+1]; }
      if (xm) p3 = ip[-1];
      if (xp) p5 = ip[1];
      if (yp){ p7 = ip[W]; if (xm) p6 = ip[W-1]; if (xp) p8 = ip[W+1]; }
      float p[9] = {p0,p1,p2,p3,p4,p5,p6,p7,p8};
      #pragma unroll
      for (int t=0;t<9;t++){
        float v = p[t];
        #pragma unroll
        for (int o=0;o<8;o++) acc[o] = fmaf(v, wch[t*8+o], acc[o]);
      }
    }
  }
  float aa = *prelu;
  short8 vh, vl;
  #pragma unroll
  for (int o=0;o<8;o++){
    float s = acc[o];
    s = (s>=0.f) ? s : aa*s;
    unsigned short hb = f2bf(s);
    float hf = __uint_as_float((unsigned)hb << 16);
    unsigned short lb = f2bf(s - hf);
    vh[o] = (short)hb; vl[o] = (short)lb;
  }
  size_t base = ((size_t)(y+1)*DRS + x)*32 + cg*8;
  *(short8*)(outHi + base) = vh;
  *(short8*)(outLo + base) = vl;
}

// ---------------- dual conv2 (32->32): implicit-GEMM MFMA, 1 wave/block ----------------
__global__ __launch_bounds__(64) void dual_mfma32(
    const unsigned short* __restrict__ hiB, const unsigned short* __restrict__ loB,
    const unsigned short* __restrict__ Bimg,   // this layer: [9][2][2][64][8]
    const float* __restrict__ bias, const float* __restrict__ prelu,
    float* __restrict__ out)
{
  int y  = blockIdx.y;                               // 0..59
  int lane = (int)threadIdx.x;
  int xw = blockIdx.x*64;                            // 0..704 step 64
  int lm = lane & 15, lq = lane >> 4;
  int laneoff = lm*32 + lq*8;
  f32x4 acc[4][2];
  #pragma unroll
  for (int s=0;s<4;s++){ acc[s][0] = (f32x4)0.f; acc[s][1] = (f32x4)0.f; }
  const short8* Bf = (const short8*)Bimg;
  #pragma unroll
  for (int dy=-1; dy<=1; dy++){
    const unsigned short* rh = hiB + (size_t)(y+dy+1)*DRS*32;
    const unsigned short* rl = loB + (size_t)(y+dy+1)*DRS*32;
    #pragma unroll
    for (int dx=-1; dx<=1; dx++){
      int tap = (dy+1)*3 + (dx+1);
      const short8* bp8 = Bf + tap*256 + lane;
      short8 bh0 = bp8[0];     // n=0 hi
      short8 bl0 = bp8[64];    // n=0 lo
      short8 bh1 = bp8[128];   // n=1 hi
      short8 bl1 = bp8[192];   // n=1 lo
      int xoff = (xw + dx)*32 + laneoff;
      #pragma unroll
      for (int s=0; s<4; s++){
        short8 ah = *(const short8*)(rh + xoff + s*512);
        short8 al = *(const short8*)(rl + xoff + s*512);
        acc[s][0] = __builtin_amdgcn_mfma_f32_16x16x32_bf16(ah, bh0, acc[s][0], 0,0,0);
        acc[s][1] = __builtin_amdgcn_mfma_f32_16x16x32_bf16(ah, bh1, acc[s][1], 0,0,0);
        acc[s][0] = __builtin_amdgcn_mfma_f32_16x16x32_bf16(al, bh0, acc[s][0], 0,0,0);
        acc[s][1] = __builtin_amdgcn_mfma_f32_16x16x32_bf16(al, bh1, acc[s][1], 0,0,0);
        acc[s][0] = __builtin_amdgcn_mfma_f32_16x16x32_bf16(ah, bl0, acc[s][0], 0,0,0);
        acc[s][1] = __builtin_amdgcn_mfma_f32_16x16x32_bf16(ah, bl1, acc[s][1], 0,0,0);
      }
    }
  }
  // epilogue: bias + prelu + planar fp32 store (4B-aligned: 729 stride is odd)
  float aa = *prelu;
  #pragma unroll
  for (int s=0;s<4;s++){
    int px0 = xw + s*16 + lq*4;
    #pragma unroll
    for (int n=0;n<2;n++){
      int o = n*16 + lm;
      float bv = bias[o];
      f32x4 v = acc[s][n];
      v.x+=bv; v.y+=bv; v.z+=bv; v.w+=bv;
      v.x=(v.x>=0.f)?v.x:aa*v.x; v.y=(v.y>=0.f)?v.y:aa*v.y;
      v.z=(v.z>=0.f)?v.z:aa*v.z; v.w=(v.w>=0.f)?v.w:aa*v.w;
      float* op = out + (size_t)o*NSIN + y*DDET + px0;
      if (px0 + 3 <= DDET-1){
        v4u st; st.x=v.x; st.y=v.y; st.z=v.z; st.w=v.w;
        *(v4u*)op = st;
      } else {
        if (px0   <= DDET-1) op[0] = v.x;
        if (px0+1 <= DDET-1) op[1] = v.y;
        if (px0+2 <= DDET-1) op[2] = v.z;
      }
    }
  }
}

// ---------------- dual conv3 (32->5): 2-way channel split + LDS reduce ----------------
template<int COUT, int W>
__global__ __launch_bounds__(256) void conv3x3_fast2(
    const float* __restrict__ in1, int Cin1,
    const float* __restrict__ wt,
    const float* __restrict__ bias,
    float* __restrict__ out, int H)
{
  __shared__ float red[128*COUT];
  int HW = H*W;
  int pl = (int)threadIdx.x & 127;
  int half = (int)threadIdx.x >> 7;
  int pix = blockIdx.x*128 + pl;
  bool valid = (pix < HW);
  float acc[COUT];
  #pragma unroll
  for (int o=0;o<COUT;o++) acc[o] = 0.f;
  if (valid){
    int y = pix / W, x = pix - y*W;
    bool ym = y>0, yp = y<H-1, xm = x>0, xp = x<W-1;
    int nch = Cin1 >> 1;
    const float* wr = wt + half*nch*9*COUT;
    const float* ip = in1 + pix + (size_t)half*nch*HW;
    for (int i=0;i<nch;i++, ip+=HW){
      float p4 = ip[0];
      float p0=0,p1=0,p2=0,p3=0,p5=0,p6=0,p7=0,p8=0;
      if (ym){ p1 = ip[-W]; if (xm) p0 = ip[-W-1]; if (xp) p2 = ip[-W+1]; }
      if (xm) p3 = ip[-1];
      if (xp) p5 = ip[1];
      if (yp){ p7 = ip[W]; if (xm) p6 = ip[W-1]; if (xp) p8 = ip[W+1]; }
      float p[9] = {p0,p1,p2,p3,p4,p5,p6,p7,p8};
      #pragma unroll
      for (int t=0;t<9;t++){
        float v = p[t];
        #pragma unroll
        for (int o=0;o<COUT;o++) acc[o] = fmaf(v, wr[t*COUT+o], acc[o]);
      }
      wr += 9*COUT;
    }
  }
  if (half == 1){
    #pragma unroll
    for (int o=0;o<COUT;o++) red[pl*COUT+o] = acc[o];
  }
  __syncthreads();
  if (half == 0 && valid){
    float* op = out + pix;
    #pragma unroll
    for (int o=0;o<COUT;o++)
      op[o*HW] += acc[o] + red[pl*COUT+o] + bias[o];
  }
}

// ---------------- primal conv1 (6->32): implicit-GEMM MFMA on NHWC8 input ----------------
// K = 9 taps x 8 ch = 72 -> 3 k-steps of 32; k = tap_local*8 + ch
__global__ __launch_bounds__(256) void prim1_mfma(
    const unsigned short* __restrict__ hi8, const unsigned short* __restrict__ lo8,  // [512][512][8]
    const unsigned short* __restrict__ Bimg1,   // this layer: [3][2][2][64][8]
    const float* __restrict__ bias, const float* __restrict__ prelu,
    unsigned short* __restrict__ outHi, unsigned short* __restrict__ outLo)
{
  __shared__ unsigned int tr[4][64][33];
  int b = blockIdx.x;                 // 0..1023
  int by = b >> 1, half = b & 1;
  int y = ((by & 7) << 6) | (by >> 3);   // XCD row swizzle
  int wv = (int)threadIdx.x >> 6;
  int lane = (int)threadIdx.x & 63;
  int xw = half*256 + wv*64;
  int lm = lane & 15, lq = lane >> 4;
  f32x4 acc[4][2];
  #pragma unroll
  for (int s=0;s<4;s++){ acc[s][0] = (f32x4)0.f; acc[s][1] = (f32x4)0.f; }
  bool fast = (y>0) && (y<511) && (xw!=0) && (xw!=448);
  const short8* Bf = (const short8*)Bimg1;
  #pragma unroll
  for (int g=0; g<3; g++){
    const short8* bp8 = Bf + g*256 + lane;
    short8 bh0 = bp8[0];
    short8 bl0 = bp8[64];
    short8 bh1 = bp8[128];
    short8 bl1 = bp8[192];
    int t = g*4 + lq; if (t > 8) t = 8;
    int dy = (t >= 6) ? 1 : ((t >= 3) ? 0 : -1);
    int dx = t - (dy+1)*3 - 1;
    int row = y + dy;
    #pragma unroll
    for (int s=0; s<4; s++){
      short8 ah, al;
      int px = xw + s*16 + lm + dx;
      if (fast){
        size_t off = ((size_t)row*SS + px)*8;
        ah = *(const short8*)(hi8 + off);
        al = *(const short8*)(lo8 + off);
      } else {
        bool ok = ((unsigned)row < 512u) && ((unsigned)px < 512u);
        size_t off = ok ? ((size_t)row*SS + px)*8 : 0;
        ah = ok ? *(const short8*)(hi8 + off) : (short8)0;
        al = ok ? *(const short8*)(lo8 + off) : (short8)0;
      }
      acc[s][0] = __builtin_amdgcn_mfma_f32_16x16x32_bf16(ah, bh0, acc[s][0], 0,0,0);
      acc[s][1] = __builtin_amdgcn_mfma_f32_16x16x32_bf16(ah, bh1, acc[s][1], 0,0,0);
      acc[s][0] = __builtin_amdgcn_mfma_f32_16x16x32_bf16(al, bh0, acc[s][0], 0,0,0);
      acc[s][1] = __builtin_amdgcn_mfma_f32_16x16x32_bf16(al, bh1, acc[s][1], 0,0,0);
      acc[s][0] = __builtin_amdgcn_mfma_f32_16x16x32_bf16(ah, bl0, acc[s][0], 0,0,0);
      acc[s][1] = __builtin_amdgcn_mfma_f32_16x16x32_bf16(ah, bl1, acc[s][1], 0,0,0);
    }
  }
  // epilogue: bias + prelu + pack hi/lo into LDS [px][ch], NHWC32 stores
  float aa = *prelu;
  #pragma unroll
  for (int s=0;s<4;s++){
    #pragma unroll
    for (int n=0;n<2;n++){
      int o = n*16 + lm;
      float bv = bias[o];
      f32x4 v = acc[s][n];
      v.x+=bv; v.y+=bv; v.z+=bv; v.w+=bv;
      v.x=(v.x>=0.f)?v.x:aa*v.x; v.y=(v.y>=0.f)?v.y:aa*v.y;
      v.z=(v.z>=0.f)?v.z:aa*v.z; v.w=(v.w>=0.f)?v.w:aa*v.w;
      #pragma unroll
      for (int r=0;r<4;r++){
        float x = v[r];
        unsigned short hb = f2bf(x);
        float hf = __uint_as_float((unsigned)hb << 16);
        unsigned short lb = f2bf(x - hf);
        tr[wv][s*16 + lq*4 + r][o] = ((unsigned)hb << 16) | (unsigned)lb;
      }
    }
  }
  __syncthreads();
  int c8 = lane & 3;
  int pxl = lane >> 2;
  #pragma unroll
  for (int k=0;k<4;k++){
    int px = pxl + k*16;
    short8 vh, vl;
    #pragma unroll
    for (int j=0;j<8;j++){
      unsigned p = tr[wv][px][c8*8 + j];
      vh[j] = (short)(p >> 16);
      vl[j] = (short)(p & 0xffffu);
    }
    size_t base = ((size_t)(y*SS + xw + px))*32 + c8*8;
    *(short8*)(outHi + base) = vh;
    *(short8*)(outLo + base) = vl;
  }
}

// ---------------- primal conv2 (32->32): implicit-GEMM MFMA bf16 hi/lo ----------------
// epilogue: bias+prelu, repack to NHWC bf16 hi/lo via per-wave LDS transpose
__global__ __launch_bounds__(256) void conv_mfma32(
    const unsigned short* __restrict__ hiB, const unsigned short* __restrict__ loB,
    const unsigned short* __restrict__ Bimg,   // this layer: [9][2][2][64][8]
    const float* __restrict__ bias, const float* __restrict__ prelu,
    unsigned short* __restrict__ outHi, unsigned short* __restrict__ outLo)
{
  __shared__ unsigned int tr[4][64][33];
  int b = blockIdx.x;                 // 0..1023
  int by = b >> 1, half = b & 1;
  int y = ((by & 7) << 6) | (by >> 3);   // XCD row swizzle
  int wv = (int)threadIdx.x >> 6;
  int lane = (int)threadIdx.x & 63;
  int xw = half*256 + wv*64;
  int lm = lane & 15, lq = lane >> 4;
  int laneoff = lm*32 + lq*8;
  f32x4 acc[4][2];
  #pragma unroll
  for (int s=0;s<4;s++){ acc[s][0] = (f32x4)0.f; acc[s][1] = (f32x4)0.f; }
  bool fastx = (xw != 0) && (xw != 448);
  const short8* Bf = (const short8*)Bimg;
  #pragma unroll
  for (int dy=-1; dy<=1; dy++){
    int yy = y + dy;
    if ((unsigned)yy >= 512u) continue;
    const unsigned short* rh = hiB + (size_t)yy*512*32;
    const unsigned short* rl = loB + (size_t)yy*512*32;
    #pragma unroll
    for (int dx=-1; dx<=1; dx++){
      int tap = (dy+1)*3 + (dx+1);
      const short8* bp8 = Bf + tap*256 + lane;
      short8 bh0 = bp8[0];     // n=0 hi
      short8 bl0 = bp8[64];    // n=0 lo
      short8 bh1 = bp8[128];   // n=1 hi
      short8 bl1 = bp8[192];   // n=1 lo
      int xoff = (xw + dx)*32 + laneoff;
      #pragma unroll
      for (int s=0; s<4; s++){
        short8 ah, al;
        const unsigned short* ph = rh + xoff + s*512;
        const unsigned short* pl = rl + xoff + s*512;
        if (fastx){
          ah = *(const short8*)ph;
          al = *(const short8*)pl;
        } else {
          int x = xw + s*16 + lm + dx;
          bool ok = ((unsigned)x < 512u);
          ah = ok ? *(const short8*)ph : (short8)0;
          al = ok ? *(const short8*)pl : (short8)0;
        }
        acc[s][0] = __builtin_amdgcn_mfma_f32_16x16x32_bf16(ah, bh0, acc[s][0], 0,0,0);
        acc[s][1] = __builtin_amdgcn_mfma_f32_16x16x32_bf16(ah, bh1, acc[s][1], 0,0,0);
        acc[s][0] = __builtin_amdgcn_mfma_f32_16x16x32_bf16(al, bh0, acc[s][0], 0,0,0);
        acc[s][1] = __builtin_amdgcn_mfma_f32_16x16x32_bf16(al, bh1, acc[s][1], 0,0,0);
        acc[s][0] = __builtin_amdgcn_mfma_f32_16x16x32_bf16(ah, bl0, acc[s][0], 0,0,0);
        acc[s][1] = __builtin_amdgcn_mfma_f32_16x16x32_bf16(ah, bl1, acc[s][1], 0,0,0);
      }
    }
  }
  // epilogue: bias + prelu + pack hi/lo into LDS [px][ch]
  float aa = *prelu;
  #pragma unroll
  for (int s=0;s<4;s++){
    #pragma unroll
    for (int n=0;n<2;n++){
      int o = n*16 + lm;
      float bv = bias[o];
      f32x4 v = acc[s][n];
      v.x+=bv; v.y+=bv; v.z+=bv; v.w+=bv;
      v.x=(v.x>=0.f)?v.x:aa*v.x; v.y=(v.y>=0.f)?v.y:aa*v.y;
      v.z=(v.z>=0.f)?v.z:aa*v.z; v.w=(v.w>=0.f)?v.w:aa*v.w;
      #pragma unroll
      for (int r=0;r<4;r++){
        float x = v[r];
        unsigned short hb = f2bf(x);
        float hf = __uint_as_float((unsigned)hb << 16);
        unsigned short lb = f2bf(x - hf);
        tr[wv][s*16 + lq*4 + r][o] = ((unsigned)hb << 16) | (unsigned)lb;
      }
    }
  }
  __syncthreads();
  // read channel-contiguous, split, coalesced NHWC stores
  int c8 = lane & 3;             // 8-channel chunk
  int pxl = lane >> 2;           // 0..15
  #pragma unroll
  for (int k=0;k<4;k++){
    int px = pxl + k*16;
    short8 vh, vl;
    #pragma unroll
    for (int j=0;j<8;j++){
      unsigned p = tr[wv][px][c8*8 + j];
      vh[j] = (short)(p >> 16);
      vl[j] = (short)(p & 0xffffu);
    }
    size_t base = ((size_t)(y*SS + xw + px))*32 + c8*8;
    *(short8*)(outHi + base) = vh;
    *(short8*)(outLo + base) = vl;
  }
}

// ---------------- primal conv3 (32->5): implicit-GEMM MFMA, N=16 (5 real) ----------------
// accumulates into f; writes imgT (ch1), final output (ch0), and NHWC8 ch0-4 for next conv1
__global__ __launch_bounds__(256) void duo_mfma(
    const unsigned short* __restrict__ hiB, const unsigned short* __restrict__ loB,
    const unsigned short* __restrict__ Bimg3,   // this layer: [9][2][64][8]
    const float* __restrict__ bias,
    float* __restrict__ f,
    float* __restrict__ fout, float* __restrict__ tout,
    unsigned short* __restrict__ hi8, unsigned short* __restrict__ lo8)
{
  __shared__ unsigned int t8[4][64][6];
  int b = blockIdx.x;                 // 0..1023
  int by = b >> 1, half = b & 1;
  int y = ((by & 7) << 6) | (by >> 3);   // XCD row swizzle
  int wv = (int)threadIdx.x >> 6;
  int lane = (int)threadIdx.x & 63;
  int xw = half*256 + wv*64;
  int lm = lane & 15, lq = lane >> 4;
  int laneoff = lm*32 + lq*8;
  f32x4 acc[4];
  #pragma unroll
  for (int s=0;s<4;s++) acc[s] = (f32x4)0.f;
  bool fastx = (xw != 0) && (xw != 448);
  const short8* Bf = (const short8*)Bimg3;
  #pragma unroll
  for (int dy=-1; dy<=1; dy++){
    int yy = y + dy;
    if ((unsigned)yy >= 512u) continue;
    const unsigned short* rh = hiB + (size_t)yy*512*32;
    const unsigned short* rl = loB + (size_t)yy*512*32;
    #pragma unroll
    for (int dx=-1; dx<=1; dx++){
      int tap = (dy+1)*3 + (dx+1);
      const short8* bp8 = Bf + tap*128 + lane;
      short8 bh = bp8[0];
      short8 bl = bp8[64];
      int xoff = (xw + dx)*32 + laneoff;
      #pragma unroll
      for (int s=0; s<4; s++){
        short8 ah, al;
        const unsigned short* ph = rh + xoff + s*512;
        const unsigned short* pl = rl + xoff + s*512;
        if (fastx){
          ah = *(const short8*)ph;
          al = *(const short8*)pl;
        } else {
          int x = xw + s*16 + lm + dx;
          bool ok = ((unsigned)x < 512u);
          ah = ok ? *(const short8*)ph : (short8)0;
          al = ok ? *(const short8*)pl : (short8)0;
        }
        acc[s] = __builtin_amdgcn_mfma_f32_16x16x32_bf16(ah, bh, acc[s], 0,0,0);
        acc[s] = __builtin_amdgcn_mfma_f32_16x16x32_bf16(al, bh, acc[s], 0,0,0);
        acc[s] = __builtin_amdgcn_mfma_f32_16x16x32_bf16(ah, bl, acc[s], 0,0,0);
      }
    }
  }
  // epilogue: f += conv3 + bias on lanes lm<5; imgT transpose (lm==1); output rep (lm==0)
  if (lm < 5){
    float bv = bias[lm];
    #pragma unroll
    for (int s=0;s<4;s++){
      int px0 = xw + s*16 + lq*4;
      float* op = f + (size_t)lm*NPIX + y*SS + px0;
      f32x4 old = *(const f32x4*)op;
      f32x4 v = acc[s];
      v.x += old.x + bv; v.y += old.y + bv;
      v.z += old.z + bv; v.w += old.w + bv;
      *(f32x4*)op = v;
      #pragma unroll
      for (int r=0;r<4;r++){
        float x = v[r];
        unsigned short hb = f2bf(x);
        float hf = __uint_as_float((unsigned)hb << 16);
        unsigned short lb = f2bf(x - hf);
        t8[wv][s*16 + lq*4 + r][lm] = ((unsigned)hb << 16) | (unsigned)lb;
      }
      if (lm == 1){
        tout[(px0  )*SS + y] = v.x;
        tout[(px0+1)*SS + y] = v.y;
        tout[(px0+2)*SS + y] = v.z;
        tout[(px0+3)*SS + y] = v.w;
      }
      if (lm == 0 && fout){
        float* q = fout + y*SS + px0;
        *(f32x4*)q = v;
        *(f32x4*)(q + NPIX) = v;
        *(f32x4*)(q + 2*NPIX) = v;
      }
    }
  }
  __syncthreads();
  // readout: lane = px; write NHWC8 ch0-4 (8B + 2B stores, hi and lo)
  {
    unsigned c0 = t8[wv][lane][0], c1 = t8[wv][lane][1], c2 = t8[wv][lane][2];
    unsigned c3 = t8[wv][lane][3], c4 = t8[wv][lane][4];
    size_t base = ((size_t)(y*SS + xw + lane))*8;
    short4v vh; vh[0]=(short)(c0>>16); vh[1]=(short)(c1>>16); vh[2]=(short)(c2>>16); vh[3]=(short)(c3>>16);
    short4v vl; vl[0]=(short)(c0&0xffffu); vl[1]=(short)(c1&0xffffu); vl[2]=(short)(c2&0xffffu); vl[3]=(short)(c3&0xffffu);
    *(short4v*)(hi8 + base) = vh;
    *(short4v*)(lo8 + base) = vl;
    hi8[base+4] = (unsigned short)(c4>>16);
    lo8[base+4] = (unsigned short)(c4&0xffffu);
  }
}

extern "C" void kernel_launch(void* const* d_in, const int* in_sizes, int n_in,
                              void* d_out, int out_size, void* d_ws, size_t ws_size,
                              hipStream_t stream){
  const float* g     = (const float*)d_in[2];
  const float* theta = (const float*)d_in[3];
  const float* dw1 = (const float*)d_in[5];
  const float* db1 = (const float*)d_in[6];
  const float* da1 = (const float*)d_in[7];
  const float* dw2 = (const float*)d_in[8];
  const float* db2 = (const float*)d_in[9];
  const float* da2 = (const float*)d_in[10];
  const float* dw3 = (const float*)d_in[11];
  const float* db3 = (const float*)d_in[12];
  const float* pw1 = (const float*)d_in[13];
  const float* pb1 = (const float*)d_in[14];
  const float* pa1 = (const float*)d_in[15];
  const float* pw2 = (const float*)d_in[16];
  const float* pb2 = (const float*)d_in[17];
  const float* pa2 = (const float*)d_in[18];
  const float* pw3 = (const float*)d_in[19];
  const float* pb3 = (const float*)d_in[20];

  float* ws     = (float*)d_ws;
  float* trig   = ws;                    // 128
  float* taps   = ws + 128;              // -> 2048
  float* h      = ws + 2048;             // 5*NSIN
  float* opf    = h + 5*NSIN;            // NSIN
  float* gcopy  = opf + NSIN;            // NSIN
  float* h1     = gcopy + NSIN;          // NSIN
  float* f      = h1 + NSIN;             // 5*NPIX
  float* bp     = f + 5*NPIX;            // NPIX (unused, keeps layout)
  float* imgT   = bp + NPIX;             // NPIX
  float* dualT1 = imgT + NPIX;           // 32*NSIN (unused, keeps layout)
  float* dualT2 = dualT1 + 32*NSIN;      // 32*NSIN
  float* primT2slot = dualT2 + 32*NSIN;  // 32*NPIX floats of space
  unsigned short* primHi = (unsigned short*)primT2slot;          // 32*NPIX ushorts
  unsigned short* primLo = primHi + (size_t)32*NPIX;             // 32*NPIX ushorts
  unsigned short* nhwcHi = (unsigned short*)(primT2slot + 32*NPIX);  // 32*NPIX ushorts
  unsigned short* nhwcLo = nhwcHi + (size_t)32*NPIX;             // 32*NPIX ushorts
  float* wsp   = (float*)(nhwcLo + (size_t)32*NPIX);
  float* wtd3  = wsp;                    // 14400
  float* wtp3  = wsp + 14400;            // 14400 (unused now)
  float* wtd1b = wsp + 28800;            // 20160
  float* wtd2b = wsp + 48960;            // 92160 (unused, keeps layout)
  float* wtp1b = wsp + 141120;           // 17280 (unused now)
  unsigned short* Bimg  = (unsigned short*)(wsp + 158400);       // 184320 ushorts
  unsigned short* Bimg2 = Bimg + 184320;                         // 184320 ushorts
  unsigned short* Bimg3 = Bimg2 + 184320;                        // 92160 ushorts
  unsigned short* Bimg1 = Bimg3 + 92160;                         // 61440 ushorts
  // dual NHWC hi/lo: 62 rows x DRS x 32ch + 64-ushort zero prefix/suffix
  const size_t DUALSZ = (size_t)64 + (size_t)62*DRS*32 + 64;
  unsigned short* dualHiRaw = Bimg1 + 61440;
  unsigned short* dualLoRaw = dualHiRaw + DUALSZ;
  unsigned short* dualHi = dualHiRaw + 64;
  unsigned short* dualLo = dualLoRaw + 64;
  // primal NHWC8 input image [512][512][8] bf16 hi/lo
  unsigned short* nh8Hi = dualLoRaw + DUALSZ;
  unsigned short* nh8Lo = nh8Hi + (size_t)NPIX*8;

  hipMemsetAsync(h, 0, (size_t)(5*NSIN)*sizeof(float), stream);
  hipMemsetAsync(f, 0, (size_t)(7*NPIX)*sizeof(float), stream);   // f, bp, imgT
  hipMemsetAsync(dualHiRaw, 0, 2*DUALSZ*sizeof(unsigned short), stream); // zero pads once
  hipMemsetAsync(nh8Hi, 0, (size_t)2*NPIX*8*sizeof(unsigned short), stream); // zero once
  hipMemcpyAsync(gcopy, g, (size_t)NSIN*sizeof(float), hipMemcpyDeviceToDevice, stream);
  trig_kernel<<<1,64,0,stream>>>(theta, trig);
  taps_kernel<<<NTAPS,256,0,stream>>>(taps);
  transpose_all<<<(28800+255)/256,256,0,stream>>>(dw3,wtd3, pw3,wtp3);
  transpose_w8<<<(20160+255)/256,256,0,stream>>>(dw1, wtd1b, 7);
  prep_bimg<<<(92160+255)/256,256,0,stream>>>(pw2, Bimg);
  prep_bimg<<<(92160+255)/256,256,0,stream>>>(dw2, Bimg2);
  prep_bimg3<<<(46080+255)/256,256,0,stream>>>(pw3, Bimg3);
  prep_bimg1<<<(30720+255)/256,256,0,stream>>>(pw1, Bimg1);

  const int GD = (NSIN+255)/256;       // 171

  for (int i=0;i<10;i++){
    radon_fwd_kernel<<<(NSIN+3)/4,256,0,stream>>>(f + NPIX, imgT, trig, opf);
    // dual block: in = [h(5) | opf | g] (opf,gcopy contiguous after h)
    conv3x3_dual1<<<dim3(GD,4),256,0,stream>>>(h, 5, opf, 2, wtd1b+(size_t)i*7*288,
                                               db1+(size_t)i*32, da1+i, dualHi, dualLo);
    dual_mfma32<<<dim3(12,AANG),64,0,stream>>>(dualHi, dualLo, Bimg2+(size_t)i*18432,
                                               db2+(size_t)i*32, da2+i, dualT2);
    conv3x3_fast2<5,DDET><<<(NSIN+127)/128,256,0,stream>>>(dualT2, 32, wtd3+i*1440, db3+(size_t)i*5, h, AANG);
    filter_kernel2<<<AANG*12,256,0,stream>>>(h, taps, h1);
    backproj_kernel<<<NPIX/256,256,0,stream>>>(h1, trig, nh8Hi, nh8Lo);
    // primal block: NHWC8 [f(5)|bp|0|0] -> conv1 -> conv2 -> conv3
    prim1_mfma<<<1024,256,0,stream>>>(nh8Hi, nh8Lo, Bimg1+(size_t)i*6144,
                                      pb1+(size_t)i*32, pa1+i, nhwcHi, nhwcLo);
    conv_mfma32<<<1024,256,0,stream>>>(nhwcHi, nhwcLo, Bimg+(size_t)i*18432, pb2+(size_t)i*32, pa2+i, primHi, primLo);
    duo_mfma<<<1024,256,0,stream>>>(primHi, primLo, Bimg3+(size_t)i*9216, pb3+(size_t)i*5, f,
                                    (i==9) ? (float*)d_out : nullptr, imgT, nh8Hi, nh8Lo);
  }
}

// Round 6
// 1849.833 us; speedup vs baseline: 1.2534x; 1.0173x over previous
//
#include <hip/hip_runtime.h>
#include <math.h>

#define SS 512
#define AANG 60
#define DDET 729
#define NPIX (SS*SS)        // 262144
#define NSIN (AANG*DDET)    // 43740
#define NTAPS 1457
#define DRS 768             // dual NHWC padded row stride

typedef float v4u __attribute__((ext_vector_type(4), aligned(4)));
typedef float v4a __attribute__((ext_vector_type(4), aligned(16)));
typedef float v2u __attribute__((ext_vector_type(2), aligned(8)));
typedef float v2a __attribute__((ext_vector_type(2), aligned(4)));
typedef short short8 __attribute__((ext_vector_type(8)));
typedef short short4v __attribute__((ext_vector_type(4)));
typedef float f32x4 __attribute__((ext_vector_type(4)));

// round-to-nearest-even fp32 -> bf16 bits
__device__ inline unsigned short f2bf(float x){
  unsigned u = __float_as_uint(x);
  return (unsigned short)((u + 0x7fffu + ((u >> 16) & 1u)) >> 16);
}

// ---------------- trig table ----------------
__global__ void trig_kernel(const float* __restrict__ theta, float* __restrict__ trig){
  int a = threadIdx.x;
  if (a < AANG){ trig[a] = cosf(theta[a]); trig[AANG+a] = sinf(theta[a]); }
}

// ---------------- ramp-filter taps ----------------
__global__ void taps_kernel(float* __restrict__ taps){
  __shared__ double red[256];
  int m  = blockIdx.x;
  int mm = m - 728;
  double s = 0.0;
  for (int k = 1 + (int)threadIdx.x; k <= 1023; k += 256){
    int phase = (k*mm) & 2047;
    s += (double)k * cos((double)phase * (M_PI/1024.0));
  }
  red[threadIdx.x] = s;
  __syncthreads();
  for (int off=128; off; off>>=1){
    if ((int)threadIdx.x < off) red[threadIdx.x] += red[threadIdx.x+off];
    __syncthreads();
  }
  if (threadIdx.x==0){
    double x = (red[0]*(1.0/512.0) + ((mm & 1) ? -1.0 : 1.0)) / 2048.0;
    taps[m] = (float)(x * (M_PI/120.0));
  }
}

// ---------------- conv3 weight transposes: -> [L][Cin][9][5] ----------------
__global__ void transpose_all(const float* __restrict__ s2, float* __restrict__ d2,
                              const float* __restrict__ s5, float* __restrict__ d5){
  int idx = blockIdx.x*256 + (int)threadIdx.x;
  const float* src; float* dst;
  int Cout = 5, Cin = 32;
  if      (idx < 14400){              src=s2; dst=d2; }
  else if (idx < 28800){ idx-=14400;  src=s5; dst=d5; }
  else return;
  int t = idx % 9; int r = idx/9;
  int i = r % Cin; r /= Cin;
  int o = r % Cout; int l = r/Cout;
  dst[((l*Cin+i)*9+t)*Cout+o] = src[idx];
}

// -------- MFMA B-fragment image: [L][tap=9][n=2][prod=2][lane=64][8] bf16 --------
// works for any [L][32][32][3][3] weight tensor (pw2 and dw2)
__global__ void prep_bimg(const float* __restrict__ w, unsigned short* __restrict__ B){
  int idx = blockIdx.x*256 + (int)threadIdx.x;
  if (idx >= 10*9*2*64*8) return;
  int j    =  idx        & 7;
  int lane = (idx >> 3)  & 63;
  int n    = (idx >> 9)  & 1;
  int r    =  idx >> 10;          // l*9 + tap
  int tap = r % 9, l = r / 9;
  int c = (lane >> 4)*8 + j;      // k = channel
  int o = n*16 + (lane & 15);     // output channel
  float x = w[(((size_t)(l*32+o)*32 + c)*9) + tap];
  unsigned short hb = f2bf(x);
  float hf = __uint_as_float((unsigned)hb << 16);
  unsigned short lb = f2bf(x - hf);
  size_t d = (size_t)l*18432 + (size_t)tap*2048 + n*1024 + lane*8 + j;
  B[d]       = hb;
  B[d + 512] = lb;
}

// -------- MFMA B-fragment image for pw3 [L][5][32][3][3]: [L][tap=9][prod=2][lane=64][8] --------
__global__ void prep_bimg3(const float* __restrict__ w, unsigned short* __restrict__ B){
  int idx = blockIdx.x*256 + (int)threadIdx.x;
  if (idx >= 10*9*64*8) return;
  int j    =  idx       & 7;
  int lane = (idx >> 3) & 63;
  int r    =  idx >> 9;           // l*9 + tap
  int tap = r % 9, l = r / 9;
  int c = (lane >> 4)*8 + j;      // k = channel
  int o = lane & 15;              // output channel (5 real)
  float x = (o < 5) ? w[(((size_t)(l*5+o)*32 + c)*9) + tap] : 0.f;
  unsigned short hb = f2bf(x);
  float hf = __uint_as_float((unsigned)hb << 16);
  unsigned short lb = f2bf(x - hf);
  size_t d = (size_t)l*9216 + (size_t)tap*1024 + lane*8 + j;
  B[d]       = hb;
  B[d + 512] = lb;
}

// -------- MFMA B-fragment image for NHWC8 conv1 weights [L][32][Cin][3][3] --------
// layout [L][g=3][n=2][prod=2][64][8]; k = tap_local*8 + ch; t = g*4+tap_local
__global__ void prep_bimg1c(const float* __restrict__ w, unsigned short* __restrict__ B, int Cin){
  int idx = blockIdx.x*256 + (int)threadIdx.x;
  if (idx >= 10*3*2*64*8) return;
  int j    =  idx       & 7;
  int lane = (idx >> 3) & 63;
  int n    = (idx >> 9) & 1;
  int r    =  idx >> 10;          // l*3 + g
  int g = r % 3, l = r / 3;
  int t = g*4 + (lane >> 4);
  int o = n*16 + (lane & 15);
  float x = (t < 9 && j < Cin) ? w[(((size_t)(l*32+o)*Cin + j)*9) + t] : 0.f;
  unsigned short hb = f2bf(x);
  float hf = __uint_as_float((unsigned)hb << 16);
  unsigned short lb = f2bf(x - hf);
  size_t d = (size_t)l*6144 + (size_t)g*2048 + n*1024 + lane*8 + j;
  B[d]       = hb;
  B[d + 512] = lb;
}

// ---------------- g -> sinogram NHWC8 ch6 (once) ----------------
__global__ void g_to_nhwc8(const float* __restrict__ g,
                           unsigned short* __restrict__ s8hi, unsigned short* __restrict__ s8lo){
  int idx = blockIdx.x*256 + (int)threadIdx.x;
  if (idx >= NSIN) return;
  int a = idx / DDET, d = idx - a*DDET;
  float x = g[idx];
  unsigned short hb = f2bf(x);
  float hf = __uint_as_float((unsigned)hb << 16);
  unsigned short lb = f2bf(x - hf);
  size_t p8 = ((size_t)(a+1)*DRS + d)*8 + 6;
  s8hi[p8] = hb;
  s8lo[p8] = lb;
}

// ---------------- radon forward: rcp-hoisted clip; writes NHWC8sin ch5 ----------------
__device__ inline void clipr(float al, float ial, float be, float lo, float hi,
                             float& A, float& B, bool& empty){
  if (fabsf(al) < 1e-7f){ if (be < lo || be > hi) empty = true; return; }
  float t0 = (lo - be)*ial, t1 = (hi - be)*ial;
  float mn = fminf(t0,t1), mx = fmaxf(t0,t1);
  A = fmaxf(A, mn); B = fminf(B, mx);
}

__device__ inline float samp_guard(const float* __restrict__ base, float aR, float bR,
                                   float aC, float bC, int t){
  float tp = (float)t - 255.5f;
  float R = fmaf(aR, tp, bR);
  float C = fmaf(aC, tp, bC);
  float rf = floorf(R), cf = floorf(C);
  int r0 = (int)rf, c0 = (int)cf;
  int r1 = r0+1,    c1 = c0+1;
  float fr = R - rf, fc = C - cf;
  bool r0ok = (r0>=0 && r0<SS), r1ok = (r1>=0 && r1<SS);
  bool c0ok = (c0>=0 && c0<SS), c1ok = (c1>=0 && c1<SS);
  float v00 = (r0ok && c0ok) ? base[r0*SS+c0] : 0.f;
  float v01 = (r0ok && c1ok) ? base[r0*SS+c1] : 0.f;
  float v10 = (r1ok && c0ok) ? base[r1*SS+c0] : 0.f;
  float v11 = (r1ok && c1ok) ? base[r1*SS+c1] : 0.f;
  return (1.f-fr)*((1.f-fc)*v00 + fc*v01) + fr*((1.f-fc)*v10 + fc*v11);
}

__global__ __launch_bounds__(256) void radon_fwd_kernel(
    const float* __restrict__ img, const float* __restrict__ imgT,
    const float* __restrict__ trig,
    unsigned short* __restrict__ s8hi, unsigned short* __restrict__ s8lo){
  int gid  = blockIdx.x*4 + ((int)threadIdx.x >> 6);
  int lane = (int)threadIdx.x & 63;
  if (gid >= NSIN) return;
  int a = gid / DDET;
  int d = gid - a*DDET;
  float ca = trig[a], sa = trig[AANG+a];
  float sd = (float)d - 364.0f;
  float Rc = fmaf(sd, sa, 255.5f);
  float Cc = fmaf(sd, ca, 255.5f);
  float aR = ca, bR = Rc, aC = -sa, bC = Cc;
  const float* base = img;
  if (fabsf(ca) > fabsf(sa)){
    base = imgT;
    float tmp;
    tmp=aR; aR=aC; aC=tmp;
    tmp=bR; bR=bC; bC=tmp;
  }
  float iaR = __builtin_amdgcn_rcpf(aR);
  float iaC = __builtin_amdgcn_rcpf(aC);
  float tiA = -255.5f, tiB = 255.5f;  bool iE=false;
  float teA = -255.5f, teB = 255.5f;  bool eE=false;
  clipr(aR,iaR,bR, 0.001f, 510.999f, tiA,tiB,iE);
  clipr(aC,iaC,bC, 0.001f, 510.999f, tiA,tiB,iE);
  clipr(aR,iaR,bR, -0.999f, 511.999f, teA,teB,eE);
  clipr(aC,iaC,bC, -0.999f, 511.999f, teA,teB,eE);
  float acc = 0.f;
  if (!eE && teA <= teB){
    int eA = max(0,   (int)floorf(teA+255.5f) - 1);
    int eB = min(511, (int)ceilf (teB+255.5f) + 1);
    int iA = (int)ceilf (tiA+255.5f) + 1;
    int iB = (int)floorf(tiB+255.5f) - 1;
    iA = max(iA, eA); iB = min(iB, eB);
    if (iE || iA > iB){
      for (int t = eA+lane; t <= eB; t += 64) acc += samp_guard(base,aR,bR,aC,bC,t);
    } else {
      for (int t = eA+lane;   t <  iA; t += 64) acc += samp_guard(base,aR,bR,aC,bC,t);
      for (int t = iB+1+lane; t <= eB; t += 64) acc += samp_guard(base,aR,bR,aC,bC,t);
      for (int t = iA+lane;   t <= iB; t += 64){
        float tp = (float)t - 255.5f;
        float R = fmaf(aR, tp, bR);
        float C = fmaf(aC, tp, bC);
        int r0 = (int)R, c0 = (int)C;
        float fr = R - (float)r0, fc = C - (float)c0;
        const float* p = base + r0*SS + c0;
        float v00 = p[0], v01 = p[1], v10 = p[SS], v11 = p[SS+1];
        float top = v00 + fc*(v01-v00);
        float bot = v10 + fc*(v11-v10);
        acc += top + fr*(bot-top);
      }
    }
  }
  for (int off=32; off; off>>=1) acc += __shfl_down(acc, off);
  if (lane==0){
    unsigned short hb = f2bf(acc);
    float hf = __uint_as_float((unsigned)hb << 16);
    unsigned short lb = f2bf(acc - hf);
    size_t p8 = ((size_t)(a+1)*DRS + d)*8 + 5;
    s8hi[p8] = hb;
    s8lo[p8] = lb;
  }
}

// ---------------- ramp filter: 4-way k-split, 64 outputs/block ----------------
__global__ __launch_bounds__(256) void filter_kernel2(
    const float* __restrict__ h0, const float* __restrict__ taps,
    float* __restrict__ h1){
  __shared__ float red[256];
  int a  = blockIdx.x / 12;
  int jb = blockIdx.x - a*12;
  int jl = (int)threadIdx.x & 63;
  int kq = (int)threadIdx.x >> 6;
  int j  = jb*64 + jl;
  float acc = 0.f;
  if (j < DDET){
    const float* row = h0 + a*DDET;
    const float* tp  = taps + 728 + j;
    int k0 = kq*183;
    int k1 = min(k0+183, DDET);
    for (int k=k0;k<k1;k++) acc = fmaf(row[k], tp[-k], acc);
  }
  red[threadIdx.x] = acc;
  __syncthreads();
  if ((int)threadIdx.x < 64 && j < DDET){
    float s = red[jl] + red[64+jl] + red[128+jl] + red[192+jl];
    h1[a*DDET + j] = s;
  }
}

// ---------------- backprojection: writes NHWC8 ch5 bf16 hi/lo ----------------
__global__ __launch_bounds__(256) void backproj_kernel(
    const float* __restrict__ h1, const float* __restrict__ trig,
    unsigned short* __restrict__ hi8, unsigned short* __restrict__ lo8){
  __shared__ float sh[AANG*28];
  __shared__ int   sbase[AANG];
  __shared__ float strig[2*AANG];
  int tid = threadIdx.x;
  int x0 = (blockIdx.x & 31) * 16, y0 = (blockIdx.x >> 5) * 16;
  if (tid < 2*AANG) strig[tid] = trig[tid];
  __syncthreads();
  if (tid < AANG){
    float ca = strig[tid], sa = strig[AANG+tid];
    float Xa = (float)x0 - 255.5f, Xb = Xa + 15.f;
    float Ya = (float)y0 - 255.5f, Yb = Ya + 15.f;
    float s00 = Xa*ca + Ya*sa, s01 = Xb*ca + Ya*sa;
    float s10 = Xa*ca + Yb*sa, s11 = Xb*ca + Yb*sa;
    float mn = fminf(fminf(s00,s01), fminf(s10,s11)) + 364.0f;
    sbase[tid] = (int)floorf(mn) - 2;
  }
  __syncthreads();
  for (int s = tid; s < AANG*28; s += 256){
    int a = s / 28, j = s - a*28;
    int idx = sbase[a] + j;
    sh[s] = (idx >= 0 && idx < DDET) ? h1[a*DDET + idx] : 0.f;
  }
  __syncthreads();
  int x = x0 + (tid & 15), y = y0 + (tid >> 4);
  float X = (float)x - 255.5f, Y = (float)y - 255.5f;
  float acc = 0.f;
  #pragma unroll 6
  for (int a=0;a<AANG;a++){
    float sidx = fmaf(X, strig[a], fmaf(Y, strig[AANG+a], 364.0f));
    float ff = floorf(sidx);
    int k = (int)ff - sbase[a];
    float fi = sidx - ff;
    float v0 = sh[a*28+k], v1 = sh[a*28+k+1];
    acc += v0 + fi*(v1-v0);
  }
  unsigned short hb = f2bf(acc);
  float hf = __uint_as_float((unsigned)hb << 16);
  unsigned short lb = f2bf(acc - hf);
  size_t p8 = ((size_t)(y*SS + x))*8 + 5;
  hi8[p8] = hb;
  lo8[p8] = lb;
}

// ---------------- dual conv1 (7->32): implicit-GEMM MFMA on sinogram NHWC8 ----------------
// K = 9 taps x 8 ch = 72 -> 3 k-steps; all loads unguarded via zero pads
__global__ __launch_bounds__(64) void dual1_mfma(
    const unsigned short* __restrict__ hi8, const unsigned short* __restrict__ lo8,  // [62][DRS][8]
    const unsigned short* __restrict__ Bimg1d,   // this layer: [3][2][2][64][8]
    const float* __restrict__ bias, const float* __restrict__ prelu,
    unsigned short* __restrict__ outHi, unsigned short* __restrict__ outLo)
{
  __shared__ unsigned int tr[64][33];
  int y  = blockIdx.y;                 // 0..59
  int lane = (int)threadIdx.x;
  int xw = blockIdx.x*64;              // 0..704
  int lm = lane & 15, lq = lane >> 4;
  f32x4 acc[4][2];
  #pragma unroll
  for (int s=0;s<4;s++){ acc[s][0] = (f32x4)0.f; acc[s][1] = (f32x4)0.f; }
  const short8* Bf = (const short8*)Bimg1d;
  #pragma unroll
  for (int g=0; g<3; g++){
    const short8* bp8 = Bf + g*256 + lane;
    short8 bh0 = bp8[0];
    short8 bl0 = bp8[64];
    short8 bh1 = bp8[128];
    short8 bl1 = bp8[192];
    int t = g*4 + lq; if (t > 8) t = 8;
    int dy = (t >= 6) ? 1 : ((t >= 3) ? 0 : -1);
    int dx = t - (dy+1)*3 - 1;
    int row = y + dy + 1;              // +1 guard-row offset
    #pragma unroll
    for (int s=0; s<4; s++){
      int px = xw + s*16 + lm + dx;
      size_t off = (size_t)(row*DRS + px)*8;
      short8 ah = *(const short8*)(hi8 + off);
      short8 al = *(const short8*)(lo8 + off);
      acc[s][0] = __builtin_amdgcn_mfma_f32_16x16x32_bf16(ah, bh0, acc[s][0], 0,0,0);
      acc[s][1] = __builtin_amdgcn_mfma_f32_16x16x32_bf16(ah, bh1, acc[s][1], 0,0,0);
      acc[s][0] = __builtin_amdgcn_mfma_f32_16x16x32_bf16(al, bh0, acc[s][0], 0,0,0);
      acc[s][1] = __builtin_amdgcn_mfma_f32_16x16x32_bf16(al, bh1, acc[s][1], 0,0,0);
      acc[s][0] = __builtin_amdgcn_mfma_f32_16x16x32_bf16(ah, bl0, acc[s][0], 0,0,0);
      acc[s][1] = __builtin_amdgcn_mfma_f32_16x16x32_bf16(ah, bl1, acc[s][1], 0,0,0);
    }
  }
  // epilogue: bias + prelu + LDS transpose -> NHWC32 hi/lo (store-masked x<=728)
  float aa = *prelu;
  #pragma unroll
  for (int s=0;s<4;s++){
    #pragma unroll
    for (int n=0;n<2;n++){
      int o = n*16 + lm;
      float bv = bias[o];
      f32x4 v = acc[s][n];
      v.x+=bv; v.y+=bv; v.z+=bv; v.w+=bv;
      v.x=(v.x>=0.f)?v.x:aa*v.x; v.y=(v.y>=0.f)?v.y:aa*v.y;
      v.z=(v.z>=0.f)?v.z:aa*v.z; v.w=(v.w>=0.f)?v.w:aa*v.w;
      #pragma unroll
      for (int r=0;r<4;r++){
        float x = v[r];
        unsigned short hb = f2bf(x);
        float hf = __uint_as_float((unsigned)hb << 16);
        unsigned short lb = f2bf(x - hf);
        tr[s*16 + lq*4 + r][o] = ((unsigned)hb << 16) | (unsigned)lb;
      }
    }
  }
  __syncthreads();
  int c8 = lane & 3;
  int pxl = lane >> 2;
  #pragma unroll
  for (int k=0;k<4;k++){
    int px = pxl + k*16;
    int x = xw + px;
    if (x > 728) continue;
    short8 vh, vl;
    #pragma unroll
    for (int j=0;j<8;j++){
      unsigned p = tr[px][c8*8 + j];
      vh[j] = (short)(p >> 16);
      vl[j] = (short)(p & 0xffffu);
    }
    size_t base = ((size_t)(y+1)*DRS + x)*32 + c8*8;
    *(short8*)(outHi + base) = vh;
    *(short8*)(outLo + base) = vl;
  }
}

// ---------------- dual conv2 (32->32): implicit-GEMM MFMA, 1 wave/block ----------------
__global__ __launch_bounds__(64) void dual_mfma32(
    const unsigned short* __restrict__ hiB, const unsigned short* __restrict__ loB,
    const unsigned short* __restrict__ Bimg,   // this layer: [9][2][2][64][8]
    const float* __restrict__ bias, const float* __restrict__ prelu,
    float* __restrict__ out)
{
  int y  = blockIdx.y;                               // 0..59
  int lane = (int)threadIdx.x;
  int xw = blockIdx.x*64;                            // 0..704 step 64
  int lm = lane & 15, lq = lane >> 4;
  int laneoff = lm*32 + lq*8;
  f32x4 acc[4][2];
  #pragma unroll
  for (int s=0;s<4;s++){ acc[s][0] = (f32x4)0.f; acc[s][1] = (f32x4)0.f; }
  const short8* Bf = (const short8*)Bimg;
  #pragma unroll
  for (int dy=-1; dy<=1; dy++){
    const unsigned short* rh = hiB + (size_t)(y+dy+1)*DRS*32;
    const unsigned short* rl = loB + (size_t)(y+dy+1)*DRS*32;
    #pragma unroll
    for (int dx=-1; dx<=1; dx++){
      int tap = (dy+1)*3 + (dx+1);
      const short8* bp8 = Bf + tap*256 + lane;
      short8 bh0 = bp8[0];     // n=0 hi
      short8 bl0 = bp8[64];    // n=0 lo
      short8 bh1 = bp8[128];   // n=1 hi
      short8 bl1 = bp8[192];   // n=1 lo
      int xoff = (xw + dx)*32 + laneoff;
      #pragma unroll
      for (int s=0; s<4; s++){
        short8 ah = *(const short8*)(rh + xoff + s*512);
        short8 al = *(const short8*)(rl + xoff + s*512);
        acc[s][0] = __builtin_amdgcn_mfma_f32_16x16x32_bf16(ah, bh0, acc[s][0], 0,0,0);
        acc[s][1] = __builtin_amdgcn_mfma_f32_16x16x32_bf16(ah, bh1, acc[s][1], 0,0,0);
        acc[s][0] = __builtin_amdgcn_mfma_f32_16x16x32_bf16(al, bh0, acc[s][0], 0,0,0);
        acc[s][1] = __builtin_amdgcn_mfma_f32_16x16x32_bf16(al, bh1, acc[s][1], 0,0,0);
        acc[s][0] = __builtin_amdgcn_mfma_f32_16x16x32_bf16(ah, bl0, acc[s][0], 0,0,0);
        acc[s][1] = __builtin_amdgcn_mfma_f32_16x16x32_bf16(ah, bl1, acc[s][1], 0,0,0);
      }
    }
  }
  // epilogue: bias + prelu + planar fp32 store (4B-aligned: 729 stride is odd)
  float aa = *prelu;
  #pragma unroll
  for (int s=0;s<4;s++){
    int px0 = xw + s*16 + lq*4;
    #pragma unroll
    for (int n=0;n<2;n++){
      int o = n*16 + lm;
      float bv = bias[o];
      f32x4 v = acc[s][n];
      v.x+=bv; v.y+=bv; v.z+=bv; v.w+=bv;
      v.x=(v.x>=0.f)?v.x:aa*v.x; v.y=(v.y>=0.f)?v.y:aa*v.y;
      v.z=(v.z>=0.f)?v.z:aa*v.z; v.w=(v.w>=0.f)?v.w:aa*v.w;
      float* op = out + (size_t)o*NSIN + y*DDET + px0;
      if (px0 + 3 <= DDET-1){
        v4u st; st.x=v.x; st.y=v.y; st.z=v.z; st.w=v.w;
        *(v4u*)op = st;
      } else {
        if (px0   <= DDET-1) op[0] = v.x;
        if (px0+1 <= DDET-1) op[1] = v.y;
        if (px0+2 <= DDET-1) op[2] = v.z;
      }
    }
  }
}

// ---------------- dual conv3 (32->5): 2-way channel split + LDS reduce ----------------
// epilogue also writes updated h into sinogram NHWC8 ch0-4
template<int COUT, int W>
__global__ __launch_bounds__(256) void conv3x3_fast2(
    const float* __restrict__ in1, int Cin1,
    const float* __restrict__ wt,
    const float* __restrict__ bias,
    float* __restrict__ out, int H,
    unsigned short* __restrict__ s8hi, unsigned short* __restrict__ s8lo)
{
  __shared__ float red[128*COUT];
  int HW = H*W;
  int pl = (int)threadIdx.x & 127;
  int half = (int)threadIdx.x >> 7;
  int pix = blockIdx.x*128 + pl;
  bool valid = (pix < HW);
  float acc[COUT];
  #pragma unroll
  for (int o=0;o<COUT;o++) acc[o] = 0.f;
  if (valid){
    int y = pix / W, x = pix - y*W;
    bool ym = y>0, yp = y<H-1, xm = x>0, xp = x<W-1;
    int nch = Cin1 >> 1;
    const float* wr = wt + half*nch*9*COUT;
    const float* ip = in1 + pix + (size_t)half*nch*HW;
    for (int i=0;i<nch;i++, ip+=HW){
      float p4 = ip[0];
      float p0=0,p1=0,p2=0,p3=0,p5=0,p6=0,p7=0,p8=0;
      if (ym){ p1 = ip[-W]; if (xm) p0 = ip[-W-1]; if (xp) p2 = ip[-W+1]; }
      if (xm) p3 = ip[-1];
      if (xp) p5 = ip[1];
      if (yp){ p7 = ip[W]; if (xm) p6 = ip[W-1]; if (xp) p8 = ip[W+1]; }
      float p[9] = {p0,p1,p2,p3,p4,p5,p6,p7,p8};
      #pragma unroll
      for (int t=0;t<9;t++){
        float v = p[t];
        #pragma unroll
        for (int o=0;o<COUT;o++) acc[o] = fmaf(v, wr[t*COUT+o], acc[o]);
      }
      wr += 9*COUT;
    }
  }
  if (half == 1){
    #pragma unroll
    for (int o=0;o<COUT;o++) red[pl*COUT+o] = acc[o];
  }
  __syncthreads();
  if (half == 0 && valid){
    int y = pix / W, x = pix - y*W;
    float* op = out + pix;
    size_t p8 = ((size_t)(y+1)*DRS + x)*8;
    #pragma unroll
    for (int o=0;o<COUT;o++){
      float nv = op[o*HW] + acc[o] + red[pl*COUT+o] + bias[o];
      op[o*HW] = nv;
      unsigned short hb = f2bf(nv);
      float hf = __uint_as_float((unsigned)hb << 16);
      unsigned short lb = f2bf(nv - hf);
      s8hi[p8+o] = hb;
      s8lo[p8+o] = lb;
    }
  }
}

// ---------------- primal conv1 (6->32): implicit-GEMM MFMA on NHWC8 input ----------------
__global__ __launch_bounds__(256) void prim1_mfma(
    const unsigned short* __restrict__ hi8, const unsigned short* __restrict__ lo8,  // [512][512][8]
    const unsigned short* __restrict__ Bimg1,   // this layer: [3][2][2][64][8]
    const float* __restrict__ bias, const float* __restrict__ prelu,
    unsigned short* __restrict__ outHi, unsigned short* __restrict__ outLo)
{
  __shared__ unsigned int tr[4][64][33];
  int b = blockIdx.x;                 // 0..1023
  int by = b >> 1, half = b & 1;
  int y = ((by & 7) << 6) | (by >> 3);   // XCD row swizzle
  int wv = (int)threadIdx.x >> 6;
  int lane = (int)threadIdx.x & 63;
  int xw = half*256 + wv*64;
  int lm = lane & 15, lq = lane >> 4;
  f32x4 acc[4][2];
  #pragma unroll
  for (int s=0;s<4;s++){ acc[s][0] = (f32x4)0.f; acc[s][1] = (f32x4)0.f; }
  bool fast = (y>0) && (y<511) && (xw!=0) && (xw!=448);
  const short8* Bf = (const short8*)Bimg1;
  #pragma unroll
  for (int g=0; g<3; g++){
    const short8* bp8 = Bf + g*256 + lane;
    short8 bh0 = bp8[0];
    short8 bl0 = bp8[64];
    short8 bh1 = bp8[128];
    short8 bl1 = bp8[192];
    int t = g*4 + lq; if (t > 8) t = 8;
    int dy = (t >= 6) ? 1 : ((t >= 3) ? 0 : -1);
    int dx = t - (dy+1)*3 - 1;
    int row = y + dy;
    #pragma unroll
    for (int s=0; s<4; s++){
      short8 ah, al;
      int px = xw + s*16 + lm + dx;
      if (fast){
        size_t off = ((size_t)row*SS + px)*8;
        ah = *(const short8*)(hi8 + off);
        al = *(const short8*)(lo8 + off);
      } else {
        bool ok = ((unsigned)row < 512u) && ((unsigned)px < 512u);
        size_t off = ok ? ((size_t)row*SS + px)*8 : 0;
        ah = ok ? *(const short8*)(hi8 + off) : (short8)0;
        al = ok ? *(const short8*)(lo8 + off) : (short8)0;
      }
      acc[s][0] = __builtin_amdgcn_mfma_f32_16x16x32_bf16(ah, bh0, acc[s][0], 0,0,0);
      acc[s][1] = __builtin_amdgcn_mfma_f32_16x16x32_bf16(ah, bh1, acc[s][1], 0,0,0);
      acc[s][0] = __builtin_amdgcn_mfma_f32_16x16x32_bf16(al, bh0, acc[s][0], 0,0,0);
      acc[s][1] = __builtin_amdgcn_mfma_f32_16x16x32_bf16(al, bh1, acc[s][1], 0,0,0);
      acc[s][0] = __builtin_amdgcn_mfma_f32_16x16x32_bf16(ah, bl0, acc[s][0], 0,0,0);
      acc[s][1] = __builtin_amdgcn_mfma_f32_16x16x32_bf16(ah, bl1, acc[s][1], 0,0,0);
    }
  }
  // epilogue: bias + prelu + pack hi/lo into LDS [px][ch], NHWC32 stores
  float aa = *prelu;
  #pragma unroll
  for (int s=0;s<4;s++){
    #pragma unroll
    for (int n=0;n<2;n++){
      int o = n*16 + lm;
      float bv = bias[o];
      f32x4 v = acc[s][n];
      v.x+=bv; v.y+=bv; v.z+=bv; v.w+=bv;
      v.x=(v.x>=0.f)?v.x:aa*v.x; v.y=(v.y>=0.f)?v.y:aa*v.y;
      v.z=(v.z>=0.f)?v.z:aa*v.z; v.w=(v.w>=0.f)?v.w:aa*v.w;
      #pragma unroll
      for (int r=0;r<4;r++){
        float x = v[r];
        unsigned short hb = f2bf(x);
        float hf = __uint_as_float((unsigned)hb << 16);
        unsigned short lb = f2bf(x - hf);
        tr[wv][s*16 + lq*4 + r][o] = ((unsigned)hb << 16) | (unsigned)lb;
      }
    }
  }
  __syncthreads();
  int c8 = lane & 3;
  int pxl = lane >> 2;
  #pragma unroll
  for (int k=0;k<4;k++){
    int px = pxl + k*16;
    short8 vh, vl;
    #pragma unroll
    for (int j=0;j<8;j++){
      unsigned p = tr[wv][px][c8*8 + j];
      vh[j] = (short)(p >> 16);
      vl[j] = (short)(p & 0xffffu);
    }
    size_t base = ((size_t)(y*SS + xw + px))*32 + c8*8;
    *(short8*)(outHi + base) = vh;
    *(short8*)(outLo + base) = vl;
  }
}

// ---------------- primal conv2 (32->32): implicit-GEMM MFMA bf16 hi/lo ----------------
__global__ __launch_bounds__(256) void conv_mfma32(
    const unsigned short* __restrict__ hiB, const unsigned short* __restrict__ loB,
    const unsigned short* __restrict__ Bimg,   // this layer: [9][2][2][64][8]
    const float* __restrict__ bias, const float* __restrict__ prelu,
    unsigned short* __restrict__ outHi, unsigned short* __restrict__ outLo)
{
  __shared__ unsigned int tr[4][64][33];
  int b = blockIdx.x;                 // 0..1023
  int by = b >> 1, half = b & 1;
  int y = ((by & 7) << 6) | (by >> 3);   // XCD row swizzle
  int wv = (int)threadIdx.x >> 6;
  int lane = (int)threadIdx.x & 63;
  int xw = half*256 + wv*64;
  int lm = lane & 15, lq = lane >> 4;
  int laneoff = lm*32 + lq*8;
  f32x4 acc[4][2];
  #pragma unroll
  for (int s=0;s<4;s++){ acc[s][0] = (f32x4)0.f; acc[s][1] = (f32x4)0.f; }
  bool fastx = (xw != 0) && (xw != 448);
  const short8* Bf = (const short8*)Bimg;
  #pragma unroll
  for (int dy=-1; dy<=1; dy++){
    int yy = y + dy;
    if ((unsigned)yy >= 512u) continue;
    const unsigned short* rh = hiB + (size_t)yy*512*32;
    const unsigned short* rl = loB + (size_t)yy*512*32;
    #pragma unroll
    for (int dx=-1; dx<=1; dx++){
      int tap = (dy+1)*3 + (dx+1);
      const short8* bp8 = Bf + tap*256 + lane;
      short8 bh0 = bp8[0];     // n=0 hi
      short8 bl0 = bp8[64];    // n=0 lo
      short8 bh1 = bp8[128];   // n=1 hi
      short8 bl1 = bp8[192];   // n=1 lo
      int xoff = (xw + dx)*32 + laneoff;
      #pragma unroll
      for (int s=0; s<4; s++){
        short8 ah, al;
        const unsigned short* ph = rh + xoff + s*512;
        const unsigned short* pl = rl + xoff + s*512;
        if (fastx){
          ah = *(const short8*)ph;
          al = *(const short8*)pl;
        } else {
          int x = xw + s*16 + lm + dx;
          bool ok = ((unsigned)x < 512u);
          ah = ok ? *(const short8*)ph : (short8)0;
          al = ok ? *(const short8*)pl : (short8)0;
        }
        acc[s][0] = __builtin_amdgcn_mfma_f32_16x16x32_bf16(ah, bh0, acc[s][0], 0,0,0);
        acc[s][1] = __builtin_amdgcn_mfma_f32_16x16x32_bf16(ah, bh1, acc[s][1], 0,0,0);
        acc[s][0] = __builtin_amdgcn_mfma_f32_16x16x32_bf16(al, bh0, acc[s][0], 0,0,0);
        acc[s][1] = __builtin_amdgcn_mfma_f32_16x16x32_bf16(al, bh1, acc[s][1], 0,0,0);
        acc[s][0] = __builtin_amdgcn_mfma_f32_16x16x32_bf16(ah, bl0, acc[s][0], 0,0,0);
        acc[s][1] = __builtin_amdgcn_mfma_f32_16x16x32_bf16(ah, bl1, acc[s][1], 0,0,0);
      }
    }
  }
  // epilogue: bias + prelu + pack hi/lo into LDS [px][ch]
  float aa = *prelu;
  #pragma unroll
  for (int s=0;s<4;s++){
    #pragma unroll
    for (int n=0;n<2;n++){
      int o = n*16 + lm;
      float bv = bias[o];
      f32x4 v = acc[s][n];
      v.x+=bv; v.y+=bv; v.z+=bv; v.w+=bv;
      v.x=(v.x>=0.f)?v.x:aa*v.x; v.y=(v.y>=0.f)?v.y:aa*v.y;
      v.z=(v.z>=0.f)?v.z:aa*v.z; v.w=(v.w>=0.f)?v.w:aa*v.w;
      #pragma unroll
      for (int r=0;r<4;r++){
        float x = v[r];
        unsigned short hb = f2bf(x);
        float hf = __uint_as_float((unsigned)hb << 16);
        unsigned short lb = f2bf(x - hf);
        tr[wv][s*16 + lq*4 + r][o] = ((unsigned)hb << 16) | (unsigned)lb;
      }
    }
  }
  __syncthreads();
  // read channel-contiguous, split, coalesced NHWC stores
  int c8 = lane & 3;             // 8-channel chunk
  int pxl = lane >> 2;           // 0..15
  #pragma unroll
  for (int k=0;k<4;k++){
    int px = pxl + k*16;
    short8 vh, vl;
    #pragma unroll
    for (int j=0;j<8;j++){
      unsigned p = tr[wv][px][c8*8 + j];
      vh[j] = (short)(p >> 16);
      vl[j] = (short)(p & 0xffffu);
    }
    size_t base = ((size_t)(y*SS + xw + px))*32 + c8*8;
    *(short8*)(outHi + base) = vh;
    *(short8*)(outLo + base) = vl;
  }
}

// ---------------- primal conv3 (32->5): implicit-GEMM MFMA, N=16 (5 real) ----------------
__global__ __launch_bounds__(256) void duo_mfma(
    const unsigned short* __restrict__ hiB, const unsigned short* __restrict__ loB,
    const unsigned short* __restrict__ Bimg3,   // this layer: [9][2][64][8]
    const float* __restrict__ bias,
    float* __restrict__ f,
    float* __restrict__ fout, float* __restrict__ tout,
    unsigned short* __restrict__ hi8, unsigned short* __restrict__ lo8)
{
  __shared__ unsigned int t8[4][64][6];
  int b = blockIdx.x;                 // 0..1023
  int by = b >> 1, half = b & 1;
  int y = ((by & 7) << 6) | (by >> 3);   // XCD row swizzle
  int wv = (int)threadIdx.x >> 6;
  int lane = (int)threadIdx.x & 63;
  int xw = half*256 + wv*64;
  int lm = lane & 15, lq = lane >> 4;
  int laneoff = lm*32 + lq*8;
  f32x4 acc[4];
  #pragma unroll
  for (int s=0;s<4;s++) acc[s] = (f32x4)0.f;
  bool fastx = (xw != 0) && (xw != 448);
  const short8* Bf = (const short8*)Bimg3;
  #pragma unroll
  for (int dy=-1; dy<=1; dy++){
    int yy = y + dy;
    if ((unsigned)yy >= 512u) continue;
    const unsigned short* rh = hiB + (size_t)yy*512*32;
    const unsigned short* rl = loB + (size_t)yy*512*32;
    #pragma unroll
    for (int dx=-1; dx<=1; dx++){
      int tap = (dy+1)*3 + (dx+1);
      const short8* bp8 = Bf + tap*128 + lane;
      short8 bh = bp8[0];
      short8 bl = bp8[64];
      int xoff = (xw + dx)*32 + laneoff;
      #pragma unroll
      for (int s=0; s<4; s++){
        short8 ah, al;
        const unsigned short* ph = rh + xoff + s*512;
        const unsigned short* pl = rl + xoff + s*512;
        if (fastx){
          ah = *(const short8*)ph;
          al = *(const short8*)pl;
        } else {
          int x = xw + s*16 + lm + dx;
          bool ok = ((unsigned)x < 512u);
          ah = ok ? *(const short8*)ph : (short8)0;
          al = ok ? *(const short8*)pl : (short8)0;
        }
        acc[s] = __builtin_amdgcn_mfma_f32_16x16x32_bf16(ah, bh, acc[s], 0,0,0);
        acc[s] = __builtin_amdgcn_mfma_f32_16x16x32_bf16(al, bh, acc[s], 0,0,0);
        acc[s] = __builtin_amdgcn_mfma_f32_16x16x32_bf16(ah, bl, acc[s], 0,0,0);
      }
    }
  }
  // epilogue: f += conv3 + bias on lanes lm<5; imgT transpose (lm==1); output rep (lm==0)
  if (lm < 5){
    float bv = bias[lm];
    #pragma unroll
    for (int s=0;s<4;s++){
      int px0 = xw + s*16 + lq*4;
      float* op = f + (size_t)lm*NPIX + y*SS + px0;
      f32x4 old = *(const f32x4*)op;
      f32x4 v = acc[s];
      v.x += old.x + bv; v.y += old.y + bv;
      v.z += old.z + bv; v.w += old.w + bv;
      *(f32x4*)op = v;
      #pragma unroll
      for (int r=0;r<4;r++){
        float x = v[r];
        unsigned short hb = f2bf(x);
        float hf = __uint_as_float((unsigned)hb << 16);
        unsigned short lb = f2bf(x - hf);
        t8[wv][s*16 + lq*4 + r][lm] = ((unsigned)hb << 16) | (unsigned)lb;
      }
      if (lm == 1){
        tout[(px0  )*SS + y] = v.x;
        tout[(px0+1)*SS + y] = v.y;
        tout[(px0+2)*SS + y] = v.z;
        tout[(px0+3)*SS + y] = v.w;
      }
      if (lm == 0 && fout){
        float* q = fout + y*SS + px0;
        *(f32x4*)q = v;
        *(f32x4*)(q + NPIX) = v;
        *(f32x4*)(q + 2*NPIX) = v;
      }
    }
  }
  __syncthreads();
  // readout: lane = px; write NHWC8 ch0-4 (8B + 2B stores, hi and lo)
  {
    unsigned c0 = t8[wv][lane][0], c1 = t8[wv][lane][1], c2 = t8[wv][lane][2];
    unsigned c3 = t8[wv][lane][3], c4 = t8[wv][lane][4];
    size_t base = ((size_t)(y*SS + xw + lane))*8;
    short4v vh; vh[0]=(short)(c0>>16); vh[1]=(short)(c1>>16); vh[2]=(short)(c2>>16); vh[3]=(short)(c3>>16);
    short4v vl; vl[0]=(short)(c0&0xffffu); vl[1]=(short)(c1&0xffffu); vl[2]=(short)(c2&0xffffu); vl[3]=(short)(c3&0xffffu);
    *(short4v*)(hi8 + base) = vh;
    *(short4v*)(lo8 + base) = vl;
    hi8[base+4] = (unsigned short)(c4>>16);
    lo8[base+4] = (unsigned short)(c4&0xffffu);
  }
}

extern "C" void kernel_launch(void* const* d_in, const int* in_sizes, int n_in,
                              void* d_out, int out_size, void* d_ws, size_t ws_size,
                              hipStream_t stream){
  const float* g     = (const float*)d_in[2];
  const float* theta = (const float*)d_in[3];
  const float* dw1 = (const float*)d_in[5];
  const float* db1 = (const float*)d_in[6];
  const float* da1 = (const float*)d_in[7];
  const float* dw2 = (const float*)d_in[8];
  const float* db2 = (const float*)d_in[9];
  const float* da2 = (const float*)d_in[10];
  const float* dw3 = (const float*)d_in[11];
  const float* db3 = (const float*)d_in[12];
  const float* pw1 = (const float*)d_in[13];
  const float* pb1 = (const float*)d_in[14];
  const float* pa1 = (const float*)d_in[15];
  const float* pw2 = (const float*)d_in[16];
  const float* pb2 = (const float*)d_in[17];
  const float* pa2 = (const float*)d_in[18];
  const float* pw3 = (const float*)d_in[19];
  const float* pb3 = (const float*)d_in[20];

  float* ws     = (float*)d_ws;
  float* trig   = ws;                    // 128
  float* taps   = ws + 128;              // -> 2048
  float* h      = ws + 2048;             // 5*NSIN
  float* opf    = h + 5*NSIN;            // NSIN (unused, keeps layout)
  float* gcopy  = opf + NSIN;            // NSIN (unused, keeps layout)
  float* h1     = gcopy + NSIN;          // NSIN
  float* f      = h1 + NSIN;             // 5*NPIX
  float* bp     = f + 5*NPIX;            // NPIX (unused, keeps layout)
  float* imgT   = bp + NPIX;             // NPIX
  float* dualT1 = imgT + NPIX;           // 32*NSIN (unused, keeps layout)
  float* dualT2 = dualT1 + 32*NSIN;      // 32*NSIN
  float* primT2slot = dualT2 + 32*NSIN;  // 32*NPIX floats of space
  unsigned short* primHi = (unsigned short*)primT2slot;          // 32*NPIX ushorts
  unsigned short* primLo = primHi + (size_t)32*NPIX;             // 32*NPIX ushorts
  unsigned short* nhwcHi = (unsigned short*)(primT2slot + 32*NPIX);  // 32*NPIX ushorts
  unsigned short* nhwcLo = nhwcHi + (size_t)32*NPIX;             // 32*NPIX ushorts
  float* wsp   = (float*)(nhwcLo + (size_t)32*NPIX);
  float* wtd3  = wsp;                    // 14400
  float* wtp3  = wsp + 14400;            // 14400 (unused)
  float* wtd1b = wsp + 28800;            // 20160 (unused, keeps layout)
  float* wtd2b = wsp + 48960;            // 92160 (unused, keeps layout)
  float* wtp1b = wsp + 141120;           // 17280 (unused, keeps layout)
  unsigned short* Bimg  = (unsigned short*)(wsp + 158400);       // 184320 ushorts
  unsigned short* Bimg2 = Bimg + 184320;                         // 184320 ushorts
  unsigned short* Bimg3 = Bimg2 + 184320;                        // 92160 ushorts
  unsigned short* Bimg1 = Bimg3 + 92160;                         // 61440 ushorts
  unsigned short* Bimg1d = Bimg1 + 61440;                        // 61440 ushorts
  // dual NHWC hi/lo: 62 rows x DRS x 32ch + 64-ushort zero prefix/suffix
  const size_t DUALSZ = (size_t)64 + (size_t)62*DRS*32 + 64;
  unsigned short* dualHiRaw = Bimg1d + 61440;
  unsigned short* dualLoRaw = dualHiRaw + DUALSZ;
  unsigned short* dualHi = dualHiRaw + 64;
  unsigned short* dualLo = dualLoRaw + 64;
  // primal NHWC8 input image [512][512][8] bf16 hi/lo
  unsigned short* nh8Hi = dualLoRaw + DUALSZ;
  unsigned short* nh8Lo = nh8Hi + (size_t)NPIX*8;
  // sinogram NHWC8 input image [62][DRS][8] bf16 hi/lo + 64-ushort prefix/suffix
  const size_t S8SZ = (size_t)64 + (size_t)62*DRS*8 + 64;
  unsigned short* s8HiRaw = nh8Lo + (size_t)NPIX*8;
  unsigned short* s8LoRaw = s8HiRaw + S8SZ;
  unsigned short* s8Hi = s8HiRaw + 64;
  unsigned short* s8Lo = s8LoRaw + 64;

  hipMemsetAsync(h, 0, (size_t)(5*NSIN)*sizeof(float), stream);
  hipMemsetAsync(f, 0, (size_t)(7*NPIX)*sizeof(float), stream);   // f, bp, imgT
  hipMemsetAsync(dualHiRaw, 0, 2*DUALSZ*sizeof(unsigned short), stream); // zero pads once
  hipMemsetAsync(nh8Hi, 0, (size_t)2*NPIX*8*sizeof(unsigned short), stream); // zero once
  hipMemsetAsync(s8HiRaw, 0, 2*S8SZ*sizeof(unsigned short), stream); // zero once
  trig_kernel<<<1,64,0,stream>>>(theta, trig);
  taps_kernel<<<NTAPS,256,0,stream>>>(taps);
  transpose_all<<<(28800+255)/256,256,0,stream>>>(dw3,wtd3, pw3,wtp3);
  prep_bimg<<<(92160+255)/256,256,0,stream>>>(pw2, Bimg);
  prep_bimg<<<(92160+255)/256,256,0,stream>>>(dw2, Bimg2);
  prep_bimg3<<<(46080+255)/256,256,0,stream>>>(pw3, Bimg3);
  prep_bimg1c<<<(30720+255)/256,256,0,stream>>>(pw1, Bimg1, 6);
  prep_bimg1c<<<(30720+255)/256,256,0,stream>>>(dw1, Bimg1d, 7);
  g_to_nhwc8<<<(NSIN+255)/256,256,0,stream>>>(g, s8Hi, s8Lo);

  for (int i=0;i<10;i++){
    radon_fwd_kernel<<<(NSIN+3)/4,256,0,stream>>>(f + NPIX, imgT, trig, s8Hi, s8Lo);
    // dual block: NHWC8 [h(5)|opf|g|0] -> conv1 -> conv2 -> conv3
    dual1_mfma<<<dim3(12,AANG),64,0,stream>>>(s8Hi, s8Lo, Bimg1d+(size_t)i*6144,
                                              db1+(size_t)i*32, da1+i, dualHi, dualLo);
    dual_mfma32<<<dim3(12,AANG),64,0,stream>>>(dualHi, dualLo, Bimg2+(size_t)i*18432,
                                               db2+(size_t)i*32, da2+i, dualT2);
    conv3x3_fast2<5,DDET><<<(NSIN+127)/128,256,0,stream>>>(dualT2, 32, wtd3+i*1440, db3+(size_t)i*5,
                                                           h, AANG, s8Hi, s8Lo);
    filter_kernel2<<<AANG*12,256,0,stream>>>(h, taps, h1);
    backproj_kernel<<<NPIX/256,256,0,stream>>>(h1, trig, nh8Hi, nh8Lo);
    // primal block: NHWC8 [f(5)|bp|0|0] -> conv1 -> conv2 -> conv3
    prim1_mfma<<<1024,256,0,stream>>>(nh8Hi, nh8Lo, Bimg1+(size_t)i*6144,
                                      pb1+(size_t)i*32, pa1+i, nhwcHi, nhwcLo);
    conv_mfma32<<<1024,256,0,stream>>>(nhwcHi, nhwcLo, Bimg+(size_t)i*18432, pb2+(size_t)i*32, pa2+i, primHi, primLo);
    duo_mfma<<<1024,256,0,stream>>>(primHi, primLo, Bimg3+(size_t)i*9216, pb3+(size_t)i*5, f,
                                    (i==9) ? (float*)d_out : nullptr, imgT, nh8Hi, nh8Lo);
  }
}

// Round 7
// 1789.314 us; speedup vs baseline: 1.2958x; 1.0338x over previous
//
#include <hip/hip_runtime.h>
#include <math.h>

#define SS 512
#define AANG 60
#define DDET 729
#define NPIX (SS*SS)        // 262144
#define NSIN (AANG*DDET)    // 43740
#define NTAPS 1457
#define DRS 768             // dual NHWC padded row stride

typedef float v4u __attribute__((ext_vector_type(4), aligned(4)));
typedef float v2u __attribute__((ext_vector_type(2), aligned(8)));
typedef short short8 __attribute__((ext_vector_type(8)));
typedef short short4v __attribute__((ext_vector_type(4)));
typedef float f32x4 __attribute__((ext_vector_type(4)));

// round-to-nearest-even fp32 -> bf16 bits
__device__ inline unsigned short f2bf(float x){
  unsigned u = __float_as_uint(x);
  return (unsigned short)((u + 0x7fffu + ((u >> 16) & 1u)) >> 16);
}

// ---------------- trig table ----------------
__global__ void trig_kernel(const float* __restrict__ theta, float* __restrict__ trig){
  int a = threadIdx.x;
  if (a < AANG){ trig[a] = cosf(theta[a]); trig[AANG+a] = sinf(theta[a]); }
}

// ---------------- ramp-filter taps ----------------
__global__ void taps_kernel(float* __restrict__ taps){
  __shared__ double red[256];
  int m  = blockIdx.x;
  int mm = m - 728;
  double s = 0.0;
  for (int k = 1 + (int)threadIdx.x; k <= 1023; k += 256){
    int phase = (k*mm) & 2047;
    s += (double)k * cos((double)phase * (M_PI/1024.0));
  }
  red[threadIdx.x] = s;
  __syncthreads();
  for (int off=128; off; off>>=1){
    if ((int)threadIdx.x < off) red[threadIdx.x] += red[threadIdx.x+off];
    __syncthreads();
  }
  if (threadIdx.x==0){
    double x = (red[0]*(1.0/512.0) + ((mm & 1) ? -1.0 : 1.0)) / 2048.0;
    taps[m] = (float)(x * (M_PI/120.0));
  }
}

// -------- MFMA B-fragment image: [L][tap=9][n=2][prod=2][lane=64][8] bf16 --------
// works for any [L][32][32][3][3] weight tensor (pw2 and dw2)
__global__ void prep_bimg(const float* __restrict__ w, unsigned short* __restrict__ B){
  int idx = blockIdx.x*256 + (int)threadIdx.x;
  if (idx >= 10*9*2*64*8) return;
  int j    =  idx        & 7;
  int lane = (idx >> 3)  & 63;
  int n    = (idx >> 9)  & 1;
  int r    =  idx >> 10;          // l*9 + tap
  int tap = r % 9, l = r / 9;
  int c = (lane >> 4)*8 + j;      // k = channel
  int o = n*16 + (lane & 15);     // output channel
  float x = w[(((size_t)(l*32+o)*32 + c)*9) + tap];
  unsigned short hb = f2bf(x);
  float hf = __uint_as_float((unsigned)hb << 16);
  unsigned short lb = f2bf(x - hf);
  size_t d = (size_t)l*18432 + (size_t)tap*2048 + n*1024 + lane*8 + j;
  B[d]       = hb;
  B[d + 512] = lb;
}

// -------- MFMA B-fragment image for [L][5][32][3][3]: [L][tap=9][prod=2][lane=64][8] --------
__global__ void prep_bimg3(const float* __restrict__ w, unsigned short* __restrict__ B){
  int idx = blockIdx.x*256 + (int)threadIdx.x;
  if (idx >= 10*9*64*8) return;
  int j    =  idx       & 7;
  int lane = (idx >> 3) & 63;
  int r    =  idx >> 9;           // l*9 + tap
  int tap = r % 9, l = r / 9;
  int c = (lane >> 4)*8 + j;      // k = channel
  int o = lane & 15;              // output channel (5 real)
  float x = (o < 5) ? w[(((size_t)(l*5+o)*32 + c)*9) + tap] : 0.f;
  unsigned short hb = f2bf(x);
  float hf = __uint_as_float((unsigned)hb << 16);
  unsigned short lb = f2bf(x - hf);
  size_t d = (size_t)l*9216 + (size_t)tap*1024 + lane*8 + j;
  B[d]       = hb;
  B[d + 512] = lb;
}

// -------- MFMA B-fragment image for NHWC8 conv1 weights [L][32][Cin][3][3] --------
// layout [L][g=3][n=2][prod=2][64][8]; k = tap_local*8 + ch; t = g*4+tap_local
__global__ void prep_bimg1c(const float* __restrict__ w, unsigned short* __restrict__ B, int Cin){
  int idx = blockIdx.x*256 + (int)threadIdx.x;
  if (idx >= 10*3*2*64*8) return;
  int j    =  idx       & 7;
  int lane = (idx >> 3) & 63;
  int n    = (idx >> 9) & 1;
  int r    =  idx >> 10;          // l*3 + g
  int g = r % 3, l = r / 3;
  int t = g*4 + (lane >> 4);
  int o = n*16 + (lane & 15);
  float x = (t < 9 && j < Cin) ? w[(((size_t)(l*32+o)*Cin + j)*9) + t] : 0.f;
  unsigned short hb = f2bf(x);
  float hf = __uint_as_float((unsigned)hb << 16);
  unsigned short lb = f2bf(x - hf);
  size_t d = (size_t)l*6144 + (size_t)g*2048 + n*1024 + lane*8 + j;
  B[d]       = hb;
  B[d + 512] = lb;
}

// ---------------- g -> sinogram NHWC8 ch6 (once) ----------------
__global__ void g_to_nhwc8(const float* __restrict__ g,
                           unsigned short* __restrict__ s8hi, unsigned short* __restrict__ s8lo){
  int idx = blockIdx.x*256 + (int)threadIdx.x;
  if (idx >= NSIN) return;
  int a = idx / DDET, d = idx - a*DDET;
  float x = g[idx];
  unsigned short hb = f2bf(x);
  float hf = __uint_as_float((unsigned)hb << 16);
  unsigned short lb = f2bf(x - hf);
  size_t p8 = ((size_t)(a+1)*DRS + d)*8 + 6;
  s8hi[p8] = hb;
  s8lo[p8] = lb;
}

// ---------------- radon forward: rcp-hoisted clip; writes NHWC8sin ch5 ----------------
__device__ inline void clipr(float al, float ial, float be, float lo, float hi,
                             float& A, float& B, bool& empty){
  if (fabsf(al) < 1e-7f){ if (be < lo || be > hi) empty = true; return; }
  float t0 = (lo - be)*ial, t1 = (hi - be)*ial;
  float mn = fminf(t0,t1), mx = fmaxf(t0,t1);
  A = fmaxf(A, mn); B = fminf(B, mx);
}

__device__ inline float samp_guard(const float* __restrict__ base, float aR, float bR,
                                   float aC, float bC, int t){
  float tp = (float)t - 255.5f;
  float R = fmaf(aR, tp, bR);
  float C = fmaf(aC, tp, bC);
  float rf = floorf(R), cf = floorf(C);
  int r0 = (int)rf, c0 = (int)cf;
  int r1 = r0+1,    c1 = c0+1;
  float fr = R - rf, fc = C - cf;
  bool r0ok = (r0>=0 && r0<SS), r1ok = (r1>=0 && r1<SS);
  bool c0ok = (c0>=0 && c0<SS), c1ok = (c1>=0 && c1<SS);
  float v00 = (r0ok && c0ok) ? base[r0*SS+c0] : 0.f;
  float v01 = (r0ok && c1ok) ? base[r0*SS+c1] : 0.f;
  float v10 = (r1ok && c0ok) ? base[r1*SS+c0] : 0.f;
  float v11 = (r1ok && c1ok) ? base[r1*SS+c1] : 0.f;
  return (1.f-fr)*((1.f-fc)*v00 + fc*v01) + fr*((1.f-fc)*v10 + fc*v11);
}

__global__ __launch_bounds__(256) void radon_fwd_kernel(
    const float* __restrict__ img, const float* __restrict__ imgT,
    const float* __restrict__ trig,
    unsigned short* __restrict__ s8hi, unsigned short* __restrict__ s8lo){
  int gid  = blockIdx.x*4 + ((int)threadIdx.x >> 6);
  int lane = (int)threadIdx.x & 63;
  if (gid >= NSIN) return;
  int a = gid / DDET;
  int d = gid - a*DDET;
  float ca = trig[a], sa = trig[AANG+a];
  float sd = (float)d - 364.0f;
  float Rc = fmaf(sd, sa, 255.5f);
  float Cc = fmaf(sd, ca, 255.5f);
  float aR = ca, bR = Rc, aC = -sa, bC = Cc;
  const float* base = img;
  if (fabsf(ca) > fabsf(sa)){
    base = imgT;
    float tmp;
    tmp=aR; aR=aC; aC=tmp;
    tmp=bR; bR=bC; bC=tmp;
  }
  float iaR = __builtin_amdgcn_rcpf(aR);
  float iaC = __builtin_amdgcn_rcpf(aC);
  float tiA = -255.5f, tiB = 255.5f;  bool iE=false;
  float teA = -255.5f, teB = 255.5f;  bool eE=false;
  clipr(aR,iaR,bR, 0.001f, 510.999f, tiA,tiB,iE);
  clipr(aC,iaC,bC, 0.001f, 510.999f, tiA,tiB,iE);
  clipr(aR,iaR,bR, -0.999f, 511.999f, teA,teB,eE);
  clipr(aC,iaC,bC, -0.999f, 511.999f, teA,teB,eE);
  float acc = 0.f;
  if (!eE && teA <= teB){
    int eA = max(0,   (int)floorf(teA+255.5f) - 1);
    int eB = min(511, (int)ceilf (teB+255.5f) + 1);
    int iA = (int)ceilf (tiA+255.5f) + 1;
    int iB = (int)floorf(tiB+255.5f) - 1;
    iA = max(iA, eA); iB = min(iB, eB);
    if (iE || iA > iB){
      for (int t = eA+lane; t <= eB; t += 64) acc += samp_guard(base,aR,bR,aC,bC,t);
    } else {
      for (int t = eA+lane;   t <  iA; t += 64) acc += samp_guard(base,aR,bR,aC,bC,t);
      for (int t = iB+1+lane; t <= eB; t += 64) acc += samp_guard(base,aR,bR,aC,bC,t);
      for (int t = iA+lane;   t <= iB; t += 64){
        float tp = (float)t - 255.5f;
        float R = fmaf(aR, tp, bR);
        float C = fmaf(aC, tp, bC);
        int r0 = (int)R, c0 = (int)C;
        float fr = R - (float)r0, fc = C - (float)c0;
        const float* p = base + r0*SS + c0;
        float v00 = p[0], v01 = p[1], v10 = p[SS], v11 = p[SS+1];
        float top = v00 + fc*(v01-v00);
        float bot = v10 + fc*(v11-v10);
        acc += top + fr*(bot-top);
      }
    }
  }
  for (int off=32; off; off>>=1) acc += __shfl_down(acc, off);
  if (lane==0){
    unsigned short hb = f2bf(acc);
    float hf = __uint_as_float((unsigned)hb << 16);
    unsigned short lb = f2bf(acc - hf);
    size_t p8 = ((size_t)(a+1)*DRS + d)*8 + 5;
    s8hi[p8] = hb;
    s8lo[p8] = lb;
  }
}

// ---------------- ramp filter: 4-way k-split, 64 outputs/block ----------------
__global__ __launch_bounds__(256) void filter_kernel2(
    const float* __restrict__ h0, const float* __restrict__ taps,
    float* __restrict__ h1){
  __shared__ float red[256];
  int a  = blockIdx.x / 12;
  int jb = blockIdx.x - a*12;
  int jl = (int)threadIdx.x & 63;
  int kq = (int)threadIdx.x >> 6;
  int j  = jb*64 + jl;
  float acc = 0.f;
  if (j < DDET){
    const float* row = h0 + a*DDET;
    const float* tp  = taps + 728 + j;
    int k0 = kq*183;
    int k1 = min(k0+183, DDET);
    for (int k=k0;k<k1;k++) acc = fmaf(row[k], tp[-k], acc);
  }
  red[threadIdx.x] = acc;
  __syncthreads();
  if ((int)threadIdx.x < 64 && j < DDET){
    float s = red[jl] + red[64+jl] + red[128+jl] + red[192+jl];
    h1[a*DDET + j] = s;
  }
}

// ---------------- backprojection: writes NHWC8 ch5 bf16 hi/lo ----------------
__global__ __launch_bounds__(256) void backproj_kernel(
    const float* __restrict__ h1, const float* __restrict__ trig,
    unsigned short* __restrict__ hi8, unsigned short* __restrict__ lo8){
  __shared__ float sh[AANG*28];
  __shared__ int   sbase[AANG];
  __shared__ float strig[2*AANG];
  int tid = threadIdx.x;
  int x0 = (blockIdx.x & 31) * 16, y0 = (blockIdx.x >> 5) * 16;
  if (tid < 2*AANG) strig[tid] = trig[tid];
  __syncthreads();
  if (tid < AANG){
    float ca = strig[tid], sa = strig[AANG+tid];
    float Xa = (float)x0 - 255.5f, Xb = Xa + 15.f;
    float Ya = (float)y0 - 255.5f, Yb = Ya + 15.f;
    float s00 = Xa*ca + Ya*sa, s01 = Xb*ca + Ya*sa;
    float s10 = Xa*ca + Yb*sa, s11 = Xb*ca + Yb*sa;
    float mn = fminf(fminf(s00,s01), fminf(s10,s11)) + 364.0f;
    sbase[tid] = (int)floorf(mn) - 2;
  }
  __syncthreads();
  for (int s = tid; s < AANG*28; s += 256){
    int a = s / 28, j = s - a*28;
    int idx = sbase[a] + j;
    sh[s] = (idx >= 0 && idx < DDET) ? h1[a*DDET + idx] : 0.f;
  }
  __syncthreads();
  int x = x0 + (tid & 15), y = y0 + (tid >> 4);
  float X = (float)x - 255.5f, Y = (float)y - 255.5f;
  float acc = 0.f;
  #pragma unroll 6
  for (int a=0;a<AANG;a++){
    float sidx = fmaf(X, strig[a], fmaf(Y, strig[AANG+a], 364.0f));
    float ff = floorf(sidx);
    int k = (int)ff - sbase[a];
    float fi = sidx - ff;
    float v0 = sh[a*28+k], v1 = sh[a*28+k+1];
    acc += v0 + fi*(v1-v0);
  }
  unsigned short hb = f2bf(acc);
  float hf = __uint_as_float((unsigned)hb << 16);
  unsigned short lb = f2bf(acc - hf);
  size_t p8 = ((size_t)(y*SS + x))*8 + 5;
  hi8[p8] = hb;
  lo8[p8] = lb;
}

// ---------------- dual conv1 (7->32): implicit-GEMM MFMA on sinogram NHWC8 ----------------
__global__ __launch_bounds__(64) void dual1_mfma(
    const unsigned short* __restrict__ hi8, const unsigned short* __restrict__ lo8,  // [62][DRS][8]
    const unsigned short* __restrict__ Bimg1d,   // this layer: [3][2][2][64][8]
    const float* __restrict__ bias, const float* __restrict__ prelu,
    unsigned short* __restrict__ outHi, unsigned short* __restrict__ outLo)
{
  __shared__ unsigned int tr[64][33];
  int y  = blockIdx.y;                 // 0..59
  int lane = (int)threadIdx.x;
  int xw = blockIdx.x*64;              // 0..704
  int lm = lane & 15, lq = lane >> 4;
  f32x4 acc[4][2];
  #pragma unroll
  for (int s=0;s<4;s++){ acc[s][0] = (f32x4)0.f; acc[s][1] = (f32x4)0.f; }
  const short8* Bf = (const short8*)Bimg1d;
  #pragma unroll
  for (int g=0; g<3; g++){
    const short8* bp8 = Bf + g*256 + lane;
    short8 bh0 = bp8[0];
    short8 bl0 = bp8[64];
    short8 bh1 = bp8[128];
    short8 bl1 = bp8[192];
    int t = g*4 + lq; if (t > 8) t = 8;
    int dy = (t >= 6) ? 1 : ((t >= 3) ? 0 : -1);
    int dx = t - (dy+1)*3 - 1;
    int row = y + dy + 1;              // +1 guard-row offset
    #pragma unroll
    for (int s=0; s<4; s++){
      int px = xw + s*16 + lm + dx;
      size_t off = (size_t)(row*DRS + px)*8;
      short8 ah = *(const short8*)(hi8 + off);
      short8 al = *(const short8*)(lo8 + off);
      acc[s][0] = __builtin_amdgcn_mfma_f32_16x16x32_bf16(ah, bh0, acc[s][0], 0,0,0);
      acc[s][1] = __builtin_amdgcn_mfma_f32_16x16x32_bf16(ah, bh1, acc[s][1], 0,0,0);
      acc[s][0] = __builtin_amdgcn_mfma_f32_16x16x32_bf16(al, bh0, acc[s][0], 0,0,0);
      acc[s][1] = __builtin_amdgcn_mfma_f32_16x16x32_bf16(al, bh1, acc[s][1], 0,0,0);
      acc[s][0] = __builtin_amdgcn_mfma_f32_16x16x32_bf16(ah, bl0, acc[s][0], 0,0,0);
      acc[s][1] = __builtin_amdgcn_mfma_f32_16x16x32_bf16(ah, bl1, acc[s][1], 0,0,0);
    }
  }
  // epilogue: bias + prelu + LDS transpose -> NHWC32 hi/lo (store-masked x<=728)
  float aa = *prelu;
  #pragma unroll
  for (int s=0;s<4;s++){
    #pragma unroll
    for (int n=0;n<2;n++){
      int o = n*16 + lm;
      float bv = bias[o];
      f32x4 v = acc[s][n];
      v.x+=bv; v.y+=bv; v.z+=bv; v.w+=bv;
      v.x=(v.x>=0.f)?v.x:aa*v.x; v.y=(v.y>=0.f)?v.y:aa*v.y;
      v.z=(v.z>=0.f)?v.z:aa*v.z; v.w=(v.w>=0.f)?v.w:aa*v.w;
      #pragma unroll
      for (int r=0;r<4;r++){
        float x = v[r];
        unsigned short hb = f2bf(x);
        float hf = __uint_as_float((unsigned)hb << 16);
        unsigned short lb = f2bf(x - hf);
        tr[s*16 + lq*4 + r][o] = ((unsigned)hb << 16) | (unsigned)lb;
      }
    }
  }
  __syncthreads();
  int c8 = lane & 3;
  int pxl = lane >> 2;
  #pragma unroll
  for (int k=0;k<4;k++){
    int px = pxl + k*16;
    int x = xw + px;
    if (x > 728) continue;
    short8 vh, vl;
    #pragma unroll
    for (int j=0;j<8;j++){
      unsigned p = tr[px][c8*8 + j];
      vh[j] = (short)(p >> 16);
      vl[j] = (short)(p & 0xffffu);
    }
    size_t base = ((size_t)(y+1)*DRS + x)*32 + c8*8;
    *(short8*)(outHi + base) = vh;
    *(short8*)(outLo + base) = vl;
  }
}

// ---------------- dual conv2 (32->32): implicit-GEMM MFMA, NHWC32 bf16 hi/lo out ----------------
__global__ __launch_bounds__(64) void dual_mfma32(
    const unsigned short* __restrict__ hiB, const unsigned short* __restrict__ loB,
    const unsigned short* __restrict__ Bimg,   // this layer: [9][2][2][64][8]
    const float* __restrict__ bias, const float* __restrict__ prelu,
    unsigned short* __restrict__ outHi, unsigned short* __restrict__ outLo)
{
  __shared__ unsigned int tr[64][33];
  int y  = blockIdx.y;                               // 0..59
  int lane = (int)threadIdx.x;
  int xw = blockIdx.x*64;                            // 0..704 step 64
  int lm = lane & 15, lq = lane >> 4;
  int laneoff = lm*32 + lq*8;
  f32x4 acc[4][2];
  #pragma unroll
  for (int s=0;s<4;s++){ acc[s][0] = (f32x4)0.f; acc[s][1] = (f32x4)0.f; }
  const short8* Bf = (const short8*)Bimg;
  #pragma unroll
  for (int dy=-1; dy<=1; dy++){
    const unsigned short* rh = hiB + (size_t)(y+dy+1)*DRS*32;
    const unsigned short* rl = loB + (size_t)(y+dy+1)*DRS*32;
    #pragma unroll
    for (int dx=-1; dx<=1; dx++){
      int tap = (dy+1)*3 + (dx+1);
      const short8* bp8 = Bf + tap*256 + lane;
      short8 bh0 = bp8[0];     // n=0 hi
      short8 bl0 = bp8[64];    // n=0 lo
      short8 bh1 = bp8[128];   // n=1 hi
      short8 bl1 = bp8[192];   // n=1 lo
      int xoff = (xw + dx)*32 + laneoff;
      #pragma unroll
      for (int s=0; s<4; s++){
        short8 ah = *(const short8*)(rh + xoff + s*512);
        short8 al = *(const short8*)(rl + xoff + s*512);
        acc[s][0] = __builtin_amdgcn_mfma_f32_16x16x32_bf16(ah, bh0, acc[s][0], 0,0,0);
        acc[s][1] = __builtin_amdgcn_mfma_f32_16x16x32_bf16(ah, bh1, acc[s][1], 0,0,0);
        acc[s][0] = __builtin_amdgcn_mfma_f32_16x16x32_bf16(al, bh0, acc[s][0], 0,0,0);
        acc[s][1] = __builtin_amdgcn_mfma_f32_16x16x32_bf16(al, bh1, acc[s][1], 0,0,0);
        acc[s][0] = __builtin_amdgcn_mfma_f32_16x16x32_bf16(ah, bl0, acc[s][0], 0,0,0);
        acc[s][1] = __builtin_amdgcn_mfma_f32_16x16x32_bf16(ah, bl1, acc[s][1], 0,0,0);
      }
    }
  }
  // epilogue: bias + prelu + LDS transpose -> NHWC32 hi/lo (store-masked x<=728)
  float aa = *prelu;
  #pragma unroll
  for (int s=0;s<4;s++){
    #pragma unroll
    for (int n=0;n<2;n++){
      int o = n*16 + lm;
      float bv = bias[o];
      f32x4 v = acc[s][n];
      v.x+=bv; v.y+=bv; v.z+=bv; v.w+=bv;
      v.x=(v.x>=0.f)?v.x:aa*v.x; v.y=(v.y>=0.f)?v.y:aa*v.y;
      v.z=(v.z>=0.f)?v.z:aa*v.z; v.w=(v.w>=0.f)?v.w:aa*v.w;
      #pragma unroll
      for (int r=0;r<4;r++){
        float x = v[r];
        unsigned short hb = f2bf(x);
        float hf = __uint_as_float((unsigned)hb << 16);
        unsigned short lb = f2bf(x - hf);
        tr[s*16 + lq*4 + r][o] = ((unsigned)hb << 16) | (unsigned)lb;
      }
    }
  }
  __syncthreads();
  int c8 = lane & 3;
  int pxl = lane >> 2;
  #pragma unroll
  for (int k=0;k<4;k++){
    int px = pxl + k*16;
    int x = xw + px;
    if (x > 728) continue;
    short8 vh, vl;
    #pragma unroll
    for (int j=0;j<8;j++){
      unsigned p = tr[px][c8*8 + j];
      vh[j] = (short)(p >> 16);
      vl[j] = (short)(p & 0xffffu);
    }
    size_t base = ((size_t)(y+1)*DRS + x)*32 + c8*8;
    *(short8*)(outHi + base) = vh;
    *(short8*)(outLo + base) = vl;
  }
}

// ---------------- dual conv3 (32->5): implicit-GEMM MFMA N=16; h += ; writes s8 ch0-4 ----------------
__global__ __launch_bounds__(64) void dual3_mfma(
    const unsigned short* __restrict__ hiB, const unsigned short* __restrict__ loB,  // NHWC32 [62][DRS][32]
    const unsigned short* __restrict__ Bimg3d,   // this layer: [9][2][64][8]
    const float* __restrict__ bias,
    float* __restrict__ h,
    unsigned short* __restrict__ s8hi, unsigned short* __restrict__ s8lo)
{
  __shared__ unsigned int t8[64][6];
  int y  = blockIdx.y;                               // 0..59
  int lane = (int)threadIdx.x;
  int xw = blockIdx.x*64;                            // 0..704
  int lm = lane & 15, lq = lane >> 4;
  int laneoff = lm*32 + lq*8;
  f32x4 acc[4];
  #pragma unroll
  for (int s=0;s<4;s++) acc[s] = (f32x4)0.f;
  const short8* Bf = (const short8*)Bimg3d;
  #pragma unroll
  for (int dy=-1; dy<=1; dy++){
    const unsigned short* rh = hiB + (size_t)(y+dy+1)*DRS*32;
    const unsigned short* rl = loB + (size_t)(y+dy+1)*DRS*32;
    #pragma unroll
    for (int dx=-1; dx<=1; dx++){
      int tap = (dy+1)*3 + (dx+1);
      const short8* bp8 = Bf + tap*128 + lane;
      short8 bh = bp8[0];
      short8 bl = bp8[64];
      int xoff = (xw + dx)*32 + laneoff;
      #pragma unroll
      for (int s=0; s<4; s++){
        short8 ah = *(const short8*)(rh + xoff + s*512);
        short8 al = *(const short8*)(rl + xoff + s*512);
        acc[s] = __builtin_amdgcn_mfma_f32_16x16x32_bf16(ah, bh, acc[s], 0,0,0);
        acc[s] = __builtin_amdgcn_mfma_f32_16x16x32_bf16(al, bh, acc[s], 0,0,0);
        acc[s] = __builtin_amdgcn_mfma_f32_16x16x32_bf16(ah, bl, acc[s], 0,0,0);
      }
    }
  }
  // epilogue: h += conv3 + bias (lanes lm<5, guarded); pack updated h into LDS
  if (lm < 5){
    float bv = bias[lm];
    #pragma unroll
    for (int s=0;s<4;s++){
      int px0 = xw + s*16 + lq*4;
      float* op = h + (size_t)lm*NSIN + y*DDET + px0;
      float nv0=0.f, nv1=0.f, nv2=0.f, nv3=0.f;
      if (px0 + 3 <= 728){
        v4u old = *(const v4u*)op;
        nv0 = old.x + acc[s].x + bv;
        nv1 = old.y + acc[s].y + bv;
        nv2 = old.z + acc[s].z + bv;
        nv3 = old.w + acc[s].w + bv;
        v4u st; st.x=nv0; st.y=nv1; st.z=nv2; st.w=nv3;
        *(v4u*)op = st;
      } else {
        if (px0   <= 728){ nv0 = op[0] + acc[s].x + bv; op[0] = nv0; }
        if (px0+1 <= 728){ nv1 = op[1] + acc[s].y + bv; op[1] = nv1; }
        if (px0+2 <= 728){ nv2 = op[2] + acc[s].z + bv; op[2] = nv2; }
        if (px0+3 <= 728){ nv3 = op[3] + acc[s].w + bv; op[3] = nv3; }
      }
      float nv[4] = {nv0,nv1,nv2,nv3};
      #pragma unroll
      for (int r=0;r<4;r++){
        float x = nv[r];
        unsigned short hb = f2bf(x);
        float hf = __uint_as_float((unsigned)hb << 16);
        unsigned short lb = f2bf(x - hf);
        t8[s*16 + lq*4 + r][lm] = ((unsigned)hb << 16) | (unsigned)lb;
      }
    }
  }
  __syncthreads();
  // readout: lane = px; write NHWC8 ch0-4 (masked x<=728)
  {
    int x = xw + lane;
    if (x <= 728){
      unsigned c0 = t8[lane][0], c1 = t8[lane][1], c2 = t8[lane][2];
      unsigned c3 = t8[lane][3], c4 = t8[lane][4];
      size_t base = ((size_t)(y+1)*DRS + x)*8;
      short4v vh; vh[0]=(short)(c0>>16); vh[1]=(short)(c1>>16); vh[2]=(short)(c2>>16); vh[3]=(short)(c3>>16);
      short4v vl; vl[0]=(short)(c0&0xffffu); vl[1]=(short)(c1&0xffffu); vl[2]=(short)(c2&0xffffu); vl[3]=(short)(c3&0xffffu);
      *(short4v*)(s8hi + base) = vh;
      *(short4v*)(s8lo + base) = vl;
      s8hi[base+4] = (unsigned short)(c4>>16);
      s8lo[base+4] = (unsigned short)(c4&0xffffu);
    }
  }
}

// ---------------- primal conv1 (6->32): implicit-GEMM MFMA on NHWC8 input ----------------
__global__ __launch_bounds__(256) void prim1_mfma(
    const unsigned short* __restrict__ hi8, const unsigned short* __restrict__ lo8,  // [512][512][8]
    const unsigned short* __restrict__ Bimg1,   // this layer: [3][2][2][64][8]
    const float* __restrict__ bias, const float* __restrict__ prelu,
    unsigned short* __restrict__ outHi, unsigned short* __restrict__ outLo)
{
  __shared__ unsigned int tr[4][64][33];
  int b = blockIdx.x;                 // 0..1023
  int by = b >> 1, half = b & 1;
  int y = ((by & 7) << 6) | (by >> 3);   // XCD row swizzle
  int wv = (int)threadIdx.x >> 6;
  int lane = (int)threadIdx.x & 63;
  int xw = half*256 + wv*64;
  int lm = lane & 15, lq = lane >> 4;
  f32x4 acc[4][2];
  #pragma unroll
  for (int s=0;s<4;s++){ acc[s][0] = (f32x4)0.f; acc[s][1] = (f32x4)0.f; }
  bool fast = (y>0) && (y<511) && (xw!=0) && (xw!=448);
  const short8* Bf = (const short8*)Bimg1;
  #pragma unroll
  for (int g=0; g<3; g++){
    const short8* bp8 = Bf + g*256 + lane;
    short8 bh0 = bp8[0];
    short8 bl0 = bp8[64];
    short8 bh1 = bp8[128];
    short8 bl1 = bp8[192];
    int t = g*4 + lq; if (t > 8) t = 8;
    int dy = (t >= 6) ? 1 : ((t >= 3) ? 0 : -1);
    int dx = t - (dy+1)*3 - 1;
    int row = y + dy;
    #pragma unroll
    for (int s=0; s<4; s++){
      short8 ah, al;
      int px = xw + s*16 + lm + dx;
      if (fast){
        size_t off = ((size_t)row*SS + px)*8;
        ah = *(const short8*)(hi8 + off);
        al = *(const short8*)(lo8 + off);
      } else {
        bool ok = ((unsigned)row < 512u) && ((unsigned)px < 512u);
        size_t off = ok ? ((size_t)row*SS + px)*8 : 0;
        ah = ok ? *(const short8*)(hi8 + off) : (short8)0;
        al = ok ? *(const short8*)(lo8 + off) : (short8)0;
      }
      acc[s][0] = __builtin_amdgcn_mfma_f32_16x16x32_bf16(ah, bh0, acc[s][0], 0,0,0);
      acc[s][1] = __builtin_amdgcn_mfma_f32_16x16x32_bf16(ah, bh1, acc[s][1], 0,0,0);
      acc[s][0] = __builtin_amdgcn_mfma_f32_16x16x32_bf16(al, bh0, acc[s][0], 0,0,0);
      acc[s][1] = __builtin_amdgcn_mfma_f32_16x16x32_bf16(al, bh1, acc[s][1], 0,0,0);
      acc[s][0] = __builtin_amdgcn_mfma_f32_16x16x32_bf16(ah, bl0, acc[s][0], 0,0,0);
      acc[s][1] = __builtin_amdgcn_mfma_f32_16x16x32_bf16(ah, bl1, acc[s][1], 0,0,0);
    }
  }
  // epilogue: bias + prelu + pack hi/lo into LDS [px][ch], NHWC32 stores
  float aa = *prelu;
  #pragma unroll
  for (int s=0;s<4;s++){
    #pragma unroll
    for (int n=0;n<2;n++){
      int o = n*16 + lm;
      float bv = bias[o];
      f32x4 v = acc[s][n];
      v.x+=bv; v.y+=bv; v.z+=bv; v.w+=bv;
      v.x=(v.x>=0.f)?v.x:aa*v.x; v.y=(v.y>=0.f)?v.y:aa*v.y;
      v.z=(v.z>=0.f)?v.z:aa*v.z; v.w=(v.w>=0.f)?v.w:aa*v.w;
      #pragma unroll
      for (int r=0;r<4;r++){
        float x = v[r];
        unsigned short hb = f2bf(x);
        float hf = __uint_as_float((unsigned)hb << 16);
        unsigned short lb = f2bf(x - hf);
        tr[wv][s*16 + lq*4 + r][o] = ((unsigned)hb << 16) | (unsigned)lb;
      }
    }
  }
  __syncthreads();
  int c8 = lane & 3;
  int pxl = lane >> 2;
  #pragma unroll
  for (int k=0;k<4;k++){
    int px = pxl + k*16;
    short8 vh, vl;
    #pragma unroll
    for (int j=0;j<8;j++){
      unsigned p = tr[wv][px][c8*8 + j];
      vh[j] = (short)(p >> 16);
      vl[j] = (short)(p & 0xffffu);
    }
    size_t base = ((size_t)(y*SS + xw + px))*32 + c8*8;
    *(short8*)(outHi + base) = vh;
    *(short8*)(outLo + base) = vl;
  }
}

// ---------------- primal conv2 (32->32): implicit-GEMM MFMA bf16 hi/lo ----------------
__global__ __launch_bounds__(256) void conv_mfma32(
    const unsigned short* __restrict__ hiB, const unsigned short* __restrict__ loB,
    const unsigned short* __restrict__ Bimg,   // this layer: [9][2][2][64][8]
    const float* __restrict__ bias, const float* __restrict__ prelu,
    unsigned short* __restrict__ outHi, unsigned short* __restrict__ outLo)
{
  __shared__ unsigned int tr[4][64][33];
  int b = blockIdx.x;                 // 0..1023
  int by = b >> 1, half = b & 1;
  int y = ((by & 7) << 6) | (by >> 3);   // XCD row swizzle
  int wv = (int)threadIdx.x >> 6;
  int lane = (int)threadIdx.x & 63;
  int xw = half*256 + wv*64;
  int lm = lane & 15, lq = lane >> 4;
  int laneoff = lm*32 + lq*8;
  f32x4 acc[4][2];
  #pragma unroll
  for (int s=0;s<4;s++){ acc[s][0] = (f32x4)0.f; acc[s][1] = (f32x4)0.f; }
  bool fastx = (xw != 0) && (xw != 448);
  const short8* Bf = (const short8*)Bimg;
  #pragma unroll
  for (int dy=-1; dy<=1; dy++){
    int yy = y + dy;
    if ((unsigned)yy >= 512u) continue;
    const unsigned short* rh = hiB + (size_t)yy*512*32;
    const unsigned short* rl = loB + (size_t)yy*512*32;
    #pragma unroll
    for (int dx=-1; dx<=1; dx++){
      int tap = (dy+1)*3 + (dx+1);
      const short8* bp8 = Bf + tap*256 + lane;
      short8 bh0 = bp8[0];     // n=0 hi
      short8 bl0 = bp8[64];    // n=0 lo
      short8 bh1 = bp8[128];   // n=1 hi
      short8 bl1 = bp8[192];   // n=1 lo
      int xoff = (xw + dx)*32 + laneoff;
      #pragma unroll
      for (int s=0; s<4; s++){
        short8 ah, al;
        const unsigned short* ph = rh + xoff + s*512;
        const unsigned short* pl = rl + xoff + s*512;
        if (fastx){
          ah = *(const short8*)ph;
          al = *(const short8*)pl;
        } else {
          int x = xw + s*16 + lm + dx;
          bool ok = ((unsigned)x < 512u);
          ah = ok ? *(const short8*)ph : (short8)0;
          al = ok ? *(const short8*)pl : (short8)0;
        }
        acc[s][0] = __builtin_amdgcn_mfma_f32_16x16x32_bf16(ah, bh0, acc[s][0], 0,0,0);
        acc[s][1] = __builtin_amdgcn_mfma_f32_16x16x32_bf16(ah, bh1, acc[s][1], 0,0,0);
        acc[s][0] = __builtin_amdgcn_mfma_f32_16x16x32_bf16(al, bh0, acc[s][0], 0,0,0);
        acc[s][1] = __builtin_amdgcn_mfma_f32_16x16x32_bf16(al, bh1, acc[s][1], 0,0,0);
        acc[s][0] = __builtin_amdgcn_mfma_f32_16x16x32_bf16(ah, bl0, acc[s][0], 0,0,0);
        acc[s][1] = __builtin_amdgcn_mfma_f32_16x16x32_bf16(ah, bl1, acc[s][1], 0,0,0);
      }
    }
  }
  // epilogue: bias + prelu + pack hi/lo into LDS [px][ch]
  float aa = *prelu;
  #pragma unroll
  for (int s=0;s<4;s++){
    #pragma unroll
    for (int n=0;n<2;n++){
      int o = n*16 + lm;
      float bv = bias[o];
      f32x4 v = acc[s][n];
      v.x+=bv; v.y+=bv; v.z+=bv; v.w+=bv;
      v.x=(v.x>=0.f)?v.x:aa*v.x; v.y=(v.y>=0.f)?v.y:aa*v.y;
      v.z=(v.z>=0.f)?v.z:aa*v.z; v.w=(v.w>=0.f)?v.w:aa*v.w;
      #pragma unroll
      for (int r=0;r<4;r++){
        float x = v[r];
        unsigned short hb = f2bf(x);
        float hf = __uint_as_float((unsigned)hb << 16);
        unsigned short lb = f2bf(x - hf);
        tr[wv][s*16 + lq*4 + r][o] = ((unsigned)hb << 16) | (unsigned)lb;
      }
    }
  }
  __syncthreads();
  // read channel-contiguous, split, coalesced NHWC stores
  int c8 = lane & 3;             // 8-channel chunk
  int pxl = lane >> 2;           // 0..15
  #pragma unroll
  for (int k=0;k<4;k++){
    int px = pxl + k*16;
    short8 vh, vl;
    #pragma unroll
    for (int j=0;j<8;j++){
      unsigned p = tr[wv][px][c8*8 + j];
      vh[j] = (short)(p >> 16);
      vl[j] = (short)(p & 0xffffu);
    }
    size_t base = ((size_t)(y*SS + xw + px))*32 + c8*8;
    *(short8*)(outHi + base) = vh;
    *(short8*)(outLo + base) = vl;
  }
}

// ---------------- primal conv3 (32->5): implicit-GEMM MFMA, N=16 (5 real) ----------------
__global__ __launch_bounds__(256) void duo_mfma(
    const unsigned short* __restrict__ hiB, const unsigned short* __restrict__ loB,
    const unsigned short* __restrict__ Bimg3,   // this layer: [9][2][64][8]
    const float* __restrict__ bias,
    float* __restrict__ f,
    float* __restrict__ fout, float* __restrict__ tout,
    unsigned short* __restrict__ hi8, unsigned short* __restrict__ lo8)
{
  __shared__ unsigned int t8[4][64][6];
  int b = blockIdx.x;                 // 0..1023
  int by = b >> 1, half = b & 1;
  int y = ((by & 7) << 6) | (by >> 3);   // XCD row swizzle
  int wv = (int)threadIdx.x >> 6;
  int lane = (int)threadIdx.x & 63;
  int xw = half*256 + wv*64;
  int lm = lane & 15, lq = lane >> 4;
  int laneoff = lm*32 + lq*8;
  f32x4 acc[4];
  #pragma unroll
  for (int s=0;s<4;s++) acc[s] = (f32x4)0.f;
  bool fastx = (xw != 0) && (xw != 448);
  const short8* Bf = (const short8*)Bimg3;
  #pragma unroll
  for (int dy=-1; dy<=1; dy++){
    int yy = y + dy;
    if ((unsigned)yy >= 512u) continue;
    const unsigned short* rh = hiB + (size_t)yy*512*32;
    const unsigned short* rl = loB + (size_t)yy*512*32;
    #pragma unroll
    for (int dx=-1; dx<=1; dx++){
      int tap = (dy+1)*3 + (dx+1);
      const short8* bp8 = Bf + tap*128 + lane;
      short8 bh = bp8[0];
      short8 bl = bp8[64];
      int xoff = (xw + dx)*32 + laneoff;
      #pragma unroll
      for (int s=0; s<4; s++){
        short8 ah, al;
        const unsigned short* ph = rh + xoff + s*512;
        const unsigned short* pl = rl + xoff + s*512;
        if (fastx){
          ah = *(const short8*)ph;
          al = *(const short8*)pl;
        } else {
          int x = xw + s*16 + lm + dx;
          bool ok = ((unsigned)x < 512u);
          ah = ok ? *(const short8*)ph : (short8)0;
          al = ok ? *(const short8*)pl : (short8)0;
        }
        acc[s] = __builtin_amdgcn_mfma_f32_16x16x32_bf16(ah, bh, acc[s], 0,0,0);
        acc[s] = __builtin_amdgcn_mfma_f32_16x16x32_bf16(al, bh, acc[s], 0,0,0);
        acc[s] = __builtin_amdgcn_mfma_f32_16x16x32_bf16(ah, bl, acc[s], 0,0,0);
      }
    }
  }
  // epilogue: f += conv3 + bias on lanes lm<5; imgT transpose (lm==1); output rep (lm==0)
  if (lm < 5){
    float bv = bias[lm];
    #pragma unroll
    for (int s=0;s<4;s++){
      int px0 = xw + s*16 + lq*4;
      float* op = f + (size_t)lm*NPIX + y*SS + px0;
      f32x4 old = *(const f32x4*)op;
      f32x4 v = acc[s];
      v.x += old.x + bv; v.y += old.y + bv;
      v.z += old.z + bv; v.w += old.w + bv;
      *(f32x4*)op = v;
      #pragma unroll
      for (int r=0;r<4;r++){
        float x = v[r];
        unsigned short hb = f2bf(x);
        float hf = __uint_as_float((unsigned)hb << 16);
        unsigned short lb = f2bf(x - hf);
        t8[wv][s*16 + lq*4 + r][lm] = ((unsigned)hb << 16) | (unsigned)lb;
      }
      if (lm == 1){
        tout[(px0  )*SS + y] = v.x;
        tout[(px0+1)*SS + y] = v.y;
        tout[(px0+2)*SS + y] = v.z;
        tout[(px0+3)*SS + y] = v.w;
      }
      if (lm == 0 && fout){
        float* q = fout + y*SS + px0;
        *(f32x4*)q = v;
        *(f32x4*)(q + NPIX) = v;
        *(f32x4*)(q + 2*NPIX) = v;
      }
    }
  }
  __syncthreads();
  // readout: lane = px; write NHWC8 ch0-4 (8B + 2B stores, hi and lo)
  {
    unsigned c0 = t8[wv][lane][0], c1 = t8[wv][lane][1], c2 = t8[wv][lane][2];
    unsigned c3 = t8[wv][lane][3], c4 = t8[wv][lane][4];
    size_t base = ((size_t)(y*SS + xw + lane))*8;
    short4v vh; vh[0]=(short)(c0>>16); vh[1]=(short)(c1>>16); vh[2]=(short)(c2>>16); vh[3]=(short)(c3>>16);
    short4v vl; vl[0]=(short)(c0&0xffffu); vl[1]=(short)(c1&0xffffu); vl[2]=(short)(c2&0xffffu); vl[3]=(short)(c3&0xffffu);
    *(short4v*)(hi8 + base) = vh;
    *(short4v*)(lo8 + base) = vl;
    hi8[base+4] = (unsigned short)(c4>>16);
    lo8[base+4] = (unsigned short)(c4&0xffffu);
  }
}

extern "C" void kernel_launch(void* const* d_in, const int* in_sizes, int n_in,
                              void* d_out, int out_size, void* d_ws, size_t ws_size,
                              hipStream_t stream){
  const float* g     = (const float*)d_in[2];
  const float* theta = (const float*)d_in[3];
  const float* dw1 = (const float*)d_in[5];
  const float* db1 = (const float*)d_in[6];
  const float* da1 = (const float*)d_in[7];
  const float* dw2 = (const float*)d_in[8];
  const float* db2 = (const float*)d_in[9];
  const float* da2 = (const float*)d_in[10];
  const float* dw3 = (const float*)d_in[11];
  const float* db3 = (const float*)d_in[12];
  const float* pw1 = (const float*)d_in[13];
  const float* pb1 = (const float*)d_in[14];
  const float* pa1 = (const float*)d_in[15];
  const float* pw2 = (const float*)d_in[16];
  const float* pb2 = (const float*)d_in[17];
  const float* pa2 = (const float*)d_in[18];
  const float* pw3 = (const float*)d_in[19];
  const float* pb3 = (const float*)d_in[20];

  float* ws     = (float*)d_ws;
  float* trig   = ws;                    // 128
  float* taps   = ws + 128;              // -> 2048
  float* h      = ws + 2048;             // 5*NSIN
  float* opf    = h + 5*NSIN;            // NSIN (unused, keeps layout)
  float* gcopy  = opf + NSIN;            // NSIN (unused, keeps layout)
  float* h1     = gcopy + NSIN;          // NSIN
  float* f      = h1 + NSIN;             // 5*NPIX
  float* bp     = f + 5*NPIX;            // NPIX (unused, keeps layout)
  float* imgT   = bp + NPIX;             // NPIX
  float* dualT1 = imgT + NPIX;           // 32*NSIN slot -> dual2Hi
  float* dualT2 = dualT1 + 32*NSIN;      // 32*NSIN slot -> dual2Lo
  float* primT2slot = dualT2 + 32*NSIN;  // 32*NPIX floats of space
  unsigned short* primHi = (unsigned short*)primT2slot;          // 32*NPIX ushorts
  unsigned short* primLo = primHi + (size_t)32*NPIX;             // 32*NPIX ushorts
  unsigned short* nhwcHi = (unsigned short*)(primT2slot + 32*NPIX);  // 32*NPIX ushorts
  unsigned short* nhwcLo = nhwcHi + (size_t)32*NPIX;             // 32*NPIX ushorts
  float* wsp   = (float*)(nhwcLo + (size_t)32*NPIX);
  unsigned short* Bimg  = (unsigned short*)(wsp + 158400);       // 184320 ushorts
  unsigned short* Bimg2 = Bimg + 184320;                         // 184320 ushorts
  unsigned short* Bimg3 = Bimg2 + 184320;                        // 92160 ushorts
  unsigned short* Bimg1 = Bimg3 + 92160;                         // 61440 ushorts
  unsigned short* Bimg1d = Bimg1 + 61440;                        // 61440 ushorts
  unsigned short* Bimg3d = Bimg1d + 61440;                       // 92160 ushorts
  // dual NHWC32 hi/lo: 62 rows x DRS x 32ch + 64-ushort zero prefix/suffix
  const size_t DUALSZ = (size_t)64 + (size_t)62*DRS*32 + 64;
  unsigned short* dualHiRaw = Bimg3d + 92160;
  unsigned short* dualLoRaw = dualHiRaw + DUALSZ;
  unsigned short* dualHi = dualHiRaw + 64;
  unsigned short* dualLo = dualLoRaw + 64;
  // dual conv2 NHWC32 output in recycled dualT1/dualT2 slots
  unsigned short* dual2HiRaw = (unsigned short*)dualT1;
  unsigned short* dual2LoRaw = (unsigned short*)dualT2;
  unsigned short* dual2Hi = dual2HiRaw + 64;
  unsigned short* dual2Lo = dual2LoRaw + 64;
  // primal NHWC8 input image [512][512][8] bf16 hi/lo
  unsigned short* nh8Hi = dualLoRaw + DUALSZ;
  unsigned short* nh8Lo = nh8Hi + (size_t)NPIX*8;
  // sinogram NHWC8 input image [62][DRS][8] bf16 hi/lo + 64-ushort prefix/suffix
  const size_t S8SZ = (size_t)64 + (size_t)62*DRS*8 + 64;
  unsigned short* s8HiRaw = nh8Lo + (size_t)NPIX*8;
  unsigned short* s8LoRaw = s8HiRaw + S8SZ;
  unsigned short* s8Hi = s8HiRaw + 64;
  unsigned short* s8Lo = s8LoRaw + 64;

  hipMemsetAsync(h, 0, (size_t)(5*NSIN)*sizeof(float), stream);
  hipMemsetAsync(f, 0, (size_t)(7*NPIX)*sizeof(float), stream);   // f, bp, imgT
  hipMemsetAsync(dualHiRaw, 0, 2*DUALSZ*sizeof(unsigned short), stream);  // zero pads once
  hipMemsetAsync(dual2HiRaw, 0, DUALSZ*sizeof(unsigned short), stream);   // zero pads once
  hipMemsetAsync(dual2LoRaw, 0, DUALSZ*sizeof(unsigned short), stream);   // zero pads once
  hipMemsetAsync(nh8Hi, 0, (size_t)2*NPIX*8*sizeof(unsigned short), stream); // zero once
  hipMemsetAsync(s8HiRaw, 0, 2*S8SZ*sizeof(unsigned short), stream); // zero once
  trig_kernel<<<1,64,0,stream>>>(theta, trig);
  taps_kernel<<<NTAPS,256,0,stream>>>(taps);
  prep_bimg<<<(92160+255)/256,256,0,stream>>>(pw2, Bimg);
  prep_bimg<<<(92160+255)/256,256,0,stream>>>(dw2, Bimg2);
  prep_bimg3<<<(46080+255)/256,256,0,stream>>>(pw3, Bimg3);
  prep_bimg3<<<(46080+255)/256,256,0,stream>>>(dw3, Bimg3d);
  prep_bimg1c<<<(30720+255)/256,256,0,stream>>>(pw1, Bimg1, 6);
  prep_bimg1c<<<(30720+255)/256,256,0,stream>>>(dw1, Bimg1d, 7);
  g_to_nhwc8<<<(NSIN+255)/256,256,0,stream>>>(g, s8Hi, s8Lo);

  for (int i=0;i<10;i++){
    radon_fwd_kernel<<<(NSIN+3)/4,256,0,stream>>>(f + NPIX, imgT, trig, s8Hi, s8Lo);
    // dual block: NHWC8 [h(5)|opf|g|0] -> conv1 -> conv2 -> conv3 (all MFMA)
    dual1_mfma<<<dim3(12,AANG),64,0,stream>>>(s8Hi, s8Lo, Bimg1d+(size_t)i*6144,
                                              db1+(size_t)i*32, da1+i, dualHi, dualLo);
    dual_mfma32<<<dim3(12,AANG),64,0,stream>>>(dualHi, dualLo, Bimg2+(size_t)i*18432,
                                               db2+(size_t)i*32, da2+i, dual2Hi, dual2Lo);
    dual3_mfma<<<dim3(12,AANG),64,0,stream>>>(dual2Hi, dual2Lo, Bimg3d+(size_t)i*9216,
                                              db3+(size_t)i*5, h, s8Hi, s8Lo);
    filter_kernel2<<<AANG*12,256,0,stream>>>(h, taps, h1);
    backproj_kernel<<<NPIX/256,256,0,stream>>>(h1, trig, nh8Hi, nh8Lo);
    // primal block: NHWC8 [f(5)|bp|0|0] -> conv1 -> conv2 -> conv3
    prim1_mfma<<<1024,256,0,stream>>>(nh8Hi, nh8Lo, Bimg1+(size_t)i*6144,
                                      pb1+(size_t)i*32, pa1+i, nhwcHi, nhwcLo);
    conv_mfma32<<<1024,256,0,stream>>>(nhwcHi, nhwcLo, Bimg+(size_t)i*18432, pb2+(size_t)i*32, pa2+i, primHi, primLo);
    duo_mfma<<<1024,256,0,stream>>>(primHi, primLo, Bimg3+(size_t)i*9216, pb3+(size_t)i*5, f,
                                    (i==9) ? (float*)d_out : nullptr, imgT, nh8Hi, nh8Lo);
  }
}